// Round 2
// baseline (6038.009 us; speedup 1.0000x reference)
//
#include <hip/hip_runtime.h>

#define PI_F 3.14159265358979323846f

constexpr int L_ = 16384;   // H*W
constexpr int PD_ = 32768;  // P*P*C

__device__ __forceinline__ float sigmoidf_(float x){ return 1.f/(1.f+__expf(-x)); }
__device__ __forceinline__ float softplusf_(float x){ return x>20.f ? x : log1pf(__expf(x)); }
__device__ __forceinline__ float geluf_(float x){ return 0.5f*x*(1.f+erff(x*0.70710678118654752f)); }

__device__ __forceinline__ float2 block_reduce2(float s, float ss){
  __shared__ float r1[256], r2[256];
  int tid = threadIdx.x;
  r1[tid]=s; r2[tid]=ss; __syncthreads();
  for(int o=128;o>0;o>>=1){ if(tid<o){ r1[tid]+=r1[tid+o]; r2[tid]+=r2[tid+o]; } __syncthreads(); }
  float2 out; out.x=r1[0]; out.y=r2[0]; __syncthreads();
  return out;
}

// ---------------- patch embed ----------------
// xn[m][k] = LN over pd of gathered patch, m = b*16 + (ih*4+iw), k=(p1*32+p2)*32+c
__global__ __launch_bounds__(256) void k_ln_pe(const float* __restrict__ img, const float* __restrict__ g,
                                               const float* __restrict__ bv, float* __restrict__ xn){
  int m = blockIdx.x; int b = m>>4, n = m&15, ih = n>>2, iw = n&3;
  int tid = threadIdx.x;
  const float* base = img + (size_t)b*32*L_;
  float s=0.f, ss=0.f;
  for (int j=tid; j<PD_; j+=256){
    int c=j>>10, p1=(j>>5)&31, p2=j&31;
    float v = base[(size_t)c*L_ + (ih*32+p1)*128 + iw*32+p2];
    s+=v; ss+=v*v;
  }
  float2 r = block_reduce2(s,ss);
  float mean = r.x/(float)PD_;
  float var  = r.y/(float)PD_ - mean*mean;
  float inv = 1.f/sqrtf(var+1e-5f);
  for (int j=tid; j<PD_; j+=256){
    int c=j>>10, p1=(j>>5)&31, p2=j&31;
    float v = base[(size_t)c*L_ + (ih*32+p1)*128 + iw*32+p2];
    int k = (p1*32+p2)*32 + c;
    xn[(size_t)m*PD_ + k] = (v-mean)*inv*g[k] + bv[k];
  }
}

// split-K GEMM for pe: t[32][512] += xn[32][32768] @ pe_w[32768][512]
__global__ __launch_bounds__(256) void k_pe_gemm(const float* __restrict__ A, const float* __restrict__ Bw,
                                                 float* __restrict__ C){
  __shared__ float As[32][64];
  int tid=threadIdx.x, tx=tid&63, ty=tid>>6;
  int n = blockIdx.x*64 + tx;
  int kbase = blockIdx.y*1024;
  float acc[8]={0,0,0,0,0,0,0,0};
  for (int k0=kbase; k0<kbase+1024; k0+=64){
    for (int i=tid;i<2048;i+=256) As[i>>6][i&63]=A[(size_t)(i>>6)*PD_ + k0 + (i&63)];
    __syncthreads();
    for (int kk=0;kk<64;kk+=4){
      float b0=Bw[(size_t)(k0+kk)*512+n], b1=Bw[(size_t)(k0+kk+1)*512+n];
      float b2=Bw[(size_t)(k0+kk+2)*512+n], b3=Bw[(size_t)(k0+kk+3)*512+n];
      #pragma unroll
      for (int r=0;r<8;r++){
        const float4 a = *(const float4*)&As[ty*8+r][kk];
        acc[r] += a.x*b0+a.y*b1+a.z*b2+a.w*b3;
      }
    }
    __syncthreads();
  }
  #pragma unroll
  for (int r=0;r<8;r++) atomicAdd(&C[(ty*8+r)*512 + n], acc[r]);
}

// t = LN(t + pe_b)*g + b + pos_emb
__global__ __launch_bounds__(256) void k_pe_post(float* __restrict__ t, const float* __restrict__ peb,
                                                 const float* __restrict__ g, const float* __restrict__ bv,
                                                 const float* __restrict__ pos){
  int m=blockIdx.x, tid=threadIdx.x;
  float v0 = t[m*512+tid] + peb[tid];
  float v1 = t[m*512+256+tid] + peb[256+tid];
  float2 r = block_reduce2(v0+v1, v0*v0+v1*v1);
  float mean=r.x/512.f, var=r.y/512.f-mean*mean, inv=1.f/sqrtf(var+1e-5f);
  int n = m&15;
  t[m*512+tid]     = (v0-mean)*inv*g[tid]+bv[tid]         + pos[n*512+tid];
  t[m*512+256+tid] = (v1-mean)*inv*g[256+tid]+bv[256+tid] + pos[n*512+256+tid];
}

// dst = LN(src)*g+b over D=512 per row (src==dst allowed)
__global__ __launch_bounds__(256) void k_ln_tok(const float* __restrict__ src, const float* __restrict__ g,
                                                const float* __restrict__ bv, float* __restrict__ dst){
  int m=blockIdx.x, tid=threadIdx.x;
  float v0=src[m*512+tid], v1=src[m*512+256+tid];
  float2 r=block_reduce2(v0+v1, v0*v0+v1*v1);
  float mean=r.x/512.f, var=r.y/512.f-mean*mean, inv=1.f/sqrtf(var+1e-5f);
  dst[m*512+tid]     =(v0-mean)*inv*g[tid]+bv[tid];
  dst[m*512+256+tid] =(v1-mean)*inv*g[256+tid]+bv[256+tid];
}

__global__ void k_addpos(const float* __restrict__ t, const float* __restrict__ pos, float* __restrict__ dst){
  int i = blockIdx.x*256+threadIdx.x;   // 16384
  int m=i>>9, j=i&511;
  dst[i]=t[i]+pos[(m&15)*512+j];
}

// generic skinny GEMM: C[32][N] = A[32][K]@B[K][N] (+bias)(+R); mode 0: store, 1: gelu-store, 2: scatter to x-NCHW
__global__ __launch_bounds__(256) void k_gemm_tok(const float* __restrict__ A, const float* __restrict__ Bw,
                                                  const float* __restrict__ bias, const float* __restrict__ R,
                                                  float* __restrict__ C, int N, int K, int mode){
  __shared__ float As[32][64];
  int tid=threadIdx.x, tx=tid&31, ty=tid>>5;
  int n = blockIdx.x*32+tx;
  float acc[4]={0,0,0,0};
  for (int k0=0;k0<K;k0+=64){
    for (int i=tid;i<2048;i+=256) As[i>>6][i&63]=A[(size_t)(i>>6)*K+k0+(i&63)];
    __syncthreads();
    for (int kk=0;kk<64;kk+=4){
      float b0=Bw[(size_t)(k0+kk)*N+n], b1=Bw[(size_t)(k0+kk+1)*N+n];
      float b2=Bw[(size_t)(k0+kk+2)*N+n], b3=Bw[(size_t)(k0+kk+3)*N+n];
      #pragma unroll
      for (int r=0;r<4;r++){
        const float4 a=*(const float4*)&As[ty*4+r][kk];
        acc[r]+=a.x*b0+a.y*b1+a.z*b2+a.w*b3;
      }
    }
    __syncthreads();
  }
  #pragma unroll
  for (int r=0;r<4;r++){
    int mrow=ty*4+r;
    float v=acc[r];
    if(bias) v+=bias[n];
    if(R) v+=R[(size_t)mrow*N+n];
    if(mode==1) v=geluf_(v);
    if(mode==2){
      int b=mrow>>4, ih=(mrow>>2)&3, iw=mrow&3;
      int cu=n>>10, f1=(n>>5)&31, f2=n&31;
      C[((size_t)(b*4+cu)*128 + ih*32+f1)*128 + iw*32+f2]=v;
    } else {
      C[(size_t)mrow*N+n]=v;
    }
  }
}

// attention for 16 tokens, one block per (b,h)
__global__ __launch_bounds__(256) void k_attn(const float* __restrict__ qkv, float* __restrict__ outb){
  int bh=blockIdx.x, b=bh>>3, h=bh&7, tid=threadIdx.x;
  __shared__ float q[16][64], kk[16][64], vv[16][64], pp[16][16];
  for (int i=tid;i<1024;i+=256){
    int row=i>>6, d=i&63;
    const float* src=qkv + (size_t)(b*16+row)*1536 + h*64+d;
    q[row][d]=src[0]; kk[row][d]=src[512]; vv[row][d]=src[1024];
  }
  __syncthreads();
  int i=tid>>4, j=tid&15;
  float s=0.f;
  #pragma unroll
  for (int d=0;d<64;d++) s+=q[i][d]*kk[j][d];
  s*=0.125f;
  float mx=s;
  for (int o=8;o>0;o>>=1) mx=fmaxf(mx,__shfl_xor(mx,o,16));
  float e=__expf(s-mx), sm=e;
  for (int o=8;o>0;o>>=1) sm+=__shfl_xor(sm,o,16);
  pp[i][j]=e/sm;
  __syncthreads();
  int d=tid&63;
  for (int pass=0;pass<4;pass++){
    int row=pass*4+(tid>>6);
    float acc=0.f;
    #pragma unroll
    for (int jj=0;jj<16;jj++) acc+=pp[row][jj]*vv[jj][d];
    outb[(size_t)(b*16+row)*512 + h*64+d]=acc;
  }
}

// ---------------- SS2D ----------------
// xz[b,e,l] = sum_c ksp[b,c,l]*w[c,e] + bias[e], e<64
__global__ __launch_bounds__(256) void k_xz(const float* __restrict__ ksp, const float* __restrict__ w,
                                            const float* __restrict__ bv, float* __restrict__ xz){
  int blk=blockIdx.x; int b=blk>>6; int p0=(blk&63)*256; int tid=threadIdx.x;
  __shared__ float lin[32][256];
  __shared__ float lw[2048];
  for (int i=tid;i<2048;i+=256) lw[i]=w[i];
  for (int i=tid;i<8192;i+=256){ int c=i>>8, p=i&255; lin[c][p]=ksp[(size_t)(b*32+c)*L_+p0+p]; }
  __syncthreads();
  float xv[32];
  #pragma unroll
  for (int c=0;c<32;c++) xv[c]=lin[c][tid];
  for (int e=0;e<64;e++){
    float a=bv[e];
    #pragma unroll
    for (int c=0;c<32;c++) a+=xv[c]*lw[c*64+e];
    xz[(size_t)(b*64+e)*L_+p0+tid]=a;
  }
}

// depthwise 3x3 + silu on channels 0..31 of xz -> xs0
__global__ void k_dwconv(const float* __restrict__ xz, const float* __restrict__ w,
                         const float* __restrict__ bv, float* __restrict__ xs0){
  int i=blockIdx.x*256+threadIdx.x;         // 2*32*16384
  int p=i&16383; int d=(i>>14)&31; int b=i>>19;
  int h=p>>7, ww=p&127;
  const float* src=xz+(size_t)(b*64+d)*L_;
  float acc=bv[d];
  for (int ky=0;ky<3;ky++){
    int hh=h+ky-1; if(hh<0||hh>127) continue;
    for (int kx=0;kx<3;kx++){
      int wx=ww+kx-1; if(wx<0||wx>127) continue;
      acc+=src[hh*128+wx]*w[d*9+ky*3+kx];
    }
  }
  xs0[(size_t)(b*32+d)*L_+p]=acc*sigmoidf_(acc);
}

// spatial transpose per (b,d): xs0T[d][w][h] = xs0[d][h][w]
__global__ __launch_bounds__(256) void k_transpose(const float* __restrict__ src, float* __restrict__ dst){
  __shared__ float tile[32][33];
  int z=blockIdx.z;
  int h0=blockIdx.y*32, w0=blockIdx.x*32;
  int tid=threadIdx.x, tx=tid&31, ty=tid>>5;
  const float* s=src+(size_t)z*L_;
  float* d=dst+(size_t)z*L_;
  for (int r=ty;r<32;r+=8) tile[r][tx]=s[(h0+r)*128+w0+tx];
  __syncthreads();
  for (int r=ty;r<32;r+=8) d[(w0+r)*128+h0+tx]=tile[tx][r];
}

// dbl[(b,k),l,c] = sum_d xs[b,k,d,l] * xproj[k,d,c], interleaved layout (...,l,18)
__global__ __launch_bounds__(256) void k_dbl(const float* __restrict__ xs0, const float* __restrict__ xs0T,
                                             const float* __restrict__ xproj, float* __restrict__ dbl){
  int bk=blockIdx.y; int b=bk>>2, k=bk&3;
  int l0=blockIdx.x*256, tid=threadIdx.x;
  const float* src=(k&1)?xs0T:xs0;
  __shared__ float xv[32][256];
  __shared__ float xp[576];
  for (int i=tid;i<576;i+=256) xp[i]=xproj[k*576+i];
  for (int i=tid;i<8192;i+=256){
    int dd=i>>8, p=i&255; int l=l0+p; int li=(k<2)?l:(16383-l);
    xv[dd][p]=src[(size_t)(b*32+dd)*L_+li];
  }
  __syncthreads();
  float xr[32];
  #pragma unroll
  for (int dd=0;dd<32;dd++) xr[dd]=xv[dd][tid];
  float* out=&dbl[((size_t)(b*4+k)*L_ + l0+tid)*18];
  for (int c=0;c<18;c++){
    float a=0.f;
    #pragma unroll
    for (int dd=0;dd<32;dd++) a+=xr[dd]*xp[dd*18+c];
    out[c]=a;
  }
}

// selective scan: one block per (b,k,d); chunked two-pass scan, 8 states
__global__ __launch_bounds__(256) void k_scan(const float* __restrict__ dbl, const float* __restrict__ xs0,
                                              const float* __restrict__ xs0T, const float* __restrict__ dtw,
                                              const float* __restrict__ dtb, const float* __restrict__ Alog,
                                              const float* __restrict__ Dp, float* __restrict__ ys){
  int id=blockIdx.x; int d=id&31, k=(id>>5)&3, b=id>>7;
  const float* src=(k&1)?xs0T:xs0;
  bool rev=(k>=2);
  const float* dbase=dbl + (size_t)(b*4+k)*L_*18;
  const float* xbase=src + (size_t)(b*32+d)*L_;
  float w0=dtw[(k*2+0)*32+d], w1=dtw[(k*2+1)*32+d], bb=dtb[k*32+d];
  float Av[8];
  #pragma unroll
  for (int s=0;s<8;s++) Av[s]=-__expf(Alog[(k*32+d)*8+s]);
  float Dv=Dp[k*32+d];
  int t=threadIdx.x, l0=t*64;
  float P[8],Q[8];
  #pragma unroll
  for (int s=0;s<8;s++){P[s]=1.f;Q[s]=0.f;}
  for (int j=0;j<64;j++){
    int l=l0+j;
    const float* e=dbase+(size_t)l*18;
    float dt=softplusf_(e[0]*w0+e[1]*w1+bb);
    float xsv=xbase[rev?(16383-l):l];
    float u=dt*xsv;
    #pragma unroll
    for (int s=0;s<8;s++){
      float a=__expf(dt*Av[s]);
      Q[s]=a*Q[s]+u*e[2+s];
      P[s]*=a;
    }
  }
  __shared__ float Ps[8][256], Qs[8][256];
  #pragma unroll
  for (int s=0;s<8;s++){Ps[s][t]=P[s];Qs[s][t]=Q[s];}
  __syncthreads();
  for (int off=1;off<256;off<<=1){
    float nP[8],nQ[8];
    if (t>=off){
      #pragma unroll
      for (int s=0;s<8;s++){
        float pP=Ps[s][t-off],pQ=Qs[s][t-off];
        nP[s]=pP*Ps[s][t];
        nQ[s]=Ps[s][t]*pQ+Qs[s][t];
      }
    }
    __syncthreads();
    if (t>=off){
      #pragma unroll
      for (int s=0;s<8;s++){Ps[s][t]=nP[s];Qs[s][t]=nQ[s];}
    }
    __syncthreads();
  }
  float hh[8];
  #pragma unroll
  for (int s=0;s<8;s++) hh[s]=(t==0)?0.f:Qs[s][t-1];
  float* yout=&ys[((size_t)(b*4+k)*32+d)*L_];
  for (int j=0;j<64;j++){
    int l=l0+j;
    const float* e=dbase+(size_t)l*18;
    float dt=softplusf_(e[0]*w0+e[1]*w1+bb);
    float xsv=xbase[rev?(16383-l):l];
    float u=dt*xsv;
    float y=0.f;
    #pragma unroll
    for (int s=0;s<8;s++){
      float a=__expf(dt*Av[s]);
      hh[s]=a*hh[s]+u*e[2+s];
      y+=hh[s]*e[10+s];
    }
    yout[l]=y+Dv*xsv;
  }
}

// combine 4 directions + LN over DI + *silu(z) + out proj (32->20)
__global__ __launch_bounds__(256) void k_ycomb(const float* __restrict__ ys, const float* __restrict__ xz,
                                               const float* __restrict__ g, const float* __restrict__ bv,
                                               const float* __restrict__ ow, const float* __restrict__ ob,
                                               float* __restrict__ oss){
  int blk=blockIdx.x; int b=blk>>6; int p=(blk&63)*256+threadIdx.x;
  int h=p>>7, w=p&127; int lt=w*128+h;
  __shared__ float lw[640]; __shared__ float lb[20]; __shared__ float lg[32], lbv[32];
  int tid=threadIdx.x;
  for (int i=tid;i<640;i+=256) lw[i]=ow[i];
  if (tid<20) lb[tid]=ob[tid];
  if (tid<32){ lg[tid]=g[tid]; lbv[tid]=bv[tid]; }
  __syncthreads();
  size_t base=(size_t)b*4*32*L_;
  float y[32];
  float s=0.f, ss=0.f;
  #pragma unroll
  for (int d=0;d<32;d++){
    float v=ys[base+(size_t)(0*32+d)*L_+p] + ys[base+(size_t)(2*32+d)*L_+16383-p]
          + ys[base+(size_t)(1*32+d)*L_+lt] + ys[base+(size_t)(3*32+d)*L_+16383-lt];
    y[d]=v; s+=v; ss+=v*v;
  }
  float mean=s/32.f, var=ss/32.f-mean*mean, inv=1.f/sqrtf(var+1e-5f);
  #pragma unroll
  for (int d=0;d<32;d++){
    float yn=(y[d]-mean)*inv*lg[d]+lbv[d];
    float zv=xz[(size_t)(b*64+32+d)*L_+p];
    y[d]=yn*(zv*sigmoidf_(zv));
  }
  for (int c=0;c<20;c++){
    float a=lb[c];
    #pragma unroll
    for (int d=0;d<32;d++) a+=y[d]*lw[d*20+c];
    oss[(size_t)(b*20+c)*L_+p]=a;
  }
}

// concat [x(4), in_imgs(32), out_ss(20)] -> xc(56)
__global__ void k_concat(const float* __restrict__ x, const float* __restrict__ img,
                         const float* __restrict__ oss, float* __restrict__ xc){
  int i=blockIdx.x*256+threadIdx.x;       // 2*56*16384
  int p=i&16383; int ch=(i>>14)%56; int b=i/(56*16384);
  float v;
  if (ch<4) v=x[(size_t)(b*4+ch)*L_+p];
  else if (ch<36) v=img[(size_t)(b*32+ch-4)*L_+p];
  else v=oss[(size_t)(b*20+ch-36)*L_+p];
  xc[i]=v;
}

// generic SAME conv3x3, NCO output channels per block in registers
template<int NCO>
__global__ __launch_bounds__(256) void k_conv3(const float* __restrict__ in, const float* __restrict__ wt,
                                               const float* __restrict__ bs, const float* __restrict__ add,
                                               float* __restrict__ out, int Cin, int Cout, int cg_count, int act){
  int b=blockIdx.z/cg_count, cg=blockIdx.z%cg_count;
  int tid=threadIdx.x, tx=tid&15, ty=tid>>4;
  int h=blockIdx.y*16+ty, w=blockIdx.x*16+tx;
  __shared__ float tile[18][18];
  float acc[NCO];
  #pragma unroll
  for (int co=0;co<NCO;co++) acc[co]=0.f;
  for (int ci=0;ci<Cin;ci++){
    const float* src=in+(size_t)(b*Cin+ci)*L_;
    for (int i=tid;i<324;i+=256){
      int r=i/18, c=i%18;
      int gh=blockIdx.y*16+r-1, gw=blockIdx.x*16+c-1;
      tile[r][c]=(gh>=0&&gh<128&&gw>=0&&gw<128)?src[gh*128+gw]:0.f;
    }
    __syncthreads();
    float n0=tile[ty][tx],  n1=tile[ty][tx+1],  n2=tile[ty][tx+2];
    float n3=tile[ty+1][tx],n4=tile[ty+1][tx+1],n5=tile[ty+1][tx+2];
    float n6=tile[ty+2][tx],n7=tile[ty+2][tx+1],n8=tile[ty+2][tx+2];
    const float* wp=wt+((size_t)(cg*NCO)*Cin+ci)*9;
    #pragma unroll
    for (int co=0;co<NCO;co++){
      const float* wq=wp+(size_t)co*Cin*9;
      acc[co]+=n0*wq[0]+n1*wq[1]+n2*wq[2]+n3*wq[3]+n4*wq[4]+n5*wq[5]+n6*wq[6]+n7*wq[7]+n8*wq[8];
    }
    __syncthreads();
  }
  #pragma unroll
  for (int co=0;co<NCO;co++){
    int gco=cg*NCO+co;
    float v=acc[co]+bs[gco];
    if (add) v+=add[(size_t)(b*Cout+gco)*L_+h*128+w];
    if (act) v=v>0.f?v:0.2f*v;
    out[(size_t)(b*Cout+gco)*L_+h*128+w]=v;
  }
}

// ---------------- FFT data consistency ----------------
__device__ __forceinline__ int rev7(int x){
  return ((x&1)<<6)|((x&2)<<4)|((x&4)<<2)|(x&8)|((x&16)>>2)|((x&32)>>4)|((x&64)>>6);
}

__global__ __launch_bounds__(256) void k_fft_dc(const float* __restrict__ x_ri, const float* __restrict__ sens,
                                                const float* __restrict__ ksp, const float* __restrict__ mask,
                                                const float* __restrict__ alpha_p, float* __restrict__ acc){
  int blk=blockIdx.x; int b=blk>>4, coil=blk&15;
  __shared__ float Sr[16384];
  __shared__ float Si[16384];
  __shared__ float twr[64], twi[64];
  int tid=threadIdx.x;
  if (tid<64){ float ang=-2.f*PI_F*(float)tid/128.f; twr[tid]=cosf(ang); twi[tid]=sinf(ang); }
  const float* srp=sens+(size_t)(b*32+2*coil)*L_;
  const float* sip=sens+(size_t)(b*32+2*coil+1)*L_;
  const float* xrp=x_ri+(size_t)(b*2)*L_;
  const float* xip=xrp+L_;
  for (int i=tid;i<16384;i+=256){
    int h=i>>7,w=i&127;
    float sg=((h+w)&1)?-1.f:1.f;
    float sr=srp[i],si=sip[i],xr=xrp[i],xi=xip[i];
    Sr[i]=sg*(sr*xr-si*xi);
    Si[i]=sg*(sr*xi+si*xr);
  }
  __syncthreads();
  // forward DIF rows (natural -> bitrev)
  for (int s=0;s<7;s++){
    int m=64>>s;
    for (int q=tid;q<8192;q+=256){
      int row=q>>6, jj=q&63;
      int j=jj&(m-1), gg=jj>>(6-s);
      int kpos=(gg<<(7-s))+j;
      int i0=row*128+kpos, i1=i0+m;
      int tw=j<<s;
      float ur=Sr[i0],ui=Si[i0],vr=Sr[i1],vi=Si[i1];
      Sr[i0]=ur+vr; Si[i0]=ui+vi;
      float dr=ur-vr,di=ui-vi,wr=twr[tw],wi=twi[tw];
      Sr[i1]=dr*wr-di*wi; Si[i1]=dr*wi+di*wr;
    }
    __syncthreads();
  }
  // forward DIF cols
  for (int s=0;s<7;s++){
    int m=64>>s;
    for (int q=tid;q<8192;q+=256){
      int cpos=q&127, jj=q>>7;
      int j=jj&(m-1), gg=jj>>(6-s);
      int kpos=(gg<<(7-s))+j;
      int i0=kpos*128+cpos, i1=i0+m*128;
      int tw=j<<s;
      float ur=Sr[i0],ui=Si[i0],vr=Sr[i1],vi=Si[i1];
      Sr[i0]=ur+vr; Si[i0]=ui+vi;
      float dr=ur-vr,di=ui-vi,wr=twr[tw],wi=twi[tw];
      Sr[i1]=dr*wr-di*wi; Si[i1]=dr*wi+di*wr;
    }
    __syncthreads();
  }
  // DC combine in bitrev coords: lds <- (1-m)*lds + m*128*S*kmeas
  float alpha=alpha_p[0];
  const float* krp=ksp+(size_t)(b*32+2*coil)*L_;
  const float* kip=ksp+(size_t)(b*32+2*coil+1)*L_;
  const float* mkp=mask+(size_t)b*L_;
  for (int i=tid;i<16384;i+=256){
    int i1=i>>7, i2=i&127;
    int k1=rev7(i1), k2=rev7(i2);
    int kidx=k1*128+k2;
    float mv=mkp[kidx]*alpha;
    float sg=((k1+k2)&1)?-128.f:128.f;  // sign pattern * fwd-scale fold
    float kr=krp[kidx]*100.f*sg, ki=kip[kidx]*100.f*sg;
    Sr[i]=(1.f-mv)*Sr[i]+mv*kr;
    Si[i]=(1.f-mv)*Si[i]+mv*ki;
  }
  __syncthreads();
  // inverse DIT cols (bitrev -> natural)
  for (int s=0;s<7;s++){
    int m=1<<s;
    for (int q=tid;q<8192;q+=256){
      int cpos=q&127, jj=q>>7;
      int j=jj&(m-1), gg=jj>>s;
      int kpos=(gg<<(s+1))+j;
      int i0=kpos*128+cpos, i1=i0+m*128;
      int tw=j<<(6-s);
      float wr=twr[tw], wi=-twi[tw];
      float vr=Sr[i1],vi=Si[i1];
      float tr=vr*wr-vi*wi, ti=vr*wi+vi*wr;
      float ur=Sr[i0],ui=Si[i0];
      Sr[i0]=ur+tr; Si[i0]=ui+ti;
      Sr[i1]=ur-tr; Si[i1]=ui-ti;
    }
    __syncthreads();
  }
  // inverse DIT rows
  for (int s=0;s<7;s++){
    int m=1<<s;
    for (int q=tid;q<8192;q+=256){
      int row=q>>6, jj=q&63;
      int j=jj&(m-1), gg=jj>>s;
      int kpos=(gg<<(s+1))+j;
      int i0=row*128+kpos, i1=i0+m;
      int tw=j<<(6-s);
      float wr=twr[tw], wi=-twi[tw];
      float vr=Sr[i1],vi=Si[i1];
      float tr=vr*wr-vi*wi, ti=vr*wi+vi*wr;
      float ur=Sr[i0],ui=Si[i0];
      Sr[i0]=ur+tr; Si[i0]=ui+ti;
      Sr[i1]=ur-tr; Si[i1]=ui-ti;
    }
    __syncthreads();
  }
  // accumulate conj(s) * S * w / 16384
  float* accr=acc+(size_t)(b*2)*L_;
  float* acci=accr+L_;
  for (int i=tid;i<16384;i+=256){
    int h=i>>7,w=i&127;
    float sc=(((h+w)&1)?-1.f:1.f)*(1.f/16384.f);
    float wr2=Sr[i]*sc, wi2=Si[i]*sc;
    float sr=srp[i], si=sip[i];
    atomicAdd(&accr[i], sr*wr2+si*wi2);
    atomicAdd(&acci[i], sr*wi2-si*wr2);
  }
}

__global__ void k_mag(const float* __restrict__ acc, float* __restrict__ out){
  int i=blockIdx.x*256+threadIdx.x;   // 32768
  int b=i>>14, p=i&16383;
  float re=acc[(size_t)(b*2)*L_+p], im=acc[(size_t)(b*2+1)*L_+p];
  out[i]=sqrtf(re*re+im*im+1e-12f);
}

extern "C" void kernel_launch(void* const* d_in, const int* in_sizes, int n_in,
                              void* d_out, int out_size, void* d_ws, size_t ws_size,
                              hipStream_t stream){
  const float* in_imgs=(const float*)d_in[0];
  const float* in_ksp=(const float*)d_in[1];
  const float* mask=(const float*)d_in[2];
  const float* sens=(const float*)d_in[3];
  const float* pe_ln1_g=(const float*)d_in[4];
  const float* pe_ln1_b=(const float*)d_in[5];
  const float* pe_w=(const float*)d_in[6];
  const float* pe_b=(const float*)d_in[7];
  const float* pe_ln2_g=(const float*)d_in[8];
  const float* pe_ln2_b=(const float*)d_in[9];
  const float* pos_emb=(const float*)d_in[10];
  const float* enc_aln_g=(const float*)d_in[11];
  const float* enc_aln_b=(const float*)d_in[12];
  const float* enc_wqkv=(const float*)d_in[13];
  const float* enc_wo=(const float*)d_in[14];
  const float* enc_bo=(const float*)d_in[15];
  const float* enc_fln_g=(const float*)d_in[16];
  const float* enc_fln_b=(const float*)d_in[17];
  const float* enc_w1=(const float*)d_in[18];
  const float* enc_b1=(const float*)d_in[19];
  const float* enc_w2=(const float*)d_in[20];
  const float* enc_b2=(const float*)d_in[21];
  const float* enc_ng=(const float*)d_in[22];
  const float* enc_nb=(const float*)d_in[23];
  const float* dec_pos=(const float*)d_in[24];
  const float* dec_aln_g=(const float*)d_in[25];
  const float* dec_aln_b=(const float*)d_in[26];
  const float* dec_wqkv=(const float*)d_in[27];
  const float* dec_wo=(const float*)d_in[28];
  const float* dec_bo=(const float*)d_in[29];
  const float* dec_fln_g=(const float*)d_in[30];
  const float* dec_fln_b=(const float*)d_in[31];
  const float* dec_w1=(const float*)d_in[32];
  const float* dec_b1=(const float*)d_in[33];
  const float* dec_w2=(const float*)d_in[34];
  const float* dec_b2=(const float*)d_in[35];
  const float* dec_ng=(const float*)d_in[36];
  const float* dec_nb=(const float*)d_in[37];
  const float* fin_w=(const float*)d_in[38];
  const float* fin_b=(const float*)d_in[39];
  const float* ss_in_w=(const float*)d_in[40];
  const float* ss_in_b=(const float*)d_in[41];
  const float* ss_conv_w=(const float*)d_in[42];
  const float* ss_conv_b=(const float*)d_in[43];
  const float* ss_xproj=(const float*)d_in[44];
  const float* ss_dt_w=(const float*)d_in[45];
  const float* ss_dt_b=(const float*)d_in[46];
  const float* ss_Alog=(const float*)d_in[47];
  const float* ss_D=(const float*)d_in[48];
  const float* ss_ln_g=(const float*)d_in[49];
  const float* ss_ln_b=(const float*)d_in[50];
  const float* ss_out_w=(const float*)d_in[51];
  const float* ss_out_b=(const float*)d_in[52];
  const float* head_w=(const float*)d_in[53];
  const float* head_b=(const float*)d_in[54];
  const float* res_w1=(const float*)d_in[55];
  const float* res_b1=(const float*)d_in[56];
  const float* res_w2=(const float*)d_in[57];
  const float* res_b2=(const float*)d_in[58];
  const float* tail_w=(const float*)d_in[59];
  const float* tail_b=(const float*)d_in[60];
  const float* dc_alpha=(const float*)d_in[61];

  char* ws=(char*)d_ws;
  size_t off=0;
  auto alloc=[&](size_t nfloats)->float*{ float* p=(float*)(ws+off); off+=((nfloats*4+255)/256)*256; return p; };
  float* xn   =alloc((size_t)32*32768);
  float* tA   =alloc(32*512);
  float* tB   =alloc(32*512);
  float* aln  =alloc(32*512);
  float* qkv  =alloc(32*1536);
  float* attno=alloc(32*512);
  float* ffh  =alloc(32*3072);
  float* xup  =alloc((size_t)2*4*L_);
  float* xz   =alloc((size_t)2*64*L_);
  float* xs0  =alloc((size_t)2*32*L_);
  float* xs0T =alloc((size_t)2*32*L_);
  float* dbl  =alloc((size_t)2*4*L_*18);
  float* ys   =alloc((size_t)2*4*32*L_);
  float* oss  =alloc((size_t)2*20*L_);
  float* xc   =alloc((size_t)2*56*L_);
  float* h0   =alloc((size_t)2*64*L_);
  float* tmpc =alloc((size_t)2*64*L_);
  float* x_ri =alloc((size_t)2*2*L_);
  float* accb =alloc((size_t)2*2*L_);
  (void)ws_size; (void)in_sizes; (void)n_in; (void)out_size;

  // ---- patch embed + encoder/decoder ----
  k_ln_pe<<<32,256,0,stream>>>(in_imgs, pe_ln1_g, pe_ln1_b, xn);
  hipMemsetAsync(tA, 0, 32*512*4, stream);
  k_pe_gemm<<<dim3(8,32),256,0,stream>>>(xn, pe_w, tA);
  k_pe_post<<<32,256,0,stream>>>(tA, pe_b, pe_ln2_g, pe_ln2_b, pos_emb);

  for (int i=0;i<4;i++){
    k_ln_tok<<<32,256,0,stream>>>(tA, enc_aln_g+i*512, enc_aln_b+i*512, aln);
    k_gemm_tok<<<48,256,0,stream>>>(aln, enc_wqkv+(size_t)i*512*1536, nullptr, nullptr, qkv, 1536, 512, 0);
    k_attn<<<16,256,0,stream>>>(qkv, attno);
    k_gemm_tok<<<16,256,0,stream>>>(attno, enc_wo+(size_t)i*512*512, enc_bo+i*512, tA, tA, 512, 512, 0);
    k_ln_tok<<<32,256,0,stream>>>(tA, enc_fln_g+i*512, enc_fln_b+i*512, aln);
    k_gemm_tok<<<64,256,0,stream>>>(aln, enc_w1+(size_t)i*512*2048, enc_b1+i*2048, nullptr, ffh, 2048, 512, 1);
    k_gemm_tok<<<16,256,0,stream>>>(ffh, enc_w2+(size_t)i*2048*512, enc_b2+i*512, tA, tA, 512, 2048, 0);
  }
  k_ln_tok<<<32,256,0,stream>>>(tA, enc_ng, enc_nb, tA);
  k_addpos<<<64,256,0,stream>>>(tA, dec_pos, tB);
  k_ln_tok<<<32,256,0,stream>>>(tB, dec_aln_g, dec_aln_b, aln);
  k_gemm_tok<<<48,256,0,stream>>>(aln, dec_wqkv, nullptr, nullptr, qkv, 1536, 512, 0);
  k_attn<<<16,256,0,stream>>>(qkv, attno);
  k_gemm_tok<<<16,256,0,stream>>>(attno, dec_wo, dec_bo, tB, tB, 512, 512, 0);
  k_ln_tok<<<32,256,0,stream>>>(tB, dec_fln_g, dec_fln_b, aln);
  k_gemm_tok<<<96,256,0,stream>>>(aln, dec_w1, dec_b1, nullptr, ffh, 3072, 512, 1);
  k_gemm_tok<<<16,256,0,stream>>>(ffh, dec_w2, dec_b2, tB, tB, 512, 3072, 0);
  k_ln_tok<<<32,256,0,stream>>>(tB, dec_ng, dec_nb, tB);
  k_gemm_tok<<<128,256,0,stream>>>(tB, fin_w, fin_b, nullptr, xup, 4096, 512, 2);

  // ---- SS2D ----
  k_xz<<<128,256,0,stream>>>(in_ksp, ss_in_w, ss_in_b, xz);
  k_dwconv<<<4096,256,0,stream>>>(xz, ss_conv_w, ss_conv_b, xs0);
  k_transpose<<<dim3(4,4,64),256,0,stream>>>(xs0, xs0T);
  k_dbl<<<dim3(64,8),256,0,stream>>>(xs0, xs0T, ss_xproj, dbl);
  k_scan<<<256,256,0,stream>>>(dbl, xs0, xs0T, ss_dt_w, ss_dt_b, ss_Alog, ss_D, ys);
  k_ycomb<<<128,256,0,stream>>>(ys, xz, ss_ln_g, ss_ln_b, ss_out_w, ss_out_b, oss);

  // ---- conv head ----
  k_concat<<<7168,256,0,stream>>>(xup, in_imgs, oss, xc);
  k_conv3<32><<<dim3(8,8,4),256,0,stream>>>(xc, head_w, head_b, nullptr, h0, 56, 64, 2, 1);
  for (int i=0;i<3;i++){
    k_conv3<32><<<dim3(8,8,4),256,0,stream>>>(h0, res_w1+(size_t)i*64*64*9, res_b1+i*64, nullptr, tmpc, 64, 64, 2, 1);
    k_conv3<32><<<dim3(8,8,4),256,0,stream>>>(tmpc, res_w2+(size_t)i*64*64*9, res_b2+i*64, h0, h0, 64, 64, 2, 1);
  }
  k_conv3<2><<<dim3(8,8,2),256,0,stream>>>(h0, tail_w, tail_b, nullptr, x_ri, 64, 2, 1, 0);

  // ---- FFT data consistency ----
  hipMemsetAsync(accb, 0, (size_t)2*2*L_*4, stream);
  k_fft_dc<<<32,256,0,stream>>>(x_ri, sens, in_ksp, mask, dc_alpha, accb);
  k_mag<<<128,256,0,stream>>>(accb, (float*)d_out);
}

// Round 3
// 3066.525 us; speedup vs baseline: 1.9690x; 1.9690x over previous
//
#include <hip/hip_runtime.h>

#define PI_F 3.14159265358979323846f

constexpr int L_ = 16384;   // H*W
constexpr int PD_ = 32768;  // P*P*C

__device__ __forceinline__ float sigmoidf_(float x){ return 1.f/(1.f+__expf(-x)); }
__device__ __forceinline__ float softplusf_(float x){ return x>20.f ? x : log1pf(__expf(x)); }
__device__ __forceinline__ float geluf_(float x){ return 0.5f*x*(1.f+erff(x*0.70710678118654752f)); }

__device__ __forceinline__ float2 block_reduce2(float s, float ss){
  __shared__ float r1[256], r2[256];
  int tid = threadIdx.x;
  r1[tid]=s; r2[tid]=ss; __syncthreads();
  for(int o=128;o>0;o>>=1){ if(tid<o){ r1[tid]+=r1[tid+o]; r2[tid]+=r2[tid+o]; } __syncthreads(); }
  float2 out; out.x=r1[0]; out.y=r2[0]; __syncthreads();
  return out;
}

// ---------------- patch embed ----------------
__global__ __launch_bounds__(256) void k_ln_pe(const float* __restrict__ img, const float* __restrict__ g,
                                               const float* __restrict__ bv, float* __restrict__ xn){
  int m = blockIdx.x; int b = m>>4, n = m&15, ih = n>>2, iw = n&3;
  int tid = threadIdx.x;
  const float* base = img + (size_t)b*32*L_;
  float s=0.f, ss=0.f;
  for (int j=tid; j<PD_; j+=256){
    int c=j>>10, p1=(j>>5)&31, p2=j&31;
    float v = base[(size_t)c*L_ + (ih*32+p1)*128 + iw*32+p2];
    s+=v; ss+=v*v;
  }
  float2 r = block_reduce2(s,ss);
  float mean = r.x/(float)PD_;
  float var  = r.y/(float)PD_ - mean*mean;
  float inv = 1.f/sqrtf(var+1e-5f);
  for (int j=tid; j<PD_; j+=256){
    int c=j>>10, p1=(j>>5)&31, p2=j&31;
    float v = base[(size_t)c*L_ + (ih*32+p1)*128 + iw*32+p2];
    int k = (p1*32+p2)*32 + c;
    xn[(size_t)m*PD_ + k] = (v-mean)*inv*g[k] + bv[k];
  }
}

// split-K skinny GEMM: C[32][N] += A[32][K]@B[K][N]; bias added by blockIdx.y==0 blocks.
// MODE 0: plain; 1: gelu applied to A on load; 2: scatter-store to NCHW x-upsample layout.
template<int KC, int MODE>
__global__ __launch_bounds__(256) void k_gemm_sk(const float* __restrict__ A, const float* __restrict__ Bw,
                                                 const float* __restrict__ bias, float* __restrict__ C,
                                                 int N, int K){
  __shared__ float As[32][KC];
  int tid=threadIdx.x, tx=tid&63, ty=tid>>6;
  int n = blockIdx.x*64+tx;
  int k0 = blockIdx.y*KC;
  for (int i=tid;i<32*KC;i+=256){
    int r=i/KC, c=i%KC;
    float v=A[(size_t)r*K + k0 + c];
    if (MODE==1) v=geluf_(v);
    As[r][c]=v;
  }
  __syncthreads();
  float acc[8]={0,0,0,0,0,0,0,0};
  for (int kk=0;kk<KC;kk+=4){
    float b0=Bw[(size_t)(k0+kk)*N+n],   b1=Bw[(size_t)(k0+kk+1)*N+n];
    float b2=Bw[(size_t)(k0+kk+2)*N+n], b3=Bw[(size_t)(k0+kk+3)*N+n];
    #pragma unroll
    for (int r=0;r<8;r++){
      const float4 a=*(const float4*)&As[ty*8+r][kk];
      acc[r]+=a.x*b0+a.y*b1+a.z*b2+a.w*b3;
    }
  }
  bool addb = (bias!=nullptr) && (blockIdx.y==0);
  #pragma unroll
  for (int r=0;r<8;r++){
    int m=ty*8+r;
    float v=acc[r]+(addb?bias[n]:0.f);
    if (MODE==2){
      int b=m>>4, ih=(m>>2)&3, iw=m&3;
      int cu=n>>10, f1=(n>>5)&31, f2=n&31;
      atomicAdd(&C[((size_t)(b*4+cu)*128+ih*32+f1)*128+iw*32+f2], v);
    } else {
      atomicAdd(&C[(size_t)m*N+n], v);
    }
  }
}

// t = LN(t)*g + b + pos_emb   (bias pe_b already added by the split-K GEMM)
__global__ __launch_bounds__(256) void k_pe_post(float* __restrict__ t,
                                                 const float* __restrict__ g, const float* __restrict__ bv,
                                                 const float* __restrict__ pos){
  int m=blockIdx.x, tid=threadIdx.x;
  float v0 = t[m*512+tid];
  float v1 = t[m*512+256+tid];
  float2 r = block_reduce2(v0+v1, v0*v0+v1*v1);
  float mean=r.x/512.f, var=r.y/512.f-mean*mean, inv=1.f/sqrtf(var+1e-5f);
  int n = m&15;
  t[m*512+tid]     = (v0-mean)*inv*g[tid]+bv[tid]         + pos[n*512+tid];
  t[m*512+256+tid] = (v1-mean)*inv*g[256+tid]+bv[256+tid] + pos[n*512+256+tid];
}

// dst = LN(src)*g+b over D=512 per row (src==dst allowed)
__global__ __launch_bounds__(256) void k_ln_tok(const float* __restrict__ src, const float* __restrict__ g,
                                                const float* __restrict__ bv, float* __restrict__ dst){
  int m=blockIdx.x, tid=threadIdx.x;
  float v0=src[m*512+tid], v1=src[m*512+256+tid];
  float2 r=block_reduce2(v0+v1, v0*v0+v1*v1);
  float mean=r.x/512.f, var=r.y/512.f-mean*mean, inv=1.f/sqrtf(var+1e-5f);
  dst[m*512+tid]     =(v0-mean)*inv*g[tid]+bv[tid];
  dst[m*512+256+tid] =(v1-mean)*inv*g[256+tid]+bv[256+tid];
}

__global__ void k_addpos(const float* __restrict__ t, const float* __restrict__ pos, float* __restrict__ dst){
  int i = blockIdx.x*256+threadIdx.x;   // 16384
  int m=i>>9, j=i&511;
  dst[i]=t[i]+pos[(m&15)*512+j];
}

// attention for 16 tokens, one block per (b,h)
__global__ __launch_bounds__(256) void k_attn(const float* __restrict__ qkv, float* __restrict__ outb){
  int bh=blockIdx.x, b=bh>>3, h=bh&7, tid=threadIdx.x;
  __shared__ float q[16][64], kk[16][64], vv[16][64], pp[16][16];
  for (int i=tid;i<1024;i+=256){
    int row=i>>6, d=i&63;
    const float* src=qkv + (size_t)(b*16+row)*1536 + h*64+d;
    q[row][d]=src[0]; kk[row][d]=src[512]; vv[row][d]=src[1024];
  }
  __syncthreads();
  int i=tid>>4, j=tid&15;
  float s=0.f;
  #pragma unroll
  for (int d=0;d<64;d++) s+=q[i][d]*kk[j][d];
  s*=0.125f;
  float mx=s;
  for (int o=8;o>0;o>>=1) mx=fmaxf(mx,__shfl_xor(mx,o,16));
  float e=__expf(s-mx), sm=e;
  for (int o=8;o>0;o>>=1) sm+=__shfl_xor(sm,o,16);
  pp[i][j]=e/sm;
  __syncthreads();
  int d=tid&63;
  for (int pass=0;pass<4;pass++){
    int row=pass*4+(tid>>6);
    float acc=0.f;
    #pragma unroll
    for (int jj=0;jj<16;jj++) acc+=pp[row][jj]*vv[jj][d];
    outb[(size_t)(b*16+row)*512 + h*64+d]=acc;
  }
}

// ---------------- SS2D ----------------
__global__ __launch_bounds__(256) void k_xz(const float* __restrict__ ksp, const float* __restrict__ w,
                                            const float* __restrict__ bv, float* __restrict__ xz){
  int blk=blockIdx.x; int b=blk>>6; int p0=(blk&63)*256; int tid=threadIdx.x;
  __shared__ float lin[32][256];
  __shared__ float lw[2048];
  for (int i=tid;i<2048;i+=256) lw[i]=w[i];
  for (int i=tid;i<8192;i+=256){ int c=i>>8, p=i&255; lin[c][p]=ksp[(size_t)(b*32+c)*L_+p0+p]; }
  __syncthreads();
  float xv[32];
  #pragma unroll
  for (int c=0;c<32;c++) xv[c]=lin[c][tid];
  for (int e=0;e<64;e++){
    float a=bv[e];
    #pragma unroll
    for (int c=0;c<32;c++) a+=xv[c]*lw[c*64+e];
    xz[(size_t)(b*64+e)*L_+p0+tid]=a;
  }
}

__global__ void k_dwconv(const float* __restrict__ xz, const float* __restrict__ w,
                         const float* __restrict__ bv, float* __restrict__ xs0){
  int i=blockIdx.x*256+threadIdx.x;         // 2*32*16384
  int p=i&16383; int d=(i>>14)&31; int b=i>>19;
  int h=p>>7, ww=p&127;
  const float* src=xz+(size_t)(b*64+d)*L_;
  float acc=bv[d];
  for (int ky=0;ky<3;ky++){
    int hh=h+ky-1; if(hh<0||hh>127) continue;
    for (int kx=0;kx<3;kx++){
      int wx=ww+kx-1; if(wx<0||wx>127) continue;
      acc+=src[hh*128+wx]*w[d*9+ky*3+kx];
    }
  }
  xs0[(size_t)(b*32+d)*L_+p]=acc*sigmoidf_(acc);
}

__global__ __launch_bounds__(256) void k_transpose(const float* __restrict__ src, float* __restrict__ dst){
  __shared__ float tile[32][33];
  int z=blockIdx.z;
  int h0=blockIdx.y*32, w0=blockIdx.x*32;
  int tid=threadIdx.x, tx=tid&31, ty=tid>>5;
  const float* s=src+(size_t)z*L_;
  float* d=dst+(size_t)z*L_;
  for (int r=ty;r<32;r+=8) tile[r][tx]=s[(h0+r)*128+w0+tx];
  __syncthreads();
  for (int r=ty;r<32;r+=8) d[(w0+r)*128+h0+tx]=tile[tx][r];
}

__global__ __launch_bounds__(256) void k_dbl(const float* __restrict__ xs0, const float* __restrict__ xs0T,
                                             const float* __restrict__ xproj, float* __restrict__ dbl){
  int bk=blockIdx.y; int b=bk>>2, k=bk&3;
  int l0=blockIdx.x*256, tid=threadIdx.x;
  const float* src=(k&1)?xs0T:xs0;
  __shared__ float xv[32][256];
  __shared__ float xp[576];
  for (int i=tid;i<576;i+=256) xp[i]=xproj[k*576+i];
  for (int i=tid;i<8192;i+=256){
    int dd=i>>8, p=i&255; int l=l0+p; int li=(k<2)?l:(16383-l);
    xv[dd][p]=src[(size_t)(b*32+dd)*L_+li];
  }
  __syncthreads();
  float xr[32];
  #pragma unroll
  for (int dd=0;dd<32;dd++) xr[dd]=xv[dd][tid];
  float* out=&dbl[((size_t)(b*4+k)*L_ + l0+tid)*18];
  for (int c=0;c<18;c++){
    float a=0.f;
    #pragma unroll
    for (int dd=0;dd<32;dd++) a+=xr[dd]*xp[dd*18+c];
    out[c]=a;
  }
}

__global__ __launch_bounds__(256) void k_scan(const float* __restrict__ dbl, const float* __restrict__ xs0,
                                              const float* __restrict__ xs0T, const float* __restrict__ dtw,
                                              const float* __restrict__ dtb, const float* __restrict__ Alog,
                                              const float* __restrict__ Dp, float* __restrict__ ys){
  int id=blockIdx.x; int d=id&31, k=(id>>5)&3, b=id>>7;
  const float* src=(k&1)?xs0T:xs0;
  bool rev=(k>=2);
  const float* dbase=dbl + (size_t)(b*4+k)*L_*18;
  const float* xbase=src + (size_t)(b*32+d)*L_;
  float w0=dtw[(k*2+0)*32+d], w1=dtw[(k*2+1)*32+d], bb=dtb[k*32+d];
  float Av[8];
  #pragma unroll
  for (int s=0;s<8;s++) Av[s]=-__expf(Alog[(k*32+d)*8+s]);
  float Dv=Dp[k*32+d];
  int t=threadIdx.x, l0=t*64;
  float P[8],Q[8];
  #pragma unroll
  for (int s=0;s<8;s++){P[s]=1.f;Q[s]=0.f;}
  for (int j=0;j<64;j++){
    int l=l0+j;
    const float* e=dbase+(size_t)l*18;
    float dt=softplusf_(e[0]*w0+e[1]*w1+bb);
    float xsv=xbase[rev?(16383-l):l];
    float u=dt*xsv;
    #pragma unroll
    for (int s=0;s<8;s++){
      float a=__expf(dt*Av[s]);
      Q[s]=a*Q[s]+u*e[2+s];
      P[s]*=a;
    }
  }
  __shared__ float Ps[8][256], Qs[8][256];
  #pragma unroll
  for (int s=0;s<8;s++){Ps[s][t]=P[s];Qs[s][t]=Q[s];}
  __syncthreads();
  for (int off=1;off<256;off<<=1){
    float nP[8],nQ[8];
    if (t>=off){
      #pragma unroll
      for (int s=0;s<8;s++){
        float pP=Ps[s][t-off],pQ=Qs[s][t-off];
        nP[s]=pP*Ps[s][t];
        nQ[s]=Ps[s][t]*pQ+Qs[s][t];
      }
    }
    __syncthreads();
    if (t>=off){
      #pragma unroll
      for (int s=0;s<8;s++){Ps[s][t]=nP[s];Qs[s][t]=nQ[s];}
    }
    __syncthreads();
  }
  float hh[8];
  #pragma unroll
  for (int s=0;s<8;s++) hh[s]=(t==0)?0.f:Qs[s][t-1];
  float* yout=&ys[((size_t)(b*4+k)*32+d)*L_];
  for (int j=0;j<64;j++){
    int l=l0+j;
    const float* e=dbase+(size_t)l*18;
    float dt=softplusf_(e[0]*w0+e[1]*w1+bb);
    float xsv=xbase[rev?(16383-l):l];
    float u=dt*xsv;
    float y=0.f;
    #pragma unroll
    for (int s=0;s<8;s++){
      float a=__expf(dt*Av[s]);
      hh[s]=a*hh[s]+u*e[2+s];
      y+=hh[s]*e[10+s];
    }
    yout[l]=y+Dv*xsv;
  }
}

__global__ __launch_bounds__(256) void k_ycomb(const float* __restrict__ ys, const float* __restrict__ xz,
                                               const float* __restrict__ g, const float* __restrict__ bv,
                                               const float* __restrict__ ow, const float* __restrict__ ob,
                                               float* __restrict__ oss){
  int blk=blockIdx.x; int b=blk>>6; int p=(blk&63)*256+threadIdx.x;
  int h=p>>7, w=p&127; int lt=w*128+h;
  __shared__ float lw[640]; __shared__ float lb[20]; __shared__ float lg[32], lbv[32];
  int tid=threadIdx.x;
  for (int i=tid;i<640;i+=256) lw[i]=ow[i];
  if (tid<20) lb[tid]=ob[tid];
  if (tid<32){ lg[tid]=g[tid]; lbv[tid]=bv[tid]; }
  __syncthreads();
  size_t base=(size_t)b*4*32*L_;
  float y[32];
  float s=0.f, ss=0.f;
  #pragma unroll
  for (int d=0;d<32;d++){
    float v=ys[base+(size_t)(0*32+d)*L_+p] + ys[base+(size_t)(2*32+d)*L_+16383-p]
          + ys[base+(size_t)(1*32+d)*L_+lt] + ys[base+(size_t)(3*32+d)*L_+16383-lt];
    y[d]=v; s+=v; ss+=v*v;
  }
  float mean=s/32.f, var=ss/32.f-mean*mean, inv=1.f/sqrtf(var+1e-5f);
  #pragma unroll
  for (int d=0;d<32;d++){
    float yn=(y[d]-mean)*inv*lg[d]+lbv[d];
    float zv=xz[(size_t)(b*64+32+d)*L_+p];
    y[d]=yn*(zv*sigmoidf_(zv));
  }
  for (int c=0;c<20;c++){
    float a=lb[c];
    #pragma unroll
    for (int d=0;d<32;d++) a+=y[d]*lw[d*20+c];
    oss[(size_t)(b*20+c)*L_+p]=a;
  }
}

__global__ void k_concat(const float* __restrict__ x, const float* __restrict__ img,
                         const float* __restrict__ oss, float* __restrict__ xc){
  int i=blockIdx.x*256+threadIdx.x;       // 2*56*16384
  int p=i&16383; int ch=(i>>14)%56; int b=i/(56*16384);
  float v;
  if (ch<4) v=x[(size_t)(b*4+ch)*L_+p];
  else if (ch<36) v=img[(size_t)(b*32+ch-4)*L_+p];
  else v=oss[(size_t)(b*20+ch-36)*L_+p];
  xc[i]=v;
}

// generic SAME conv3x3, NCO output channels per block in registers
template<int NCO>
__global__ __launch_bounds__(256) void k_conv3(const float* __restrict__ in, const float* __restrict__ wt,
                                               const float* __restrict__ bs, const float* __restrict__ add,
                                               float* __restrict__ out, int Cin, int Cout, int cg_count, int act){
  int b=blockIdx.z/cg_count, cg=blockIdx.z%cg_count;
  int tid=threadIdx.x, tx=tid&15, ty=tid>>4;
  int h=blockIdx.y*16+ty, w=blockIdx.x*16+tx;
  __shared__ float tile[18][18];
  float acc[NCO];
  #pragma unroll
  for (int co=0;co<NCO;co++) acc[co]=0.f;
  for (int ci=0;ci<Cin;ci++){
    const float* src=in+(size_t)(b*Cin+ci)*L_;
    for (int i=tid;i<324;i+=256){
      int r=i/18, c=i%18;
      int gh=blockIdx.y*16+r-1, gw=blockIdx.x*16+c-1;
      tile[r][c]=(gh>=0&&gh<128&&gw>=0&&gw<128)?src[gh*128+gw]:0.f;
    }
    __syncthreads();
    float n0=tile[ty][tx],  n1=tile[ty][tx+1],  n2=tile[ty][tx+2];
    float n3=tile[ty+1][tx],n4=tile[ty+1][tx+1],n5=tile[ty+1][tx+2];
    float n6=tile[ty+2][tx],n7=tile[ty+2][tx+1],n8=tile[ty+2][tx+2];
    const float* wp=wt+((size_t)(cg*NCO)*Cin+ci)*9;
    #pragma unroll
    for (int co=0;co<NCO;co++){
      const float* wq=wp+(size_t)co*Cin*9;
      acc[co]+=n0*wq[0]+n1*wq[1]+n2*wq[2]+n3*wq[3]+n4*wq[4]+n5*wq[5]+n6*wq[6]+n7*wq[7]+n8*wq[8];
    }
    __syncthreads();
  }
  #pragma unroll
  for (int co=0;co<NCO;co++){
    int gco=cg*NCO+co;
    float v=acc[co]+bs[gco];
    if (add) v+=add[(size_t)(b*Cout+gco)*L_+h*128+w];
    if (act) v=v>0.f?v:0.2f*v;
    out[(size_t)(b*Cout+gco)*L_+h*128+w]=v;
  }
}

// ---------------- FFT data consistency ----------------
__device__ __forceinline__ int rev7(int x){
  return ((x&1)<<6)|((x&2)<<4)|((x&4)<<2)|(x&8)|((x&16)>>2)|((x&32)>>4)|((x&64)>>6);
}

__global__ __launch_bounds__(256) void k_fft_dc(const float* __restrict__ x_ri, const float* __restrict__ sens,
                                                const float* __restrict__ ksp, const float* __restrict__ mask,
                                                const float* __restrict__ alpha_p, float* __restrict__ acc){
  int blk=blockIdx.x; int b=blk>>4, coil=blk&15;
  __shared__ float Sr[16384];
  __shared__ float Si[16384];
  __shared__ float twr[64], twi[64];
  int tid=threadIdx.x;
  if (tid<64){ float ang=-2.f*PI_F*(float)tid/128.f; twr[tid]=cosf(ang); twi[tid]=sinf(ang); }
  const float* srp=sens+(size_t)(b*32+2*coil)*L_;
  const float* sip=sens+(size_t)(b*32+2*coil+1)*L_;
  const float* xrp=x_ri+(size_t)(b*2)*L_;
  const float* xip=xrp+L_;
  for (int i=tid;i<16384;i+=256){
    int h=i>>7,w=i&127;
    float sg=((h+w)&1)?-1.f:1.f;
    float sr=srp[i],si=sip[i],xr=xrp[i],xi=xip[i];
    Sr[i]=sg*(sr*xr-si*xi);
    Si[i]=sg*(sr*xi+si*xr);
  }
  __syncthreads();
  for (int s=0;s<7;s++){
    int m=64>>s;
    for (int q=tid;q<8192;q+=256){
      int row=q>>6, jj=q&63;
      int j=jj&(m-1), gg=jj>>(6-s);
      int kpos=(gg<<(7-s))+j;
      int i0=row*128+kpos, i1=i0+m;
      int tw=j<<s;
      float ur=Sr[i0],ui=Si[i0],vr=Sr[i1],vi=Si[i1];
      Sr[i0]=ur+vr; Si[i0]=ui+vi;
      float dr=ur-vr,di=ui-vi,wr=twr[tw],wi=twi[tw];
      Sr[i1]=dr*wr-di*wi; Si[i1]=dr*wi+di*wr;
    }
    __syncthreads();
  }
  for (int s=0;s<7;s++){
    int m=64>>s;
    for (int q=tid;q<8192;q+=256){
      int cpos=q&127, jj=q>>7;
      int j=jj&(m-1), gg=jj>>(6-s);
      int kpos=(gg<<(7-s))+j;
      int i0=kpos*128+cpos, i1=i0+m*128;
      int tw=j<<s;
      float ur=Sr[i0],ui=Si[i0],vr=Sr[i1],vi=Si[i1];
      Sr[i0]=ur+vr; Si[i0]=ui+vi;
      float dr=ur-vr,di=ui-vi,wr=twr[tw],wi=twi[tw];
      Sr[i1]=dr*wr-di*wi; Si[i1]=dr*wi+di*wr;
    }
    __syncthreads();
  }
  float alpha=alpha_p[0];
  const float* krp=ksp+(size_t)(b*32+2*coil)*L_;
  const float* kip=ksp+(size_t)(b*32+2*coil+1)*L_;
  const float* mkp=mask+(size_t)b*L_;
  for (int i=tid;i<16384;i+=256){
    int i1=i>>7, i2=i&127;
    int k1=rev7(i1), k2=rev7(i2);
    int kidx=k1*128+k2;
    float mv=mkp[kidx]*alpha;
    float sg=((k1+k2)&1)?-128.f:128.f;
    float kr=krp[kidx]*100.f*sg, ki=kip[kidx]*100.f*sg;
    Sr[i]=(1.f-mv)*Sr[i]+mv*kr;
    Si[i]=(1.f-mv)*Si[i]+mv*ki;
  }
  __syncthreads();
  for (int s=0;s<7;s++){
    int m=1<<s;
    for (int q=tid;q<8192;q+=256){
      int cpos=q&127, jj=q>>7;
      int j=jj&(m-1), gg=jj>>s;
      int kpos=(gg<<(s+1))+j;
      int i0=kpos*128+cpos, i1=i0+m*128;
      int tw=j<<(6-s);
      float wr=twr[tw], wi=-twi[tw];
      float vr=Sr[i1],vi=Si[i1];
      float tr=vr*wr-vi*wi, ti=vr*wi+vi*wr;
      float ur=Sr[i0],ui=Si[i0];
      Sr[i0]=ur+tr; Si[i0]=ui+ti;
      Sr[i1]=ur-tr; Si[i1]=ui-ti;
    }
    __syncthreads();
  }
  for (int s=0;s<7;s++){
    int m=1<<s;
    for (int q=tid;q<8192;q+=256){
      int row=q>>6, jj=q&63;
      int j=jj&(m-1), gg=jj>>s;
      int kpos=(gg<<(s+1))+j;
      int i0=row*128+kpos, i1=i0+m;
      int tw=j<<(6-s);
      float wr=twr[tw], wi=-twi[tw];
      float vr=Sr[i1],vi=Si[i1];
      float tr=vr*wr-vi*wi, ti=vr*wi+vi*wr;
      float ur=Sr[i0],ui=Si[i0];
      Sr[i0]=ur+tr; Si[i0]=ui+ti;
      Sr[i1]=ur-tr; Si[i1]=ui-ti;
    }
    __syncthreads();
  }
  float* accr=acc+(size_t)(b*2)*L_;
  float* acci=accr+L_;
  for (int i=tid;i<16384;i+=256){
    int h=i>>7,w=i&127;
    float sc=(((h+w)&1)?-1.f:1.f)*(1.f/16384.f);
    float wr2=Sr[i]*sc, wi2=Si[i]*sc;
    float sr=srp[i], si=sip[i];
    atomicAdd(&accr[i], sr*wr2+si*wi2);
    atomicAdd(&acci[i], sr*wi2-si*wr2);
  }
}

__global__ void k_mag(const float* __restrict__ acc, float* __restrict__ out){
  int i=blockIdx.x*256+threadIdx.x;   // 32768
  int b=i>>14, p=i&16383;
  float re=acc[(size_t)(b*2)*L_+p], im=acc[(size_t)(b*2+1)*L_+p];
  out[i]=sqrtf(re*re+im*im+1e-12f);
}

extern "C" void kernel_launch(void* const* d_in, const int* in_sizes, int n_in,
                              void* d_out, int out_size, void* d_ws, size_t ws_size,
                              hipStream_t stream){
  const float* in_imgs=(const float*)d_in[0];
  const float* in_ksp=(const float*)d_in[1];
  const float* mask=(const float*)d_in[2];
  const float* sens=(const float*)d_in[3];
  const float* pe_ln1_g=(const float*)d_in[4];
  const float* pe_ln1_b=(const float*)d_in[5];
  const float* pe_w=(const float*)d_in[6];
  const float* pe_b=(const float*)d_in[7];
  const float* pe_ln2_g=(const float*)d_in[8];
  const float* pe_ln2_b=(const float*)d_in[9];
  const float* pos_emb=(const float*)d_in[10];
  const float* enc_aln_g=(const float*)d_in[11];
  const float* enc_aln_b=(const float*)d_in[12];
  const float* enc_wqkv=(const float*)d_in[13];
  const float* enc_wo=(const float*)d_in[14];
  const float* enc_bo=(const float*)d_in[15];
  const float* enc_fln_g=(const float*)d_in[16];
  const float* enc_fln_b=(const float*)d_in[17];
  const float* enc_w1=(const float*)d_in[18];
  const float* enc_b1=(const float*)d_in[19];
  const float* enc_w2=(const float*)d_in[20];
  const float* enc_b2=(const float*)d_in[21];
  const float* enc_ng=(const float*)d_in[22];
  const float* enc_nb=(const float*)d_in[23];
  const float* dec_pos=(const float*)d_in[24];
  const float* dec_aln_g=(const float*)d_in[25];
  const float* dec_aln_b=(const float*)d_in[26];
  const float* dec_wqkv=(const float*)d_in[27];
  const float* dec_wo=(const float*)d_in[28];
  const float* dec_bo=(const float*)d_in[29];
  const float* dec_fln_g=(const float*)d_in[30];
  const float* dec_fln_b=(const float*)d_in[31];
  const float* dec_w1=(const float*)d_in[32];
  const float* dec_b1=(const float*)d_in[33];
  const float* dec_w2=(const float*)d_in[34];
  const float* dec_b2=(const float*)d_in[35];
  const float* dec_ng=(const float*)d_in[36];
  const float* dec_nb=(const float*)d_in[37];
  const float* fin_w=(const float*)d_in[38];
  const float* fin_b=(const float*)d_in[39];
  const float* ss_in_w=(const float*)d_in[40];
  const float* ss_in_b=(const float*)d_in[41];
  const float* ss_conv_w=(const float*)d_in[42];
  const float* ss_conv_b=(const float*)d_in[43];
  const float* ss_xproj=(const float*)d_in[44];
  const float* ss_dt_w=(const float*)d_in[45];
  const float* ss_dt_b=(const float*)d_in[46];
  const float* ss_Alog=(const float*)d_in[47];
  const float* ss_D=(const float*)d_in[48];
  const float* ss_ln_g=(const float*)d_in[49];
  const float* ss_ln_b=(const float*)d_in[50];
  const float* ss_out_w=(const float*)d_in[51];
  const float* ss_out_b=(const float*)d_in[52];
  const float* head_w=(const float*)d_in[53];
  const float* head_b=(const float*)d_in[54];
  const float* res_w1=(const float*)d_in[55];
  const float* res_b1=(const float*)d_in[56];
  const float* res_w2=(const float*)d_in[57];
  const float* res_b2=(const float*)d_in[58];
  const float* tail_w=(const float*)d_in[59];
  const float* tail_b=(const float*)d_in[60];
  const float* dc_alpha=(const float*)d_in[61];

  char* ws=(char*)d_ws;
  size_t off=0;
  auto alloc=[&](size_t nfloats)->float*{ float* p=(float*)(ws+off); off+=((nfloats*4+255)/256)*256; return p; };
  float* xn   =alloc((size_t)32*32768);
  float* tA   =alloc(32*512);
  float* tB   =alloc(32*512);
  float* aln  =alloc(32*512);
  float* qkv  =alloc(32*1536);
  float* attno=alloc(32*512);
  float* ffh  =alloc(32*3072);
  float* xup  =alloc((size_t)2*4*L_);
  float* xz   =alloc((size_t)2*64*L_);
  float* xs0  =alloc((size_t)2*32*L_);
  float* xs0T =alloc((size_t)2*32*L_);
  float* dbl  =alloc((size_t)2*4*L_*18);
  float* ys   =alloc((size_t)2*4*32*L_);
  float* oss  =alloc((size_t)2*20*L_);
  float* xc   =alloc((size_t)2*56*L_);
  float* h0   =alloc((size_t)2*64*L_);
  float* tmpc =alloc((size_t)2*64*L_);
  float* x_ri =alloc((size_t)2*2*L_);
  float* accb =alloc((size_t)2*2*L_);
  (void)ws_size; (void)in_sizes; (void)n_in; (void)out_size;

  // ---- patch embed + encoder/decoder ----
  k_ln_pe<<<32,256,0,stream>>>(in_imgs, pe_ln1_g, pe_ln1_b, xn);
  hipMemsetAsync(tA, 0, 32*512*4, stream);
  k_gemm_sk<256,0><<<dim3(8,128),256,0,stream>>>(xn, pe_w, pe_b, tA, 512, 32768);
  k_pe_post<<<32,256,0,stream>>>(tA, pe_ln2_g, pe_ln2_b, pos_emb);

  for (int i=0;i<4;i++){
    k_ln_tok<<<32,256,0,stream>>>(tA, enc_aln_g+i*512, enc_aln_b+i*512, aln);
    hipMemsetAsync(qkv, 0, 32*1536*4, stream);
    k_gemm_sk<64,0><<<dim3(24,8),256,0,stream>>>(aln, enc_wqkv+(size_t)i*512*1536, nullptr, qkv, 1536, 512);
    k_attn<<<16,256,0,stream>>>(qkv, attno);
    k_gemm_sk<64,0><<<dim3(8,8),256,0,stream>>>(attno, enc_wo+(size_t)i*512*512, enc_bo+i*512, tA, 512, 512);
    k_ln_tok<<<32,256,0,stream>>>(tA, enc_fln_g+i*512, enc_fln_b+i*512, aln);
    hipMemsetAsync(ffh, 0, 32*2048*4, stream);
    k_gemm_sk<64,0><<<dim3(32,8),256,0,stream>>>(aln, enc_w1+(size_t)i*512*2048, enc_b1+i*2048, ffh, 2048, 512);
    k_gemm_sk<64,1><<<dim3(8,32),256,0,stream>>>(ffh, enc_w2+(size_t)i*2048*512, enc_b2+i*512, tA, 512, 2048);
  }
  k_ln_tok<<<32,256,0,stream>>>(tA, enc_ng, enc_nb, tA);
  k_addpos<<<64,256,0,stream>>>(tA, dec_pos, tB);
  k_ln_tok<<<32,256,0,stream>>>(tB, dec_aln_g, dec_aln_b, aln);
  hipMemsetAsync(qkv, 0, 32*1536*4, stream);
  k_gemm_sk<64,0><<<dim3(24,8),256,0,stream>>>(aln, dec_wqkv, nullptr, qkv, 1536, 512);
  k_attn<<<16,256,0,stream>>>(qkv, attno);
  k_gemm_sk<64,0><<<dim3(8,8),256,0,stream>>>(attno, dec_wo, dec_bo, tB, 512, 512);
  k_ln_tok<<<32,256,0,stream>>>(tB, dec_fln_g, dec_fln_b, aln);
  hipMemsetAsync(ffh, 0, 32*3072*4, stream);
  k_gemm_sk<64,0><<<dim3(48,8),256,0,stream>>>(aln, dec_w1, dec_b1, ffh, 3072, 512);
  k_gemm_sk<64,1><<<dim3(8,48),256,0,stream>>>(ffh, dec_w2, dec_b2, tB, 512, 3072);
  k_ln_tok<<<32,256,0,stream>>>(tB, dec_ng, dec_nb, tB);
  hipMemsetAsync(xup, 0, (size_t)2*4*L_*4, stream);
  k_gemm_sk<64,2><<<dim3(64,8),256,0,stream>>>(tB, fin_w, fin_b, xup, 4096, 512);

  // ---- SS2D ----
  k_xz<<<128,256,0,stream>>>(in_ksp, ss_in_w, ss_in_b, xz);
  k_dwconv<<<4096,256,0,stream>>>(xz, ss_conv_w, ss_conv_b, xs0);
  k_transpose<<<dim3(4,4,64),256,0,stream>>>(xs0, xs0T);
  k_dbl<<<dim3(64,8),256,0,stream>>>(xs0, xs0T, ss_xproj, dbl);
  k_scan<<<256,256,0,stream>>>(dbl, xs0, xs0T, ss_dt_w, ss_dt_b, ss_Alog, ss_D, ys);
  k_ycomb<<<128,256,0,stream>>>(ys, xz, ss_ln_g, ss_ln_b, ss_out_w, ss_out_b, oss);

  // ---- conv head ----
  k_concat<<<7168,256,0,stream>>>(xup, in_imgs, oss, xc);
  k_conv3<32><<<dim3(8,8,4),256,0,stream>>>(xc, head_w, head_b, nullptr, h0, 56, 64, 2, 1);
  for (int i=0;i<3;i++){
    k_conv3<32><<<dim3(8,8,4),256,0,stream>>>(h0, res_w1+(size_t)i*64*64*9, res_b1+i*64, nullptr, tmpc, 64, 64, 2, 1);
    k_conv3<32><<<dim3(8,8,4),256,0,stream>>>(tmpc, res_w2+(size_t)i*64*64*9, res_b2+i*64, h0, h0, 64, 64, 2, 1);
  }
  k_conv3<2><<<dim3(8,8,2),256,0,stream>>>(h0, tail_w, tail_b, nullptr, x_ri, 64, 2, 1, 0);

  // ---- FFT data consistency ----
  hipMemsetAsync(accb, 0, (size_t)2*2*L_*4, stream);
  k_fft_dc<<<32,256,0,stream>>>(x_ri, sens, in_ksp, mask, dc_alpha, accb);
  k_mag<<<128,256,0,stream>>>(accb, (float*)d_out);
}

// Round 4
// 1841.130 us; speedup vs baseline: 3.2795x; 1.6656x over previous
//
#include <hip/hip_runtime.h>

#define PI_F 3.14159265358979323846f

constexpr int L_ = 16384;   // H*W
constexpr int PD_ = 32768;  // P*P*C

__device__ __forceinline__ float sigmoidf_(float x){ return 1.f/(1.f+__expf(-x)); }
__device__ __forceinline__ float softplusf_(float x){ return x>20.f ? x : log1pf(__expf(x)); }
__device__ __forceinline__ float geluf_(float x){ return 0.5f*x*(1.f+erff(x*0.70710678118654752f)); }

__device__ __forceinline__ float2 block_reduce2(float s, float ss){
  __shared__ float r1[256], r2[256];
  int tid = threadIdx.x;
  r1[tid]=s; r2[tid]=ss; __syncthreads();
  for(int o=128;o>0;o>>=1){ if(tid<o){ r1[tid]+=r1[tid+o]; r2[tid]+=r2[tid+o]; } __syncthreads(); }
  float2 out; out.x=r1[0]; out.y=r2[0]; __syncthreads();
  return out;
}

// ---------------- patch embed ----------------
__global__ __launch_bounds__(256) void k_ln_pe(const float* __restrict__ img, const float* __restrict__ g,
                                               const float* __restrict__ bv, float* __restrict__ xn){
  int m = blockIdx.x; int b = m>>4, n = m&15, ih = n>>2, iw = n&3;
  int tid = threadIdx.x;
  const float* base = img + (size_t)b*32*L_;
  float s=0.f, ss=0.f;
  for (int j=tid; j<PD_; j+=256){
    int c=j>>10, p1=(j>>5)&31, p2=j&31;
    float v = base[(size_t)c*L_ + (ih*32+p1)*128 + iw*32+p2];
    s+=v; ss+=v*v;
  }
  float2 r = block_reduce2(s,ss);
  float mean = r.x/(float)PD_;
  float var  = r.y/(float)PD_ - mean*mean;
  float inv = 1.f/sqrtf(var+1e-5f);
  for (int j=tid; j<PD_; j+=256){
    int c=j>>10, p1=(j>>5)&31, p2=j&31;
    float v = base[(size_t)c*L_ + (ih*32+p1)*128 + iw*32+p2];
    int k = (p1*32+p2)*32 + c;
    xn[(size_t)m*PD_ + k] = (v-mean)*inv*g[k] + bv[k];
  }
}

// split-K skinny GEMM: C[32][N] += A[32][K]@B[K][N]; bias added by blockIdx.y==0 blocks.
// MODE 0: plain; 1: gelu applied to A on load; 2: scatter-store to NCHW x-upsample layout.
template<int KC, int MODE>
__global__ __launch_bounds__(256) void k_gemm_sk(const float* __restrict__ A, const float* __restrict__ Bw,
                                                 const float* __restrict__ bias, float* __restrict__ C,
                                                 int N, int K){
  __shared__ float As[32][KC];
  int tid=threadIdx.x, tx=tid&63, ty=tid>>6;
  int n = blockIdx.x*64+tx;
  int k0 = blockIdx.y*KC;
  for (int i=tid;i<32*KC;i+=256){
    int r=i/KC, c=i%KC;
    float v=A[(size_t)r*K + k0 + c];
    if (MODE==1) v=geluf_(v);
    As[r][c]=v;
  }
  __syncthreads();
  float acc[8]={0,0,0,0,0,0,0,0};
  for (int kk=0;kk<KC;kk+=4){
    float b0=Bw[(size_t)(k0+kk)*N+n],   b1=Bw[(size_t)(k0+kk+1)*N+n];
    float b2=Bw[(size_t)(k0+kk+2)*N+n], b3=Bw[(size_t)(k0+kk+3)*N+n];
    #pragma unroll
    for (int r=0;r<8;r++){
      const float4 a=*(const float4*)&As[ty*8+r][kk];
      acc[r]+=a.x*b0+a.y*b1+a.z*b2+a.w*b3;
    }
  }
  bool addb = (bias!=nullptr) && (blockIdx.y==0);
  #pragma unroll
  for (int r=0;r<8;r++){
    int m=ty*8+r;
    float v=acc[r]+(addb?bias[n]:0.f);
    if (MODE==2){
      int b=m>>4, ih=(m>>2)&3, iw=m&3;
      int cu=n>>10, f1=(n>>5)&31, f2=n&31;
      atomicAdd(&C[((size_t)(b*4+cu)*128+ih*32+f1)*128+iw*32+f2], v);
    } else {
      atomicAdd(&C[(size_t)m*N+n], v);
    }
  }
}

// t = LN(t)*g + b + pos_emb
__global__ __launch_bounds__(256) void k_pe_post(float* __restrict__ t,
                                                 const float* __restrict__ g, const float* __restrict__ bv,
                                                 const float* __restrict__ pos){
  int m=blockIdx.x, tid=threadIdx.x;
  float v0 = t[m*512+tid];
  float v1 = t[m*512+256+tid];
  float2 r = block_reduce2(v0+v1, v0*v0+v1*v1);
  float mean=r.x/512.f, var=r.y/512.f-mean*mean, inv=1.f/sqrtf(var+1e-5f);
  int n = m&15;
  t[m*512+tid]     = (v0-mean)*inv*g[tid]+bv[tid]         + pos[n*512+tid];
  t[m*512+256+tid] = (v1-mean)*inv*g[256+tid]+bv[256+tid] + pos[n*512+256+tid];
}

__global__ __launch_bounds__(256) void k_ln_tok(const float* __restrict__ src, const float* __restrict__ g,
                                                const float* __restrict__ bv, float* __restrict__ dst){
  int m=blockIdx.x, tid=threadIdx.x;
  float v0=src[m*512+tid], v1=src[m*512+256+tid];
  float2 r=block_reduce2(v0+v1, v0*v0+v1*v1);
  float mean=r.x/512.f, var=r.y/512.f-mean*mean, inv=1.f/sqrtf(var+1e-5f);
  dst[m*512+tid]     =(v0-mean)*inv*g[tid]+bv[tid];
  dst[m*512+256+tid] =(v1-mean)*inv*g[256+tid]+bv[256+tid];
}

__global__ void k_addpos(const float* __restrict__ t, const float* __restrict__ pos, float* __restrict__ dst){
  int i = blockIdx.x*256+threadIdx.x;   // 16384
  int m=i>>9, j=i&511;
  dst[i]=t[i]+pos[(m&15)*512+j];
}

// attention for 16 tokens, one block per (b,h)
__global__ __launch_bounds__(256) void k_attn(const float* __restrict__ qkv, float* __restrict__ outb){
  int bh=blockIdx.x, b=bh>>3, h=bh&7, tid=threadIdx.x;
  __shared__ float q[16][64], kk[16][64], vv[16][64], pp[16][16];
  for (int i=tid;i<1024;i+=256){
    int row=i>>6, d=i&63;
    const float* src=qkv + (size_t)(b*16+row)*1536 + h*64+d;
    q[row][d]=src[0]; kk[row][d]=src[512]; vv[row][d]=src[1024];
  }
  __syncthreads();
  int i=tid>>4, j=tid&15;
  float s=0.f;
  #pragma unroll
  for (int d=0;d<64;d++) s+=q[i][d]*kk[j][d];
  s*=0.125f;
  float mx=s;
  for (int o=8;o>0;o>>=1) mx=fmaxf(mx,__shfl_xor(mx,o,16));
  float e=__expf(s-mx), sm=e;
  for (int o=8;o>0;o>>=1) sm+=__shfl_xor(sm,o,16);
  pp[i][j]=e/sm;
  __syncthreads();
  int d=tid&63;
  for (int pass=0;pass<4;pass++){
    int row=pass*4+(tid>>6);
    float acc=0.f;
    #pragma unroll
    for (int jj=0;jj<16;jj++) acc+=pp[row][jj]*vv[jj][d];
    outb[(size_t)(b*16+row)*512 + h*64+d]=acc;
  }
}

// ---------------- SS2D ----------------
__global__ __launch_bounds__(256) void k_xz(const float* __restrict__ ksp, const float* __restrict__ w,
                                            const float* __restrict__ bv, float* __restrict__ xz){
  int blk=blockIdx.x; int b=blk>>6; int p0=(blk&63)*256; int tid=threadIdx.x;
  __shared__ float lin[32][256];
  __shared__ float lw[2048];
  for (int i=tid;i<2048;i+=256) lw[i]=w[i];
  for (int i=tid;i<8192;i+=256){ int c=i>>8, p=i&255; lin[c][p]=ksp[(size_t)(b*32+c)*L_+p0+p]; }
  __syncthreads();
  float xv[32];
  #pragma unroll
  for (int c=0;c<32;c++) xv[c]=lin[c][tid];
  for (int e=0;e<64;e++){
    float a=bv[e];
    #pragma unroll
    for (int c=0;c<32;c++) a+=xv[c]*lw[c*64+e];
    xz[(size_t)(b*64+e)*L_+p0+tid]=a;
  }
}

__global__ void k_dwconv(const float* __restrict__ xz, const float* __restrict__ w,
                         const float* __restrict__ bv, float* __restrict__ xs0){
  int i=blockIdx.x*256+threadIdx.x;         // 2*32*16384
  int p=i&16383; int d=(i>>14)&31; int b=i>>19;
  int h=p>>7, ww=p&127;
  const float* src=xz+(size_t)(b*64+d)*L_;
  float acc=bv[d];
  for (int ky=0;ky<3;ky++){
    int hh=h+ky-1; if(hh<0||hh>127) continue;
    for (int kx=0;kx<3;kx++){
      int wx=ww+kx-1; if(wx<0||wx>127) continue;
      acc+=src[hh*128+wx]*w[d*9+ky*3+kx];
    }
  }
  xs0[(size_t)(b*32+d)*L_+p]=acc*sigmoidf_(acc);
}

__global__ __launch_bounds__(256) void k_transpose(const float* __restrict__ src, float* __restrict__ dst){
  __shared__ float tile[32][33];
  int z=blockIdx.z;
  int h0=blockIdx.y*32, w0=blockIdx.x*32;
  int tid=threadIdx.x, tx=tid&31, ty=tid>>5;
  const float* s=src+(size_t)z*L_;
  float* d=dst+(size_t)z*L_;
  for (int r=ty;r<32;r+=8) tile[r][tx]=s[(h0+r)*128+w0+tx];
  __syncthreads();
  for (int r=ty;r<32;r+=8) d[(w0+r)*128+h0+tx]=tile[tx][r];
}

__global__ __launch_bounds__(256) void k_dbl(const float* __restrict__ xs0, const float* __restrict__ xs0T,
                                             const float* __restrict__ xproj, float* __restrict__ dbl){
  int bk=blockIdx.y; int b=bk>>2, k=bk&3;
  int l0=blockIdx.x*256, tid=threadIdx.x;
  const float* src=(k&1)?xs0T:xs0;
  __shared__ float xv[32][256];
  __shared__ float xp[576];
  for (int i=tid;i<576;i+=256) xp[i]=xproj[k*576+i];
  for (int i=tid;i<8192;i+=256){
    int dd=i>>8, p=i&255; int l=l0+p; int li=(k<2)?l:(16383-l);
    xv[dd][p]=src[(size_t)(b*32+dd)*L_+li];
  }
  __syncthreads();
  float xr[32];
  #pragma unroll
  for (int dd=0;dd<32;dd++) xr[dd]=xv[dd][tid];
  float* out=&dbl[((size_t)(b*4+k)*L_ + l0+tid)*18];
  for (int c=0;c<18;c++){
    float a=0.f;
    #pragma unroll
    for (int dd=0;dd<32;dd++) a+=xr[dd]*xp[dd*18+c];
    out[c]=a;
  }
}

__global__ __launch_bounds__(256) void k_scan(const float* __restrict__ dbl, const float* __restrict__ xs0,
                                              const float* __restrict__ xs0T, const float* __restrict__ dtw,
                                              const float* __restrict__ dtb, const float* __restrict__ Alog,
                                              const float* __restrict__ Dp, float* __restrict__ ys){
  int id=blockIdx.x; int d=id&31, k=(id>>5)&3, b=id>>7;
  const float* src=(k&1)?xs0T:xs0;
  bool rev=(k>=2);
  const float* dbase=dbl + (size_t)(b*4+k)*L_*18;
  const float* xbase=src + (size_t)(b*32+d)*L_;
  float w0=dtw[(k*2+0)*32+d], w1=dtw[(k*2+1)*32+d], bb=dtb[k*32+d];
  float Av[8];
  #pragma unroll
  for (int s=0;s<8;s++) Av[s]=-__expf(Alog[(k*32+d)*8+s]);
  float Dv=Dp[k*32+d];
  int t=threadIdx.x, l0=t*64;
  float P[8],Q[8];
  #pragma unroll
  for (int s=0;s<8;s++){P[s]=1.f;Q[s]=0.f;}
  for (int j=0;j<64;j++){
    int l=l0+j;
    const float* e=dbase+(size_t)l*18;
    float dt=softplusf_(e[0]*w0+e[1]*w1+bb);
    float xsv=xbase[rev?(16383-l):l];
    float u=dt*xsv;
    #pragma unroll
    for (int s=0;s<8;s++){
      float a=__expf(dt*Av[s]);
      Q[s]=a*Q[s]+u*e[2+s];
      P[s]*=a;
    }
  }
  __shared__ float Ps[8][256], Qs[8][256];
  #pragma unroll
  for (int s=0;s<8;s++){Ps[s][t]=P[s];Qs[s][t]=Q[s];}
  __syncthreads();
  for (int off=1;off<256;off<<=1){
    float nP[8],nQ[8];
    if (t>=off){
      #pragma unroll
      for (int s=0;s<8;s++){
        float pP=Ps[s][t-off],pQ=Qs[s][t-off];
        nP[s]=pP*Ps[s][t];
        nQ[s]=Ps[s][t]*pQ+Qs[s][t];
      }
    }
    __syncthreads();
    if (t>=off){
      #pragma unroll
      for (int s=0;s<8;s++){Ps[s][t]=nP[s];Qs[s][t]=nQ[s];}
    }
    __syncthreads();
  }
  float hh[8];
  #pragma unroll
  for (int s=0;s<8;s++) hh[s]=(t==0)?0.f:Qs[s][t-1];
  float* yout=&ys[((size_t)(b*4+k)*32+d)*L_];
  for (int j=0;j<64;j++){
    int l=l0+j;
    const float* e=dbase+(size_t)l*18;
    float dt=softplusf_(e[0]*w0+e[1]*w1+bb);
    float xsv=xbase[rev?(16383-l):l];
    float u=dt*xsv;
    float y=0.f;
    #pragma unroll
    for (int s=0;s<8;s++){
      float a=__expf(dt*Av[s]);
      hh[s]=a*hh[s]+u*e[2+s];
      y+=hh[s]*e[10+s];
    }
    yout[l]=y+Dv*xsv;
  }
}

__global__ __launch_bounds__(256) void k_ycomb(const float* __restrict__ ys, const float* __restrict__ xz,
                                               const float* __restrict__ g, const float* __restrict__ bv,
                                               const float* __restrict__ ow, const float* __restrict__ ob,
                                               float* __restrict__ oss){
  int blk=blockIdx.x; int b=blk>>6; int p=(blk&63)*256+threadIdx.x;
  int h=p>>7, w=p&127; int lt=w*128+h;
  __shared__ float lw[640]; __shared__ float lb[20]; __shared__ float lg[32], lbv[32];
  int tid=threadIdx.x;
  for (int i=tid;i<640;i+=256) lw[i]=ow[i];
  if (tid<20) lb[tid]=ob[tid];
  if (tid<32){ lg[tid]=g[tid]; lbv[tid]=bv[tid]; }
  __syncthreads();
  size_t base=(size_t)b*4*32*L_;
  float y[32];
  float s=0.f, ss=0.f;
  #pragma unroll
  for (int d=0;d<32;d++){
    float v=ys[base+(size_t)(0*32+d)*L_+p] + ys[base+(size_t)(2*32+d)*L_+16383-p]
          + ys[base+(size_t)(1*32+d)*L_+lt] + ys[base+(size_t)(3*32+d)*L_+16383-lt];
    y[d]=v; s+=v; ss+=v*v;
  }
  float mean=s/32.f, var=ss/32.f-mean*mean, inv=1.f/sqrtf(var+1e-5f);
  #pragma unroll
  for (int d=0;d<32;d++){
    float yn=(y[d]-mean)*inv*lg[d]+lbv[d];
    float zv=xz[(size_t)(b*64+32+d)*L_+p];
    y[d]=yn*(zv*sigmoidf_(zv));
  }
  for (int c=0;c<20;c++){
    float a=lb[c];
    #pragma unroll
    for (int d=0;d<32;d++) a+=y[d]*lw[d*20+c];
    oss[(size_t)(b*20+c)*L_+p]=a;
  }
}

__global__ void k_concat(const float* __restrict__ x, const float* __restrict__ img,
                         const float* __restrict__ oss, float* __restrict__ xc){
  int i=blockIdx.x*256+threadIdx.x;       // 2*56*16384
  int p=i&16383; int ch=(i>>14)%56; int b=i/(56*16384);
  float v;
  if (ch<4) v=x[(size_t)(b*4+ch)*L_+p];
  else if (ch<36) v=img[(size_t)(b*32+ch-4)*L_+p];
  else v=oss[(size_t)(b*20+ch-36)*L_+p];
  xc[i]=v;
}

// ---- fast conv3x3: split-Cin, LDS weights, 32x32 tile, 2x2 px/thread ----
// grid: x=16 spatial tiles(4x4), y=Cout/NCO channel groups, z=b*2+ks
// scratch sc layout: [ks][b][co][128][128]
template<int NCO>
__global__ __launch_bounds__(256) void k_conv3s(const float* __restrict__ in, const float* __restrict__ wt,
                                                float* __restrict__ sc, int Cin, int Cout, int CIS){
  int tile=blockIdx.x; int th0=(tile>>2)*32, tw0=(tile&3)*32;
  int cg=blockIdx.y;
  int bz=blockIdx.z; int b=bz>>1, ks=bz&1;
  int cibase=ks*CIS;
  int cic=Cin-cibase; if (cic>CIS) cic=CIS;
  __shared__ float wlds[32][NCO][9];
  __shared__ float ibuf[2][34][34];
  int tid=threadIdx.x;
  for (int i=tid;i<cic*NCO*9;i+=256){
    int ci=i/(NCO*9), rem=i%(NCO*9), co=rem/9, q=rem%9;
    wlds[ci][co][q]=wt[(((size_t)(cg*NCO+co))*Cin + cibase+ci)*9+q];
  }
  auto stage=[&](int buf, int ci){
    const float* src=in+((size_t)b*Cin+cibase+ci)*L_;
    for (int i=tid;i<34*34;i+=256){
      int r=i/34, c=i%34;
      int gh=th0+r-1, gw=tw0+c-1;
      ibuf[buf][r][c]=(gh>=0&&gh<128&&gw>=0&&gw<128)?src[gh*128+gw]:0.f;
    }
  };
  stage(0,0);
  __syncthreads();
  float acc[NCO][4];
  #pragma unroll
  for (int co=0;co<NCO;co++){acc[co][0]=0.f;acc[co][1]=0.f;acc[co][2]=0.f;acc[co][3]=0.f;}
  int tr=((tid>>4)&15)<<1, tc=(tid&15)<<1;
  for (int ci=0;ci<cic;ci++){
    int cur=ci&1;
    if (ci+1<cic) stage(cur^1, ci+1);
    float iv[4][4];
    #pragma unroll
    for (int dr=0;dr<4;dr++)
      #pragma unroll
      for (int dc=0;dc<4;dc++) iv[dr][dc]=ibuf[cur][tr+dr][tc+dc];
    #pragma unroll
    for (int co=0;co<NCO;co++){
      float w0=wlds[ci][co][0],w1=wlds[ci][co][1],w2=wlds[ci][co][2];
      float w3=wlds[ci][co][3],w4=wlds[ci][co][4],w5=wlds[ci][co][5];
      float w6=wlds[ci][co][6],w7=wlds[ci][co][7],w8=wlds[ci][co][8];
      acc[co][0]+=iv[0][0]*w0+iv[0][1]*w1+iv[0][2]*w2
                 +iv[1][0]*w3+iv[1][1]*w4+iv[1][2]*w5
                 +iv[2][0]*w6+iv[2][1]*w7+iv[2][2]*w8;
      acc[co][1]+=iv[0][1]*w0+iv[0][2]*w1+iv[0][3]*w2
                 +iv[1][1]*w3+iv[1][2]*w4+iv[1][3]*w5
                 +iv[2][1]*w6+iv[2][2]*w7+iv[2][3]*w8;
      acc[co][2]+=iv[1][0]*w0+iv[1][1]*w1+iv[1][2]*w2
                 +iv[2][0]*w3+iv[2][1]*w4+iv[2][2]*w5
                 +iv[3][0]*w6+iv[3][1]*w7+iv[3][2]*w8;
      acc[co][3]+=iv[1][1]*w0+iv[1][2]*w1+iv[1][3]*w2
                 +iv[2][1]*w3+iv[2][2]*w4+iv[2][3]*w5
                 +iv[3][1]*w6+iv[3][2]*w7+iv[3][3]*w8;
    }
    __syncthreads();
  }
  #pragma unroll
  for (int co=0;co<NCO;co++){
    int gco=cg*NCO+co;
    float* dst=sc+((size_t)((ks*2+b)*Cout+gco))*L_+(size_t)(th0+tr)*128+tw0+tc;
    float2 a={acc[co][0],acc[co][1]}, c={acc[co][2],acc[co][3]};
    *(float2*)dst=a;
    *(float2*)(dst+128)=c;
  }
}

// epilogue: out = act( sc[0]+sc[1]+bias (+res) )
__global__ void k_epi(const float* __restrict__ sc, const float* __restrict__ bias,
                      const float* __restrict__ res, float* __restrict__ out, int Cout, int act){
  int i=blockIdx.x*256+threadIdx.x;  // 2*Cout*L_
  int co=(i/L_)%Cout;
  size_t half=(size_t)2*Cout*L_;
  float v=sc[i]+sc[half+i]+bias[co];
  if (res) v+=res[i];
  if (act) v=v>0.f?v:0.2f*v;
  out[i]=v;
}

// legacy conv (tail only)
template<int NCO>
__global__ __launch_bounds__(256) void k_conv3(const float* __restrict__ in, const float* __restrict__ wt,
                                               const float* __restrict__ bs, const float* __restrict__ add,
                                               float* __restrict__ out, int Cin, int Cout, int cg_count, int act){
  int b=blockIdx.z/cg_count, cg=blockIdx.z%cg_count;
  int tid=threadIdx.x, tx=tid&15, ty=tid>>4;
  int h=blockIdx.y*16+ty, w=blockIdx.x*16+tx;
  __shared__ float tile[18][18];
  float acc[NCO];
  #pragma unroll
  for (int co=0;co<NCO;co++) acc[co]=0.f;
  for (int ci=0;ci<Cin;ci++){
    const float* src=in+(size_t)(b*Cin+ci)*L_;
    for (int i=tid;i<324;i+=256){
      int r=i/18, c=i%18;
      int gh=blockIdx.y*16+r-1, gw=blockIdx.x*16+c-1;
      tile[r][c]=(gh>=0&&gh<128&&gw>=0&&gw<128)?src[gh*128+gw]:0.f;
    }
    __syncthreads();
    float n0=tile[ty][tx],  n1=tile[ty][tx+1],  n2=tile[ty][tx+2];
    float n3=tile[ty+1][tx],n4=tile[ty+1][tx+1],n5=tile[ty+1][tx+2];
    float n6=tile[ty+2][tx],n7=tile[ty+2][tx+1],n8=tile[ty+2][tx+2];
    const float* wp=wt+((size_t)(cg*NCO)*Cin+ci)*9;
    #pragma unroll
    for (int co=0;co<NCO;co++){
      const float* wq=wp+(size_t)co*Cin*9;
      acc[co]+=n0*wq[0]+n1*wq[1]+n2*wq[2]+n3*wq[3]+n4*wq[4]+n5*wq[5]+n6*wq[6]+n7*wq[7]+n8*wq[8];
    }
    __syncthreads();
  }
  #pragma unroll
  for (int co=0;co<NCO;co++){
    int gco=cg*NCO+co;
    float v=acc[co]+bs[gco];
    if (add) v+=add[(size_t)(b*Cout+gco)*L_+h*128+w];
    if (act) v=v>0.f?v:0.2f*v;
    out[(size_t)(b*Cout+gco)*L_+h*128+w]=v;
  }
}

// ---------------- FFT data consistency ----------------
__device__ __forceinline__ int rev7(int x){
  return ((x&1)<<6)|((x&2)<<4)|((x&4)<<2)|(x&8)|((x&16)>>2)|((x&32)>>4)|((x&64)>>6);
}

__global__ __launch_bounds__(256) void k_fft_dc(const float* __restrict__ x_ri, const float* __restrict__ sens,
                                                const float* __restrict__ ksp, const float* __restrict__ mask,
                                                const float* __restrict__ alpha_p, float* __restrict__ acc){
  int blk=blockIdx.x; int b=blk>>4, coil=blk&15;
  __shared__ float Sr[16384];
  __shared__ float Si[16384];
  __shared__ float twr[64], twi[64];
  int tid=threadIdx.x;
  if (tid<64){ float ang=-2.f*PI_F*(float)tid/128.f; twr[tid]=cosf(ang); twi[tid]=sinf(ang); }
  const float* srp=sens+(size_t)(b*32+2*coil)*L_;
  const float* sip=sens+(size_t)(b*32+2*coil+1)*L_;
  const float* xrp=x_ri+(size_t)(b*2)*L_;
  const float* xip=xrp+L_;
  for (int i=tid;i<16384;i+=256){
    int h=i>>7,w=i&127;
    float sg=((h+w)&1)?-1.f:1.f;
    float sr=srp[i],si=sip[i],xr=xrp[i],xi=xip[i];
    Sr[i]=sg*(sr*xr-si*xi);
    Si[i]=sg*(sr*xi+si*xr);
  }
  __syncthreads();
  for (int s=0;s<7;s++){
    int m=64>>s;
    for (int q=tid;q<8192;q+=256){
      int row=q>>6, jj=q&63;
      int j=jj&(m-1), gg=jj>>(6-s);
      int kpos=(gg<<(7-s))+j;
      int i0=row*128+kpos, i1=i0+m;
      int tw=j<<s;
      float ur=Sr[i0],ui=Si[i0],vr=Sr[i1],vi=Si[i1];
      Sr[i0]=ur+vr; Si[i0]=ui+vi;
      float dr=ur-vr,di=ui-vi,wr=twr[tw],wi=twi[tw];
      Sr[i1]=dr*wr-di*wi; Si[i1]=dr*wi+di*wr;
    }
    __syncthreads();
  }
  for (int s=0;s<7;s++){
    int m=64>>s;
    for (int q=tid;q<8192;q+=256){
      int cpos=q&127, jj=q>>7;
      int j=jj&(m-1), gg=jj>>(6-s);
      int kpos=(gg<<(7-s))+j;
      int i0=kpos*128+cpos, i1=i0+m*128;
      int tw=j<<s;
      float ur=Sr[i0],ui=Si[i0],vr=Sr[i1],vi=Si[i1];
      Sr[i0]=ur+vr; Si[i0]=ui+vi;
      float dr=ur-vr,di=ui-vi,wr=twr[tw],wi=twi[tw];
      Sr[i1]=dr*wr-di*wi; Si[i1]=dr*wi+di*wr;
    }
    __syncthreads();
  }
  float alpha=alpha_p[0];
  const float* krp=ksp+(size_t)(b*32+2*coil)*L_;
  const float* kip=ksp+(size_t)(b*32+2*coil+1)*L_;
  const float* mkp=mask+(size_t)b*L_;
  for (int i=tid;i<16384;i+=256){
    int i1=i>>7, i2=i&127;
    int k1=rev7(i1), k2=rev7(i2);
    int kidx=k1*128+k2;
    float mv=mkp[kidx]*alpha;
    float sg=((k1+k2)&1)?-128.f:128.f;
    float kr=krp[kidx]*100.f*sg, ki=kip[kidx]*100.f*sg;
    Sr[i]=(1.f-mv)*Sr[i]+mv*kr;
    Si[i]=(1.f-mv)*Si[i]+mv*ki;
  }
  __syncthreads();
  for (int s=0;s<7;s++){
    int m=1<<s;
    for (int q=tid;q<8192;q+=256){
      int cpos=q&127, jj=q>>7;
      int j=jj&(m-1), gg=jj>>s;
      int kpos=(gg<<(s+1))+j;
      int i0=kpos*128+cpos, i1=i0+m*128;
      int tw=j<<(6-s);
      float wr=twr[tw], wi=-twi[tw];
      float vr=Sr[i1],vi=Si[i1];
      float tr=vr*wr-vi*wi, ti=vr*wi+vi*wr;
      float ur=Sr[i0],ui=Si[i0];
      Sr[i0]=ur+tr; Si[i0]=ui+ti;
      Sr[i1]=ur-tr; Si[i1]=ui-ti;
    }
    __syncthreads();
  }
  for (int s=0;s<7;s++){
    int m=1<<s;
    for (int q=tid;q<8192;q+=256){
      int row=q>>6, jj=q&63;
      int j=jj&(m-1), gg=jj>>s;
      int kpos=(gg<<(s+1))+j;
      int i0=row*128+kpos, i1=i0+m;
      int tw=j<<(6-s);
      float wr=twr[tw], wi=-twi[tw];
      float vr=Sr[i1],vi=Si[i1];
      float tr=vr*wr-vi*wi, ti=vr*wi+vi*wr;
      float ur=Sr[i0],ui=Si[i0];
      Sr[i0]=ur+tr; Si[i0]=ui+ti;
      Sr[i1]=ur-tr; Si[i1]=ui-ti;
    }
    __syncthreads();
  }
  float* accr=acc+(size_t)(b*2)*L_;
  float* acci=accr+L_;
  for (int i=tid;i<16384;i+=256){
    int h=i>>7,w=i&127;
    float sc=(((h+w)&1)?-1.f:1.f)*(1.f/16384.f);
    float wr2=Sr[i]*sc, wi2=Si[i]*sc;
    float sr=srp[i], si=sip[i];
    atomicAdd(&accr[i], sr*wr2+si*wi2);
    atomicAdd(&acci[i], sr*wi2-si*wr2);
  }
}

__global__ void k_mag(const float* __restrict__ acc, float* __restrict__ out){
  int i=blockIdx.x*256+threadIdx.x;   // 32768
  int b=i>>14, p=i&16383;
  float re=acc[(size_t)(b*2)*L_+p], im=acc[(size_t)(b*2+1)*L_+p];
  out[i]=sqrtf(re*re+im*im+1e-12f);
}

extern "C" void kernel_launch(void* const* d_in, const int* in_sizes, int n_in,
                              void* d_out, int out_size, void* d_ws, size_t ws_size,
                              hipStream_t stream){
  const float* in_imgs=(const float*)d_in[0];
  const float* in_ksp=(const float*)d_in[1];
  const float* mask=(const float*)d_in[2];
  const float* sens=(const float*)d_in[3];
  const float* pe_ln1_g=(const float*)d_in[4];
  const float* pe_ln1_b=(const float*)d_in[5];
  const float* pe_w=(const float*)d_in[6];
  const float* pe_b=(const float*)d_in[7];
  const float* pe_ln2_g=(const float*)d_in[8];
  const float* pe_ln2_b=(const float*)d_in[9];
  const float* pos_emb=(const float*)d_in[10];
  const float* enc_aln_g=(const float*)d_in[11];
  const float* enc_aln_b=(const float*)d_in[12];
  const float* enc_wqkv=(const float*)d_in[13];
  const float* enc_wo=(const float*)d_in[14];
  const float* enc_bo=(const float*)d_in[15];
  const float* enc_fln_g=(const float*)d_in[16];
  const float* enc_fln_b=(const float*)d_in[17];
  const float* enc_w1=(const float*)d_in[18];
  const float* enc_b1=(const float*)d_in[19];
  const float* enc_w2=(const float*)d_in[20];
  const float* enc_b2=(const float*)d_in[21];
  const float* enc_ng=(const float*)d_in[22];
  const float* enc_nb=(const float*)d_in[23];
  const float* dec_pos=(const float*)d_in[24];
  const float* dec_aln_g=(const float*)d_in[25];
  const float* dec_aln_b=(const float*)d_in[26];
  const float* dec_wqkv=(const float*)d_in[27];
  const float* dec_wo=(const float*)d_in[28];
  const float* dec_bo=(const float*)d_in[29];
  const float* dec_fln_g=(const float*)d_in[30];
  const float* dec_fln_b=(const float*)d_in[31];
  const float* dec_w1=(const float*)d_in[32];
  const float* dec_b1=(const float*)d_in[33];
  const float* dec_w2=(const float*)d_in[34];
  const float* dec_b2=(const float*)d_in[35];
  const float* dec_ng=(const float*)d_in[36];
  const float* dec_nb=(const float*)d_in[37];
  const float* fin_w=(const float*)d_in[38];
  const float* fin_b=(const float*)d_in[39];
  const float* ss_in_w=(const float*)d_in[40];
  const float* ss_in_b=(const float*)d_in[41];
  const float* ss_conv_w=(const float*)d_in[42];
  const float* ss_conv_b=(const float*)d_in[43];
  const float* ss_xproj=(const float*)d_in[44];
  const float* ss_dt_w=(const float*)d_in[45];
  const float* ss_dt_b=(const float*)d_in[46];
  const float* ss_Alog=(const float*)d_in[47];
  const float* ss_D=(const float*)d_in[48];
  const float* ss_ln_g=(const float*)d_in[49];
  const float* ss_ln_b=(const float*)d_in[50];
  const float* ss_out_w=(const float*)d_in[51];
  const float* ss_out_b=(const float*)d_in[52];
  const float* head_w=(const float*)d_in[53];
  const float* head_b=(const float*)d_in[54];
  const float* res_w1=(const float*)d_in[55];
  const float* res_b1=(const float*)d_in[56];
  const float* res_w2=(const float*)d_in[57];
  const float* res_b2=(const float*)d_in[58];
  const float* tail_w=(const float*)d_in[59];
  const float* tail_b=(const float*)d_in[60];
  const float* dc_alpha=(const float*)d_in[61];

  char* ws=(char*)d_ws;
  size_t off=0;
  auto alloc=[&](size_t nfloats)->float*{ float* p=(float*)(ws+off); off+=((nfloats*4+255)/256)*256; return p; };
  float* xn   =alloc((size_t)32*32768);
  float* tA   =alloc(32*512);
  float* tB   =alloc(32*512);
  float* aln  =alloc(32*512);
  float* qkv  =alloc(32*1536);
  float* attno=alloc(32*512);
  float* ffh  =alloc(32*3072);
  float* xup  =alloc((size_t)2*4*L_);
  float* xz   =alloc((size_t)2*64*L_);
  float* xs0  =alloc((size_t)2*32*L_);
  float* xs0T =alloc((size_t)2*32*L_);
  float* dbl  =alloc((size_t)2*4*L_*18);
  float* ys   =alloc((size_t)2*4*32*L_);
  float* oss  =alloc((size_t)2*20*L_);
  float* xc   =alloc((size_t)2*56*L_);
  float* h0   =alloc((size_t)2*64*L_);
  float* tmpc =alloc((size_t)2*64*L_);
  float* csc  =alloc((size_t)2*2*64*L_);   // conv split-K scratch [ks][b][co][L]
  float* x_ri =alloc((size_t)2*2*L_);
  float* accb =alloc((size_t)2*2*L_);
  (void)ws_size; (void)in_sizes; (void)n_in; (void)out_size;

  // ---- patch embed + encoder/decoder ----
  k_ln_pe<<<32,256,0,stream>>>(in_imgs, pe_ln1_g, pe_ln1_b, xn);
  hipMemsetAsync(tA, 0, 32*512*4, stream);
  k_gemm_sk<256,0><<<dim3(8,128),256,0,stream>>>(xn, pe_w, pe_b, tA, 512, 32768);
  k_pe_post<<<32,256,0,stream>>>(tA, pe_ln2_g, pe_ln2_b, pos_emb);

  for (int i=0;i<4;i++){
    k_ln_tok<<<32,256,0,stream>>>(tA, enc_aln_g+i*512, enc_aln_b+i*512, aln);
    hipMemsetAsync(qkv, 0, 32*1536*4, stream);
    k_gemm_sk<64,0><<<dim3(24,8),256,0,stream>>>(aln, enc_wqkv+(size_t)i*512*1536, nullptr, qkv, 1536, 512);
    k_attn<<<16,256,0,stream>>>(qkv, attno);
    k_gemm_sk<64,0><<<dim3(8,8),256,0,stream>>>(attno, enc_wo+(size_t)i*512*512, enc_bo+i*512, tA, 512, 512);
    k_ln_tok<<<32,256,0,stream>>>(tA, enc_fln_g+i*512, enc_fln_b+i*512, aln);
    hipMemsetAsync(ffh, 0, 32*2048*4, stream);
    k_gemm_sk<64,0><<<dim3(32,8),256,0,stream>>>(aln, enc_w1+(size_t)i*512*2048, enc_b1+i*2048, ffh, 2048, 512);
    k_gemm_sk<64,1><<<dim3(8,32),256,0,stream>>>(ffh, enc_w2+(size_t)i*2048*512, enc_b2+i*512, tA, 512, 2048);
  }
  k_ln_tok<<<32,256,0,stream>>>(tA, enc_ng, enc_nb, tA);
  k_addpos<<<64,256,0,stream>>>(tA, dec_pos, tB);
  k_ln_tok<<<32,256,0,stream>>>(tB, dec_aln_g, dec_aln_b, aln);
  hipMemsetAsync(qkv, 0, 32*1536*4, stream);
  k_gemm_sk<64,0><<<dim3(24,8),256,0,stream>>>(aln, dec_wqkv, nullptr, qkv, 1536, 512);
  k_attn<<<16,256,0,stream>>>(qkv, attno);
  k_gemm_sk<64,0><<<dim3(8,8),256,0,stream>>>(attno, dec_wo, dec_bo, tB, 512, 512);
  k_ln_tok<<<32,256,0,stream>>>(tB, dec_fln_g, dec_fln_b, aln);
  hipMemsetAsync(ffh, 0, 32*3072*4, stream);
  k_gemm_sk<64,0><<<dim3(48,8),256,0,stream>>>(aln, dec_w1, dec_b1, ffh, 3072, 512);
  k_gemm_sk<64,1><<<dim3(8,48),256,0,stream>>>(ffh, dec_w2, dec_b2, tB, 512, 3072);
  k_ln_tok<<<32,256,0,stream>>>(tB, dec_ng, dec_nb, tB);
  hipMemsetAsync(xup, 0, (size_t)2*4*L_*4, stream);
  k_gemm_sk<64,2><<<dim3(64,8),256,0,stream>>>(tB, fin_w, fin_b, xup, 4096, 512);

  // ---- SS2D ----
  k_xz<<<128,256,0,stream>>>(in_ksp, ss_in_w, ss_in_b, xz);
  k_dwconv<<<4096,256,0,stream>>>(xz, ss_conv_w, ss_conv_b, xs0);
  k_transpose<<<dim3(4,4,64),256,0,stream>>>(xs0, xs0T);
  k_dbl<<<dim3(64,8),256,0,stream>>>(xs0, xs0T, ss_xproj, dbl);
  k_scan<<<256,256,0,stream>>>(dbl, xs0, xs0T, ss_dt_w, ss_dt_b, ss_Alog, ss_D, ys);
  k_ycomb<<<128,256,0,stream>>>(ys, xz, ss_ln_g, ss_ln_b, ss_out_w, ss_out_b, oss);

  // ---- conv head (fast path) ----
  k_concat<<<7168,256,0,stream>>>(xup, in_imgs, oss, xc);
  k_conv3s<4><<<dim3(16,16,4),256,0,stream>>>(xc, head_w, csc, 56, 64, 28);
  k_epi<<<8192,256,0,stream>>>(csc, head_b, nullptr, h0, 64, 1);
  for (int i=0;i<3;i++){
    k_conv3s<4><<<dim3(16,16,4),256,0,stream>>>(h0, res_w1+(size_t)i*64*64*9, csc, 64, 64, 32);
    k_epi<<<8192,256,0,stream>>>(csc, res_b1+i*64, nullptr, tmpc, 64, 1);
    k_conv3s<4><<<dim3(16,16,4),256,0,stream>>>(tmpc, res_w2+(size_t)i*64*64*9, csc, 64, 64, 32);
    k_epi<<<8192,256,0,stream>>>(csc, res_b2+i*64, h0, h0, 64, 1);
  }
  k_conv3<2><<<dim3(8,8,2),256,0,stream>>>(h0, tail_w, tail_b, nullptr, x_ri, 64, 2, 1, 0);

  // ---- FFT data consistency ----
  hipMemsetAsync(accb, 0, (size_t)2*2*L_*4, stream);
  k_fft_dc<<<32,256,0,stream>>>(x_ri, sens, in_ksp, mask, dc_alpha, accb);
  k_mag<<<128,256,0,stream>>>(accb, (float*)d_out);
}

// Round 5
// 1792.430 us; speedup vs baseline: 3.3686x; 1.0272x over previous
//
#include <hip/hip_runtime.h>

#define PI_F 3.14159265358979323846f

constexpr int L_ = 16384;   // H*W
constexpr int PD_ = 32768;  // P*P*C

__device__ __forceinline__ float sigmoidf_(float x){ return 1.f/(1.f+__expf(-x)); }
__device__ __forceinline__ float softplusf_(float x){ return x>20.f ? x : log1pf(__expf(x)); }
__device__ __forceinline__ float geluf_(float x){ return 0.5f*x*(1.f+erff(x*0.70710678118654752f)); }

__device__ __forceinline__ float2 block_reduce2(float s, float ss){
  __shared__ float r1[256], r2[256];
  int tid = threadIdx.x;
  r1[tid]=s; r2[tid]=ss; __syncthreads();
  for(int o=128;o>0;o>>=1){ if(tid<o){ r1[tid]+=r1[tid+o]; r2[tid]+=r2[tid+o]; } __syncthreads(); }
  float2 out; out.x=r1[0]; out.y=r2[0]; __syncthreads();
  return out;
}

// ---------------- patch embed (split: partial sums, then normalize) ----------------
__global__ __launch_bounds__(256) void k_pesum(const float* __restrict__ img, float* __restrict__ stats){
  int blk=blockIdx.x; int m=blk>>3, sl=blk&7;
  int b=m>>4, n=m&15, ih=n>>2, iw=n&3;
  int tid=threadIdx.x;
  const float* base=img+(size_t)b*32*L_;
  float s=0.f, ss=0.f;
  for (int i=tid;i<4096;i+=256){
    int j=sl*4096+i;
    int c=j>>10, p1=(j>>5)&31, p2=j&31;
    float v=base[(size_t)c*L_+(ih*32+p1)*128+iw*32+p2];
    s+=v; ss+=v*v;
  }
  float2 r=block_reduce2(s,ss);
  if (tid==0){ atomicAdd(&stats[m*2],r.x); atomicAdd(&stats[m*2+1],r.y); }
}

__global__ __launch_bounds__(256) void k_penorm(const float* __restrict__ img, const float* __restrict__ stats,
                                                const float* __restrict__ g, const float* __restrict__ bv,
                                                float* __restrict__ xn){
  int blk=blockIdx.x; int m=blk>>3, sl=blk&7;
  int b=m>>4, n=m&15, ih=n>>2, iw=n&3;
  int tid=threadIdx.x;
  const float* base=img+(size_t)b*32*L_;
  float mean=stats[m*2]/(float)PD_;
  float var =stats[m*2+1]/(float)PD_-mean*mean;
  float inv =1.f/sqrtf(var+1e-5f);
  for (int i=tid;i<4096;i+=256){
    int j=sl*4096+i;
    int c=j>>10, p1=(j>>5)&31, p2=j&31;
    float v=base[(size_t)c*L_+(ih*32+p1)*128+iw*32+p2];
    int k=(p1*32+p2)*32+c;
    xn[(size_t)m*PD_+k]=(v-mean)*inv*g[k]+bv[k];
  }
}

// split-K skinny GEMM (unchanged)
template<int KC, int MODE>
__global__ __launch_bounds__(256) void k_gemm_sk(const float* __restrict__ A, const float* __restrict__ Bw,
                                                 const float* __restrict__ bias, float* __restrict__ C,
                                                 int N, int K){
  __shared__ float As[32][KC];
  int tid=threadIdx.x, tx=tid&63, ty=tid>>6;
  int n = blockIdx.x*64+tx;
  int k0 = blockIdx.y*KC;
  for (int i=tid;i<32*KC;i+=256){
    int r=i/KC, c=i%KC;
    float v=A[(size_t)r*K + k0 + c];
    if (MODE==1) v=geluf_(v);
    As[r][c]=v;
  }
  __syncthreads();
  float acc[8]={0,0,0,0,0,0,0,0};
  for (int kk=0;kk<KC;kk+=4){
    float b0=Bw[(size_t)(k0+kk)*N+n],   b1=Bw[(size_t)(k0+kk+1)*N+n];
    float b2=Bw[(size_t)(k0+kk+2)*N+n], b3=Bw[(size_t)(k0+kk+3)*N+n];
    #pragma unroll
    for (int r=0;r<8;r++){
      const float4 a=*(const float4*)&As[ty*8+r][kk];
      acc[r]+=a.x*b0+a.y*b1+a.z*b2+a.w*b3;
    }
  }
  bool addb = (bias!=nullptr) && (blockIdx.y==0);
  #pragma unroll
  for (int r=0;r<8;r++){
    int m=ty*8+r;
    float v=acc[r]+(addb?bias[n]:0.f);
    if (MODE==2){
      int b=m>>4, ih=(m>>2)&3, iw=m&3;
      int cu=n>>10, f1=(n>>5)&31, f2=n&31;
      atomicAdd(&C[((size_t)(b*4+cu)*128+ih*32+f1)*128+iw*32+f2], v);
    } else {
      atomicAdd(&C[(size_t)m*N+n], v);
    }
  }
}

__global__ __launch_bounds__(256) void k_pe_post(float* __restrict__ t,
                                                 const float* __restrict__ g, const float* __restrict__ bv,
                                                 const float* __restrict__ pos){
  int m=blockIdx.x, tid=threadIdx.x;
  float v0 = t[m*512+tid];
  float v1 = t[m*512+256+tid];
  float2 r = block_reduce2(v0+v1, v0*v0+v1*v1);
  float mean=r.x/512.f, var=r.y/512.f-mean*mean, inv=1.f/sqrtf(var+1e-5f);
  int n = m&15;
  t[m*512+tid]     = (v0-mean)*inv*g[tid]+bv[tid]         + pos[n*512+tid];
  t[m*512+256+tid] = (v1-mean)*inv*g[256+tid]+bv[256+tid] + pos[n*512+256+tid];
}

__global__ __launch_bounds__(256) void k_ln_tok(const float* __restrict__ src, const float* __restrict__ g,
                                                const float* __restrict__ bv, float* __restrict__ dst){
  int m=blockIdx.x, tid=threadIdx.x;
  float v0=src[m*512+tid], v1=src[m*512+256+tid];
  float2 r=block_reduce2(v0+v1, v0*v0+v1*v1);
  float mean=r.x/512.f, var=r.y/512.f-mean*mean, inv=1.f/sqrtf(var+1e-5f);
  dst[m*512+tid]     =(v0-mean)*inv*g[tid]+bv[tid];
  dst[m*512+256+tid] =(v1-mean)*inv*g[256+tid]+bv[256+tid];
}

__global__ void k_addpos(const float* __restrict__ t, const float* __restrict__ pos, float* __restrict__ dst){
  int i = blockIdx.x*256+threadIdx.x;   // 16384
  int m=i>>9, j=i&511;
  dst[i]=t[i]+pos[(m&15)*512+j];
}

__global__ __launch_bounds__(256) void k_attn(const float* __restrict__ qkv, float* __restrict__ outb){
  int bh=blockIdx.x, b=bh>>3, h=bh&7, tid=threadIdx.x;
  __shared__ float q[16][64], kk[16][64], vv[16][64], pp[16][16];
  for (int i=tid;i<1024;i+=256){
    int row=i>>6, d=i&63;
    const float* src=qkv + (size_t)(b*16+row)*1536 + h*64+d;
    q[row][d]=src[0]; kk[row][d]=src[512]; vv[row][d]=src[1024];
  }
  __syncthreads();
  int i=tid>>4, j=tid&15;
  float s=0.f;
  #pragma unroll
  for (int d=0;d<64;d++) s+=q[i][d]*kk[j][d];
  s*=0.125f;
  float mx=s;
  for (int o=8;o>0;o>>=1) mx=fmaxf(mx,__shfl_xor(mx,o,16));
  float e=__expf(s-mx), sm=e;
  for (int o=8;o>0;o>>=1) sm+=__shfl_xor(sm,o,16);
  pp[i][j]=e/sm;
  __syncthreads();
  int d=tid&63;
  for (int pass=0;pass<4;pass++){
    int row=pass*4+(tid>>6);
    float acc=0.f;
    #pragma unroll
    for (int jj=0;jj<16;jj++) acc+=pp[row][jj]*vv[jj][d];
    outb[(size_t)(b*16+row)*512 + h*64+d]=acc;
  }
}

// ---------------- SS2D ----------------
__global__ __launch_bounds__(256) void k_xz(const float* __restrict__ ksp, const float* __restrict__ w,
                                            const float* __restrict__ bv, float* __restrict__ xz){
  int blk=blockIdx.x; int b=blk>>6; int p0=(blk&63)*256; int tid=threadIdx.x;
  __shared__ float lin[32][256];
  __shared__ float lw[2048];
  for (int i=tid;i<2048;i+=256) lw[i]=w[i];
  for (int i=tid;i<8192;i+=256){ int c=i>>8, p=i&255; lin[c][p]=ksp[(size_t)(b*32+c)*L_+p0+p]; }
  __syncthreads();
  float xv[32];
  #pragma unroll
  for (int c=0;c<32;c++) xv[c]=lin[c][tid];
  for (int e=0;e<64;e++){
    float a=bv[e];
    #pragma unroll
    for (int c=0;c<32;c++) a+=xv[c]*lw[c*64+e];
    xz[(size_t)(b*64+e)*L_+p0+tid]=a;
  }
}

__global__ void k_dwconv(const float* __restrict__ xz, const float* __restrict__ w,
                         const float* __restrict__ bv, float* __restrict__ xs0){
  int i=blockIdx.x*256+threadIdx.x;
  int p=i&16383; int d=(i>>14)&31; int b=i>>19;
  int h=p>>7, ww=p&127;
  const float* src=xz+(size_t)(b*64+d)*L_;
  float acc=bv[d];
  for (int ky=0;ky<3;ky++){
    int hh=h+ky-1; if(hh<0||hh>127) continue;
    for (int kx=0;kx<3;kx++){
      int wx=ww+kx-1; if(wx<0||wx>127) continue;
      acc+=src[hh*128+wx]*w[d*9+ky*3+kx];
    }
  }
  xs0[(size_t)(b*32+d)*L_+p]=acc*sigmoidf_(acc);
}

__global__ __launch_bounds__(256) void k_transpose(const float* __restrict__ src, float* __restrict__ dst){
  __shared__ float tile[32][33];
  int z=blockIdx.z;
  int h0=blockIdx.y*32, w0=blockIdx.x*32;
  int tid=threadIdx.x, tx=tid&31, ty=tid>>5;
  const float* s=src+(size_t)z*L_;
  float* d=dst+(size_t)z*L_;
  for (int r=ty;r<32;r+=8) tile[r][tx]=s[(h0+r)*128+w0+tx];
  __syncthreads();
  for (int r=ty;r<32;r+=8) d[(w0+r)*128+h0+tx]=tile[tx][r];
}

__global__ __launch_bounds__(256) void k_dbl(const float* __restrict__ xs0, const float* __restrict__ xs0T,
                                             const float* __restrict__ xproj, float* __restrict__ dbl){
  int bk=blockIdx.y; int b=bk>>2, k=bk&3;
  int l0=blockIdx.x*256, tid=threadIdx.x;
  const float* src=(k&1)?xs0T:xs0;
  __shared__ float xv[32][256];
  __shared__ float xp[576];
  for (int i=tid;i<576;i+=256) xp[i]=xproj[k*576+i];
  for (int i=tid;i<8192;i+=256){
    int dd=i>>8, p=i&255; int l=l0+p; int li=(k<2)?l:(16383-l);
    xv[dd][p]=src[(size_t)(b*32+dd)*L_+li];
  }
  __syncthreads();
  float xr[32];
  #pragma unroll
  for (int dd=0;dd<32;dd++) xr[dd]=xv[dd][tid];
  float* out=&dbl[((size_t)(b*4+k)*L_ + l0+tid)*18];
  for (int c=0;c<18;c++){
    float a=0.f;
    #pragma unroll
    for (int dd=0;dd<32;dd++) a+=xr[dd]*xp[dd*18+c];
    out[c]=a;
  }
}

// ---- chunked 3-phase selective scan ----
// phase1: block=(bk,chunk of 128), thread=(d,s). LDS-stage dbl+xs, local scan -> summary (P,Q)
__global__ __launch_bounds__(256) void k_scan1(const float* __restrict__ dbl, const float* __restrict__ xs0,
                                               const float* __restrict__ xs0T, const float* __restrict__ dtw,
                                               const float* __restrict__ dtb, const float* __restrict__ Alog,
                                               float2* __restrict__ sm){
  int blk=blockIdx.x; int bk=blk>>7, c=blk&127;
  int b=bk>>2, k=bk&3;
  int tid=threadIdx.x, d=tid>>3, s=tid&7;
  __shared__ float ed[128][18];
  __shared__ float xsl[32][128];
  const float* dbase=dbl+((size_t)bk*L_+c*128)*18;
  for (int i=tid;i<2304;i+=256) ((float*)ed)[i]=dbase[i];
  const float* src=(k&1)?xs0T:xs0;
  bool rev=(k>=2);
  for (int i=tid;i<4096;i+=256){
    int dd=i>>7, j=i&127; int l=c*128+j;
    xsl[dd][j]=src[(size_t)(b*32+dd)*L_+(rev?(16383-l):l)];
  }
  __syncthreads();
  float w0=dtw[(k*2+0)*32+d], w1=dtw[(k*2+1)*32+d], bb=dtb[k*32+d];
  float Av=-__expf(Alog[(k*32+d)*8+s]);
  float P=1.f, Q=0.f;
  for (int j=0;j<128;j++){
    float dt=softplusf_(ed[j][0]*w0+ed[j][1]*w1+bb);
    float u=dt*xsl[d][j];
    float a=__expf(dt*Av);
    Q=a*Q+u*ed[j][2+s];
    P*=a;
  }
  sm[((size_t)bk*128+c)*256+tid]=make_float2(P,Q);
}

// phase2: per (bk) stitch 128 chunk summaries; pre[c] = state before chunk c
__global__ __launch_bounds__(256) void k_scan2(const float2* __restrict__ sm, float* __restrict__ pre){
  int bk=blockIdx.x, tid=threadIdx.x;
  float run=0.f;
  for (int c=0;c<128;c++){
    size_t idx=((size_t)bk*128+c)*256+tid;
    pre[idx]=run;
    float2 pq=sm[idx];
    run=pq.x*run+pq.y;
  }
}

// phase3: rescan with injected prefix, produce y
__global__ __launch_bounds__(256) void k_scan3(const float* __restrict__ dbl, const float* __restrict__ xs0,
                                               const float* __restrict__ xs0T, const float* __restrict__ dtw,
                                               const float* __restrict__ dtb, const float* __restrict__ Alog,
                                               const float* __restrict__ Dp, const float* __restrict__ pre,
                                               float* __restrict__ ys){
  int blk=blockIdx.x; int bk=blk>>7, c=blk&127;
  int b=bk>>2, k=bk&3;
  int tid=threadIdx.x, d=tid>>3, s=tid&7;
  __shared__ float ed[128][18];
  __shared__ float xsl[32][128];
  __shared__ float ybuf[32][128];
  const float* dbase=dbl+((size_t)bk*L_+c*128)*18;
  for (int i=tid;i<2304;i+=256) ((float*)ed)[i]=dbase[i];
  const float* src=(k&1)?xs0T:xs0;
  bool rev=(k>=2);
  for (int i=tid;i<4096;i+=256){
    int dd=i>>7, j=i&127; int l=c*128+j;
    xsl[dd][j]=src[(size_t)(b*32+dd)*L_+(rev?(16383-l):l)];
  }
  __syncthreads();
  float w0=dtw[(k*2+0)*32+d], w1=dtw[(k*2+1)*32+d], bb=dtb[k*32+d];
  float Av=-__expf(Alog[(k*32+d)*8+s]);
  float Dv=Dp[k*32+d];
  float h=pre[((size_t)bk*128+c)*256+tid];
  for (int j=0;j<128;j++){
    float xsv=xsl[d][j];
    float dt=softplusf_(ed[j][0]*w0+ed[j][1]*w1+bb);
    float u=dt*xsv;
    float a=__expf(dt*Av);
    h=a*h+u*ed[j][2+s];
    float yp=h*ed[j][10+s];
    yp+=__shfl_xor(yp,1,8);
    yp+=__shfl_xor(yp,2,8);
    yp+=__shfl_xor(yp,4,8);
    if (s==0) ybuf[d][j]=yp+Dv*xsv;
  }
  __syncthreads();
  float* yout=ys+((size_t)bk*32)*L_+c*128;
  for (int i=tid;i<4096;i+=256){
    int dd=i>>7, j=i&127;
    yout[(size_t)dd*L_+j]=ybuf[dd][j];
  }
}

__global__ __launch_bounds__(256) void k_ycomb(const float* __restrict__ ys, const float* __restrict__ xz,
                                               const float* __restrict__ g, const float* __restrict__ bv,
                                               const float* __restrict__ ow, const float* __restrict__ ob,
                                               float* __restrict__ oss){
  int blk=blockIdx.x; int b=blk>>6; int p=(blk&63)*256+threadIdx.x;
  int h=p>>7, w=p&127; int lt=w*128+h;
  __shared__ float lw[640]; __shared__ float lb[20]; __shared__ float lg[32], lbv[32];
  int tid=threadIdx.x;
  for (int i=tid;i<640;i+=256) lw[i]=ow[i];
  if (tid<20) lb[tid]=ob[tid];
  if (tid<32){ lg[tid]=g[tid]; lbv[tid]=bv[tid]; }
  __syncthreads();
  size_t base=(size_t)b*4*32*L_;
  float y[32];
  float s=0.f, ss=0.f;
  #pragma unroll
  for (int d=0;d<32;d++){
    float v=ys[base+(size_t)(0*32+d)*L_+p] + ys[base+(size_t)(2*32+d)*L_+16383-p]
          + ys[base+(size_t)(1*32+d)*L_+lt] + ys[base+(size_t)(3*32+d)*L_+16383-lt];
    y[d]=v; s+=v; ss+=v*v;
  }
  float mean=s/32.f, var=ss/32.f-mean*mean, inv=1.f/sqrtf(var+1e-5f);
  #pragma unroll
  for (int d=0;d<32;d++){
    float yn=(y[d]-mean)*inv*lg[d]+lbv[d];
    float zv=xz[(size_t)(b*64+32+d)*L_+p];
    y[d]=yn*(zv*sigmoidf_(zv));
  }
  for (int c=0;c<20;c++){
    float a=lb[c];
    #pragma unroll
    for (int d=0;d<32;d++) a+=y[d]*lw[d*20+c];
    oss[(size_t)(b*20+c)*L_+p]=a;
  }
}

__global__ void k_concat(const float* __restrict__ x, const float* __restrict__ img,
                         const float* __restrict__ oss, float* __restrict__ xc){
  int i=blockIdx.x*256+threadIdx.x;
  int p=i&16383; int ch=(i>>14)%56; int b=i/(56*16384);
  float v;
  if (ch<4) v=x[(size_t)(b*4+ch)*L_+p];
  else if (ch<36) v=img[(size_t)(b*32+ch-4)*L_+p];
  else v=oss[(size_t)(b*20+ch-36)*L_+p];
  xc[i]=v;
}

// ---- fast conv3x3 ----
template<int NCO>
__global__ __launch_bounds__(256) void k_conv3s(const float* __restrict__ in, const float* __restrict__ wt,
                                                float* __restrict__ sc, int Cin, int Cout, int CIS){
  int tile=blockIdx.x; int th0=(tile>>2)*32, tw0=(tile&3)*32;
  int cg=blockIdx.y;
  int bz=blockIdx.z; int b=bz>>1, ks=bz&1;
  int cibase=ks*CIS;
  int cic=Cin-cibase; if (cic>CIS) cic=CIS;
  __shared__ float wlds[32][NCO][9];
  __shared__ float ibuf[2][34][34];
  int tid=threadIdx.x;
  for (int i=tid;i<cic*NCO*9;i+=256){
    int ci=i/(NCO*9), rem=i%(NCO*9), co=rem/9, q=rem%9;
    wlds[ci][co][q]=wt[(((size_t)(cg*NCO+co))*Cin + cibase+ci)*9+q];
  }
  auto stage=[&](int buf, int ci){
    const float* src=in+((size_t)b*Cin+cibase+ci)*L_;
    for (int i=tid;i<34*34;i+=256){
      int r=i/34, c=i%34;
      int gh=th0+r-1, gw=tw0+c-1;
      ibuf[buf][r][c]=(gh>=0&&gh<128&&gw>=0&&gw<128)?src[gh*128+gw]:0.f;
    }
  };
  stage(0,0);
  __syncthreads();
  float acc[NCO][4];
  #pragma unroll
  for (int co=0;co<NCO;co++){acc[co][0]=0.f;acc[co][1]=0.f;acc[co][2]=0.f;acc[co][3]=0.f;}
  int tr=((tid>>4)&15)<<1, tc=(tid&15)<<1;
  for (int ci=0;ci<cic;ci++){
    int cur=ci&1;
    if (ci+1<cic) stage(cur^1, ci+1);
    float iv[4][4];
    #pragma unroll
    for (int dr=0;dr<4;dr++)
      #pragma unroll
      for (int dc=0;dc<4;dc++) iv[dr][dc]=ibuf[cur][tr+dr][tc+dc];
    #pragma unroll
    for (int co=0;co<NCO;co++){
      float w0=wlds[ci][co][0],w1=wlds[ci][co][1],w2=wlds[ci][co][2];
      float w3=wlds[ci][co][3],w4=wlds[ci][co][4],w5=wlds[ci][co][5];
      float w6=wlds[ci][co][6],w7=wlds[ci][co][7],w8=wlds[ci][co][8];
      acc[co][0]+=iv[0][0]*w0+iv[0][1]*w1+iv[0][2]*w2
                 +iv[1][0]*w3+iv[1][1]*w4+iv[1][2]*w5
                 +iv[2][0]*w6+iv[2][1]*w7+iv[2][2]*w8;
      acc[co][1]+=iv[0][1]*w0+iv[0][2]*w1+iv[0][3]*w2
                 +iv[1][1]*w3+iv[1][2]*w4+iv[1][3]*w5
                 +iv[2][1]*w6+iv[2][2]*w7+iv[2][3]*w8;
      acc[co][2]+=iv[1][0]*w0+iv[1][1]*w1+iv[1][2]*w2
                 +iv[2][0]*w3+iv[2][1]*w4+iv[2][2]*w5
                 +iv[3][0]*w6+iv[3][1]*w7+iv[3][2]*w8;
      acc[co][3]+=iv[1][1]*w0+iv[1][2]*w1+iv[1][3]*w2
                 +iv[2][1]*w3+iv[2][2]*w4+iv[2][3]*w5
                 +iv[3][1]*w6+iv[3][2]*w7+iv[3][3]*w8;
    }
    __syncthreads();
  }
  #pragma unroll
  for (int co=0;co<NCO;co++){
    int gco=cg*NCO+co;
    float* dst=sc+((size_t)((ks*2+b)*Cout+gco))*L_+(size_t)(th0+tr)*128+tw0+tc;
    float2 a={acc[co][0],acc[co][1]}, c={acc[co][2],acc[co][3]};
    *(float2*)dst=a;
    *(float2*)(dst+128)=c;
  }
}

__global__ void k_epi(const float* __restrict__ sc, const float* __restrict__ bias,
                      const float* __restrict__ res, float* __restrict__ out, int Cout, int act){
  int i=blockIdx.x*256+threadIdx.x;
  int co=(i/L_)%Cout;
  size_t half=(size_t)2*Cout*L_;
  float v=sc[i]+sc[half+i]+bias[co];
  if (res) v+=res[i];
  if (act) v=v>0.f?v:0.2f*v;
  out[i]=v;
}

// ---------------- FFT data consistency (3-way split) ----------------
__device__ __forceinline__ int rev7(int x){
  return ((x&1)<<6)|((x&2)<<4)|((x&4)<<2)|(x&8)|((x&16)>>2)|((x&32)>>4)|((x&64)>>6);
}

// phase A: sign*sens*x, forward DIF on rows (16 rows per block)
__global__ __launch_bounds__(256) void k_fftA(const float* __restrict__ x_ri, const float* __restrict__ sens,
                                              float* __restrict__ tmp){
  int blk=blockIdx.x; int b=blk>>7, coil=(blk>>3)&15, rg=blk&7;
  int r0=rg*16;
  __shared__ float Ar[16][128], Ai[16][128];
  __shared__ float twr[64], twi[64];
  int tid=threadIdx.x;
  if (tid<64){ float ang=-2.f*PI_F*(float)tid/128.f; twr[tid]=cosf(ang); twi[tid]=sinf(ang); }
  const float* srp=sens+(size_t)(b*32+2*coil)*L_;
  const float* sip=sens+(size_t)(b*32+2*coil+1)*L_;
  const float* xrp=x_ri+(size_t)(b*2)*L_;
  const float* xip=xrp+L_;
  for (int i=tid;i<2048;i+=256){
    int lr=i>>7, w=i&127; int gh=r0+lr; int idx=gh*128+w;
    float sg=((gh+w)&1)?-1.f:1.f;
    float sr=srp[idx],si=sip[idx],xr=xrp[idx],xi=xip[idx];
    Ar[lr][w]=sg*(sr*xr-si*xi);
    Ai[lr][w]=sg*(sr*xi+si*xr);
  }
  __syncthreads();
  for (int s=0;s<7;s++){
    int m=64>>s;
    for (int q=tid;q<1024;q+=256){
      int lr=q>>6, jj=q&63;
      int j=jj&(m-1), gg=jj>>(6-s);
      int kpos=(gg<<(7-s))+j;
      int tw=j<<s;
      float ur=Ar[lr][kpos],ui=Ai[lr][kpos],vr=Ar[lr][kpos+m],vi=Ai[lr][kpos+m];
      Ar[lr][kpos]=ur+vr; Ai[lr][kpos]=ui+vi;
      float dr=ur-vr,di=ui-vi,wr=twr[tw],wi=twi[tw];
      Ar[lr][kpos+m]=dr*wr-di*wi; Ai[lr][kpos+m]=dr*wi+di*wr;
    }
    __syncthreads();
  }
  float* tr=tmp+(size_t)(b*16+coil)*2*L_;
  float* ti=tr+L_;
  for (int i=tid;i<2048;i+=256){
    int lr=i>>7, w=i&127; int idx=(r0+lr)*128+w;
    tr[idx]=Ar[lr][w]; ti[idx]=Ai[lr][w];
  }
}

// phase B: forward DIF cols + DC + inverse DIT cols (16 cols per block)
__global__ __launch_bounds__(256) void k_fftB(float* __restrict__ tmp, const float* __restrict__ ksp,
                                              const float* __restrict__ mask, const float* __restrict__ alpha_p){
  int blk=blockIdx.x; int b=blk>>7, coil=(blk>>3)&15, cg=blk&7;
  int c0=cg*16;
  __shared__ float Br[128][17], Bi[128][17];
  __shared__ float twr[64], twi[64];
  int tid=threadIdx.x;
  if (tid<64){ float ang=-2.f*PI_F*(float)tid/128.f; twr[tid]=cosf(ang); twi[tid]=sinf(ang); }
  float* tr=tmp+(size_t)(b*16+coil)*2*L_;
  float* ti=tr+L_;
  for (int i=tid;i<2048;i+=256){
    int r=i>>4, lc=i&15;
    Br[r][lc]=tr[r*128+c0+lc]; Bi[r][lc]=ti[r*128+c0+lc];
  }
  __syncthreads();
  for (int s=0;s<7;s++){
    int m=64>>s;
    for (int q=tid;q<1024;q+=256){
      int lc=q&15, jj=q>>4;
      int j=jj&(m-1), gg=jj>>(6-s);
      int kpos=(gg<<(7-s))+j;
      int tw=j<<s;
      float ur=Br[kpos][lc],ui=Bi[kpos][lc],vr=Br[kpos+m][lc],vi=Bi[kpos+m][lc];
      Br[kpos][lc]=ur+vr; Bi[kpos][lc]=ui+vi;
      float dr=ur-vr,di=ui-vi,wr=twr[tw],wi=twi[tw];
      Br[kpos+m][lc]=dr*wr-di*wi; Bi[kpos+m][lc]=dr*wi+di*wr;
    }
    __syncthreads();
  }
  float alpha=alpha_p[0];
  const float* krp=ksp+(size_t)(b*32+2*coil)*L_;
  const float* kip=ksp+(size_t)(b*32+2*coil+1)*L_;
  const float* mkp=mask+(size_t)b*L_;
  for (int i=tid;i<2048;i+=256){
    int r=i>>4, lc=i&15;
    int k1=rev7(r), k2=rev7(c0+lc);
    int kidx=k1*128+k2;
    float mv=mkp[kidx]*alpha;
    float sg=((k1+k2)&1)?-128.f:128.f;
    float kr=krp[kidx]*100.f*sg, ki=kip[kidx]*100.f*sg;
    Br[r][lc]=(1.f-mv)*Br[r][lc]+mv*kr;
    Bi[r][lc]=(1.f-mv)*Bi[r][lc]+mv*ki;
  }
  __syncthreads();
  for (int s=0;s<7;s++){
    int m=1<<s;
    for (int q=tid;q<1024;q+=256){
      int lc=q&15, jj=q>>4;
      int j=jj&(m-1), gg=jj>>s;
      int kpos=(gg<<(s+1))+j;
      int tw=j<<(6-s);
      float wr=twr[tw], wi=-twi[tw];
      float vr=Br[kpos+m][lc],vi=Bi[kpos+m][lc];
      float t2r=vr*wr-vi*wi, t2i=vr*wi+vi*wr;
      float ur=Br[kpos][lc],ui=Bi[kpos][lc];
      Br[kpos][lc]=ur+t2r; Bi[kpos][lc]=ui+t2i;
      Br[kpos+m][lc]=ur-t2r; Bi[kpos+m][lc]=ui-t2i;
    }
    __syncthreads();
  }
  for (int i=tid;i<2048;i+=256){
    int r=i>>4, lc=i&15;
    tr[r*128+c0+lc]=Br[r][lc]; ti[r*128+c0+lc]=Bi[r][lc];
  }
}

// phase C: inverse DIT rows + conj(s)*./N + accumulate (16 rows per block)
__global__ __launch_bounds__(256) void k_fftC(const float* __restrict__ tmp, const float* __restrict__ sens,
                                              float* __restrict__ acc){
  int blk=blockIdx.x; int b=blk>>7, coil=(blk>>3)&15, rg=blk&7;
  int r0=rg*16;
  __shared__ float Ar[16][128], Ai[16][128];
  __shared__ float twr[64], twi[64];
  int tid=threadIdx.x;
  if (tid<64){ float ang=-2.f*PI_F*(float)tid/128.f; twr[tid]=cosf(ang); twi[tid]=sinf(ang); }
  const float* tr=tmp+(size_t)(b*16+coil)*2*L_;
  const float* ti=tr+L_;
  for (int i=tid;i<2048;i+=256){
    int lr=i>>7, w=i&127; int idx=(r0+lr)*128+w;
    Ar[lr][w]=tr[idx]; Ai[lr][w]=ti[idx];
  }
  __syncthreads();
  for (int s=0;s<7;s++){
    int m=1<<s;
    for (int q=tid;q<1024;q+=256){
      int lr=q>>6, jj=q&63;
      int j=jj&(m-1), gg=jj>>s;
      int kpos=(gg<<(s+1))+j;
      int tw=j<<(6-s);
      float wr=twr[tw], wi=-twi[tw];
      float vr=Ar[lr][kpos+m],vi=Ai[lr][kpos+m];
      float t2r=vr*wr-vi*wi, t2i=vr*wi+vi*wr;
      float ur=Ar[lr][kpos],ui=Ai[lr][kpos];
      Ar[lr][kpos]=ur+t2r; Ai[lr][kpos]=ui+t2i;
      Ar[lr][kpos+m]=ur-t2r; Ai[lr][kpos+m]=ui-t2i;
    }
    __syncthreads();
  }
  const float* srp=sens+(size_t)(b*32+2*coil)*L_;
  const float* sip=sens+(size_t)(b*32+2*coil+1)*L_;
  float* accr=acc+(size_t)(b*2)*L_;
  float* acci=accr+L_;
  for (int i=tid;i<2048;i+=256){
    int lr=i>>7, w=i&127; int gh=r0+lr; int idx=gh*128+w;
    float sc=(((gh+w)&1)?-1.f:1.f)*(1.f/16384.f);
    float wr2=Ar[lr][w]*sc, wi2=Ai[lr][w]*sc;
    float sr=srp[idx], si=sip[idx];
    atomicAdd(&accr[idx], sr*wr2+si*wi2);
    atomicAdd(&acci[idx], sr*wi2-si*wr2);
  }
}

__global__ void k_mag(const float* __restrict__ acc, float* __restrict__ out){
  int i=blockIdx.x*256+threadIdx.x;
  int b=i>>14, p=i&16383;
  float re=acc[(size_t)(b*2)*L_+p], im=acc[(size_t)(b*2+1)*L_+p];
  out[i]=sqrtf(re*re+im*im+1e-12f);
}

extern "C" void kernel_launch(void* const* d_in, const int* in_sizes, int n_in,
                              void* d_out, int out_size, void* d_ws, size_t ws_size,
                              hipStream_t stream){
  const float* in_imgs=(const float*)d_in[0];
  const float* in_ksp=(const float*)d_in[1];
  const float* mask=(const float*)d_in[2];
  const float* sens=(const float*)d_in[3];
  const float* pe_ln1_g=(const float*)d_in[4];
  const float* pe_ln1_b=(const float*)d_in[5];
  const float* pe_w=(const float*)d_in[6];
  const float* pe_b=(const float*)d_in[7];
  const float* pe_ln2_g=(const float*)d_in[8];
  const float* pe_ln2_b=(const float*)d_in[9];
  const float* pos_emb=(const float*)d_in[10];
  const float* enc_aln_g=(const float*)d_in[11];
  const float* enc_aln_b=(const float*)d_in[12];
  const float* enc_wqkv=(const float*)d_in[13];
  const float* enc_wo=(const float*)d_in[14];
  const float* enc_bo=(const float*)d_in[15];
  const float* enc_fln_g=(const float*)d_in[16];
  const float* enc_fln_b=(const float*)d_in[17];
  const float* enc_w1=(const float*)d_in[18];
  const float* enc_b1=(const float*)d_in[19];
  const float* enc_w2=(const float*)d_in[20];
  const float* enc_b2=(const float*)d_in[21];
  const float* enc_ng=(const float*)d_in[22];
  const float* enc_nb=(const float*)d_in[23];
  const float* dec_pos=(const float*)d_in[24];
  const float* dec_aln_g=(const float*)d_in[25];
  const float* dec_aln_b=(const float*)d_in[26];
  const float* dec_wqkv=(const float*)d_in[27];
  const float* dec_wo=(const float*)d_in[28];
  const float* dec_bo=(const float*)d_in[29];
  const float* dec_fln_g=(const float*)d_in[30];
  const float* dec_fln_b=(const float*)d_in[31];
  const float* dec_w1=(const float*)d_in[32];
  const float* dec_b1=(const float*)d_in[33];
  const float* dec_w2=(const float*)d_in[34];
  const float* dec_b2=(const float*)d_in[35];
  const float* dec_ng=(const float*)d_in[36];
  const float* dec_nb=(const float*)d_in[37];
  const float* fin_w=(const float*)d_in[38];
  const float* fin_b=(const float*)d_in[39];
  const float* ss_in_w=(const float*)d_in[40];
  const float* ss_in_b=(const float*)d_in[41];
  const float* ss_conv_w=(const float*)d_in[42];
  const float* ss_conv_b=(const float*)d_in[43];
  const float* ss_xproj=(const float*)d_in[44];
  const float* ss_dt_w=(const float*)d_in[45];
  const float* ss_dt_b=(const float*)d_in[46];
  const float* ss_Alog=(const float*)d_in[47];
  const float* ss_D=(const float*)d_in[48];
  const float* ss_ln_g=(const float*)d_in[49];
  const float* ss_ln_b=(const float*)d_in[50];
  const float* ss_out_w=(const float*)d_in[51];
  const float* ss_out_b=(const float*)d_in[52];
  const float* head_w=(const float*)d_in[53];
  const float* head_b=(const float*)d_in[54];
  const float* res_w1=(const float*)d_in[55];
  const float* res_b1=(const float*)d_in[56];
  const float* res_w2=(const float*)d_in[57];
  const float* res_b2=(const float*)d_in[58];
  const float* tail_w=(const float*)d_in[59];
  const float* tail_b=(const float*)d_in[60];
  const float* dc_alpha=(const float*)d_in[61];

  char* ws=(char*)d_ws;
  size_t off=0;
  auto alloc=[&](size_t nfloats)->float*{ float* p=(float*)(ws+off); off+=((nfloats*4+255)/256)*256; return p; };
  float* xn   =alloc((size_t)32*32768);
  float* stats=alloc(64);
  float* tA   =alloc(32*512);
  float* tB   =alloc(32*512);
  float* aln  =alloc(32*512);
  float* qkv  =alloc(32*1536);
  float* attno=alloc(32*512);
  float* ffh  =alloc(32*3072);
  float* xup  =alloc((size_t)2*4*L_);
  float* xz   =alloc((size_t)2*64*L_);
  float* xs0  =alloc((size_t)2*32*L_);
  float* xs0T =alloc((size_t)2*32*L_);
  float* dbl  =alloc((size_t)2*4*L_*18);
  float* ys   =alloc((size_t)2*4*32*L_);
  float* smv  =alloc((size_t)8*128*256*2);   // float2 summaries
  float* prев =alloc((size_t)8*128*256);
  float* oss  =alloc((size_t)2*20*L_);
  float* xc   =alloc((size_t)2*56*L_);
  float* h0   =alloc((size_t)2*64*L_);
  float* tmpc =alloc((size_t)2*64*L_);
  float* csc  =alloc((size_t)2*2*64*L_);
  float* x_ri =alloc((size_t)2*2*L_);
  float* ftmp =alloc((size_t)32*2*L_);
  float* accb =alloc((size_t)2*2*L_);
  (void)ws_size; (void)in_sizes; (void)n_in; (void)out_size;

  // ---- patch embed + encoder/decoder ----
  hipMemsetAsync(stats, 0, 64*4, stream);
  k_pesum<<<256,256,0,stream>>>(in_imgs, stats);
  k_penorm<<<256,256,0,stream>>>(in_imgs, stats, pe_ln1_g, pe_ln1_b, xn);
  hipMemsetAsync(tA, 0, 32*512*4, stream);
  k_gemm_sk<256,0><<<dim3(8,128),256,0,stream>>>(xn, pe_w, pe_b, tA, 512, 32768);
  k_pe_post<<<32,256,0,stream>>>(tA, pe_ln2_g, pe_ln2_b, pos_emb);

  for (int i=0;i<4;i++){
    k_ln_tok<<<32,256,0,stream>>>(tA, enc_aln_g+i*512, enc_aln_b+i*512, aln);
    hipMemsetAsync(qkv, 0, 32*1536*4, stream);
    k_gemm_sk<64,0><<<dim3(24,8),256,0,stream>>>(aln, enc_wqkv+(size_t)i*512*1536, nullptr, qkv, 1536, 512);
    k_attn<<<16,256,0,stream>>>(qkv, attno);
    k_gemm_sk<64,0><<<dim3(8,8),256,0,stream>>>(attno, enc_wo+(size_t)i*512*512, enc_bo+i*512, tA, 512, 512);
    k_ln_tok<<<32,256,0,stream>>>(tA, enc_fln_g+i*512, enc_fln_b+i*512, aln);
    hipMemsetAsync(ffh, 0, 32*2048*4, stream);
    k_gemm_sk<64,0><<<dim3(32,8),256,0,stream>>>(aln, enc_w1+(size_t)i*512*2048, enc_b1+i*2048, ffh, 2048, 512);
    k_gemm_sk<64,1><<<dim3(8,32),256,0,stream>>>(ffh, enc_w2+(size_t)i*2048*512, enc_b2+i*512, tA, 512, 2048);
  }
  k_ln_tok<<<32,256,0,stream>>>(tA, enc_ng, enc_nb, tA);
  k_addpos<<<64,256,0,stream>>>(tA, dec_pos, tB);
  k_ln_tok<<<32,256,0,stream>>>(tB, dec_aln_g, dec_aln_b, aln);
  hipMemsetAsync(qkv, 0, 32*1536*4, stream);
  k_gemm_sk<64,0><<<dim3(24,8),256,0,stream>>>(aln, dec_wqkv, nullptr, qkv, 1536, 512);
  k_attn<<<16,256,0,stream>>>(qkv, attno);
  k_gemm_sk<64,0><<<dim3(8,8),256,0,stream>>>(attno, dec_wo, dec_bo, tB, 512, 512);
  k_ln_tok<<<32,256,0,stream>>>(tB, dec_fln_g, dec_fln_b, aln);
  hipMemsetAsync(ffh, 0, 32*3072*4, stream);
  k_gemm_sk<64,0><<<dim3(48,8),256,0,stream>>>(aln, dec_w1, dec_b1, ffh, 3072, 512);
  k_gemm_sk<64,1><<<dim3(8,48),256,0,stream>>>(ffh, dec_w2, dec_b2, tB, 512, 3072);
  k_ln_tok<<<32,256,0,stream>>>(tB, dec_ng, dec_nb, tB);
  hipMemsetAsync(xup, 0, (size_t)2*4*L_*4, stream);
  k_gemm_sk<64,2><<<dim3(64,8),256,0,stream>>>(tB, fin_w, fin_b, xup, 4096, 512);

  // ---- SS2D ----
  k_xz<<<128,256,0,stream>>>(in_ksp, ss_in_w, ss_in_b, xz);
  k_dwconv<<<4096,256,0,stream>>>(xz, ss_conv_w, ss_conv_b, xs0);
  k_transpose<<<dim3(4,4,64),256,0,stream>>>(xs0, xs0T);
  k_dbl<<<dim3(64,8),256,0,stream>>>(xs0, xs0T, ss_xproj, dbl);
  k_scan1<<<1024,256,0,stream>>>(dbl, xs0, xs0T, ss_dt_w, ss_dt_b, ss_Alog, (float2*)smv);
  k_scan2<<<8,256,0,stream>>>((const float2*)smv, prев);
  k_scan3<<<1024,256,0,stream>>>(dbl, xs0, xs0T, ss_dt_w, ss_dt_b, ss_Alog, ss_D, prев, ys);
  k_ycomb<<<128,256,0,stream>>>(ys, xz, ss_ln_g, ss_ln_b, ss_out_w, ss_out_b, oss);

  // ---- conv head ----
  k_concat<<<7168,256,0,stream>>>(xup, in_imgs, oss, xc);
  k_conv3s<4><<<dim3(16,16,4),256,0,stream>>>(xc, head_w, csc, 56, 64, 28);
  k_epi<<<8192,256,0,stream>>>(csc, head_b, nullptr, h0, 64, 1);
  for (int i=0;i<3;i++){
    k_conv3s<4><<<dim3(16,16,4),256,0,stream>>>(h0, res_w1+(size_t)i*64*64*9, csc, 64, 64, 32);
    k_epi<<<8192,256,0,stream>>>(csc, res_b1+i*64, nullptr, tmpc, 64, 1);
    k_conv3s<4><<<dim3(16,16,4),256,0,stream>>>(tmpc, res_w2+(size_t)i*64*64*9, csc, 64, 64, 32);
    k_epi<<<8192,256,0,stream>>>(csc, res_b2+i*64, h0, h0, 64, 1);
  }
  k_conv3s<2><<<dim3(16,1,4),256,0,stream>>>(h0, tail_w, csc, 64, 2, 32);
  k_epi<<<256,256,0,stream>>>(csc, tail_b, nullptr, x_ri, 2, 0);

  // ---- FFT data consistency ----
  hipMemsetAsync(accb, 0, (size_t)2*2*L_*4, stream);
  k_fftA<<<256,256,0,stream>>>(x_ri, sens, ftmp);
  k_fftB<<<256,256,0,stream>>>(ftmp, in_ksp, mask, dc_alpha);
  k_fftC<<<256,256,0,stream>>>(ftmp, sens, accb);
  k_mag<<<128,256,0,stream>>>(accb, (float*)d_out);
}

// Round 6
// 1582.430 us; speedup vs baseline: 3.8157x; 1.1327x over previous
//
#include <hip/hip_runtime.h>

#define PI_F 3.14159265358979323846f

constexpr int L_ = 16384;   // H*W
constexpr int PD_ = 32768;  // P*P*C

__device__ __forceinline__ float sigmoidf_(float x){ return 1.f/(1.f+__expf(-x)); }
__device__ __forceinline__ float softplusf_(float x){ return x>20.f ? x : log1pf(__expf(x)); }
__device__ __forceinline__ float geluf_(float x){ return 0.5f*x*(1.f+erff(x*0.70710678118654752f)); }

__device__ __forceinline__ float2 block_reduce2(float s, float ss){
  __shared__ float r1[256], r2[256];
  int tid = threadIdx.x;
  r1[tid]=s; r2[tid]=ss; __syncthreads();
  for(int o=128;o>0;o>>=1){ if(tid<o){ r1[tid]+=r1[tid+o]; r2[tid]+=r2[tid+o]; } __syncthreads(); }
  float2 out; out.x=r1[0]; out.y=r2[0]; __syncthreads();
  return out;
}

// ---------------- patch embed ----------------
__global__ __launch_bounds__(256) void k_pesum(const float* __restrict__ img, float* __restrict__ stats){
  int blk=blockIdx.x; int m=blk>>3, sl=blk&7;
  int b=m>>4, n=m&15, ih=n>>2, iw=n&3;
  int tid=threadIdx.x;
  const float* base=img+(size_t)b*32*L_;
  float s=0.f, ss=0.f;
  for (int i=tid;i<4096;i+=256){
    int j=sl*4096+i;
    int c=j>>10, p1=(j>>5)&31, p2=j&31;
    float v=base[(size_t)c*L_+(ih*32+p1)*128+iw*32+p2];
    s+=v; ss+=v*v;
  }
  float2 r=block_reduce2(s,ss);
  if (tid==0){ atomicAdd(&stats[m*2],r.x); atomicAdd(&stats[m*2+1],r.y); }
}

__global__ __launch_bounds__(256) void k_penorm(const float* __restrict__ img, const float* __restrict__ stats,
                                                const float* __restrict__ g, const float* __restrict__ bv,
                                                float* __restrict__ xn){
  int blk=blockIdx.x; int m=blk>>3, sl=blk&7;
  int b=m>>4, n=m&15, ih=n>>2, iw=n&3;
  int tid=threadIdx.x;
  const float* base=img+(size_t)b*32*L_;
  float mean=stats[m*2]/(float)PD_;
  float var =stats[m*2+1]/(float)PD_-mean*mean;
  float inv =1.f/sqrtf(var+1e-5f);
  for (int i=tid;i<4096;i+=256){
    int j=sl*4096+i;
    int c=j>>10, p1=(j>>5)&31, p2=j&31;
    float v=base[(size_t)c*L_+(ih*32+p1)*128+iw*32+p2];
    int k=(p1*32+p2)*32+c;
    xn[(size_t)m*PD_+k]=(v-mean)*inv*g[k]+bv[k];
  }
}

// split-K skinny GEMM
template<int KC, int MODE>
__global__ __launch_bounds__(256) void k_gemm_sk(const float* __restrict__ A, const float* __restrict__ Bw,
                                                 const float* __restrict__ bias, float* __restrict__ C,
                                                 int N, int K){
  __shared__ float As[32][KC];
  int tid=threadIdx.x, tx=tid&63, ty=tid>>6;
  int n = blockIdx.x*64+tx;
  int k0 = blockIdx.y*KC;
  for (int i=tid;i<32*KC;i+=256){
    int r=i/KC, c=i%KC;
    float v=A[(size_t)r*K + k0 + c];
    if (MODE==1) v=geluf_(v);
    As[r][c]=v;
  }
  __syncthreads();
  float acc[8]={0,0,0,0,0,0,0,0};
  for (int kk=0;kk<KC;kk+=4){
    float b0=Bw[(size_t)(k0+kk)*N+n],   b1=Bw[(size_t)(k0+kk+1)*N+n];
    float b2=Bw[(size_t)(k0+kk+2)*N+n], b3=Bw[(size_t)(k0+kk+3)*N+n];
    #pragma unroll
    for (int r=0;r<8;r++){
      const float4 a=*(const float4*)&As[ty*8+r][kk];
      acc[r]+=a.x*b0+a.y*b1+a.z*b2+a.w*b3;
    }
  }
  bool addb = (bias!=nullptr) && (blockIdx.y==0);
  #pragma unroll
  for (int r=0;r<8;r++){
    int m=ty*8+r;
    float v=acc[r]+(addb?bias[n]:0.f);
    if (MODE==2){
      int b=m>>4, ih=(m>>2)&3, iw=m&3;
      int cu=n>>10, f1=(n>>5)&31, f2=n&31;
      atomicAdd(&C[((size_t)(b*4+cu)*128+ih*32+f1)*128+iw*32+f2], v);
    } else {
      atomicAdd(&C[(size_t)m*N+n], v);
    }
  }
}

__global__ __launch_bounds__(256) void k_pe_post(float* __restrict__ t,
                                                 const float* __restrict__ g, const float* __restrict__ bv,
                                                 const float* __restrict__ pos){
  int m=blockIdx.x, tid=threadIdx.x;
  float v0 = t[m*512+tid];
  float v1 = t[m*512+256+tid];
  float2 r = block_reduce2(v0+v1, v0*v0+v1*v1);
  float mean=r.x/512.f, var=r.y/512.f-mean*mean, inv=1.f/sqrtf(var+1e-5f);
  int n = m&15;
  t[m*512+tid]     = (v0-mean)*inv*g[tid]+bv[tid]         + pos[n*512+tid];
  t[m*512+256+tid] = (v1-mean)*inv*g[256+tid]+bv[256+tid] + pos[n*512+256+tid];
}

__global__ __launch_bounds__(256) void k_ln_tok(const float* __restrict__ src, const float* __restrict__ g,
                                                const float* __restrict__ bv, float* __restrict__ dst){
  int m=blockIdx.x, tid=threadIdx.x;
  float v0=src[m*512+tid], v1=src[m*512+256+tid];
  float2 r=block_reduce2(v0+v1, v0*v0+v1*v1);
  float mean=r.x/512.f, var=r.y/512.f-mean*mean, inv=1.f/sqrtf(var+1e-5f);
  dst[m*512+tid]     =(v0-mean)*inv*g[tid]+bv[tid];
  dst[m*512+256+tid] =(v1-mean)*inv*g[256+tid]+bv[256+tid];
}

__global__ void k_addpos(const float* __restrict__ t, const float* __restrict__ pos, float* __restrict__ dst){
  int i = blockIdx.x*256+threadIdx.x;
  int m=i>>9, j=i&511;
  dst[i]=t[i]+pos[(m&15)*512+j];
}

__global__ __launch_bounds__(256) void k_attn(const float* __restrict__ qkv, float* __restrict__ outb){
  int bh=blockIdx.x, b=bh>>3, h=bh&7, tid=threadIdx.x;
  __shared__ float q[16][64], kk[16][64], vv[16][64], pp[16][16];
  for (int i=tid;i<1024;i+=256){
    int row=i>>6, d=i&63;
    const float* src=qkv + (size_t)(b*16+row)*1536 + h*64+d;
    q[row][d]=src[0]; kk[row][d]=src[512]; vv[row][d]=src[1024];
  }
  __syncthreads();
  int i=tid>>4, j=tid&15;
  float s=0.f;
  #pragma unroll
  for (int d=0;d<64;d++) s+=q[i][d]*kk[j][d];
  s*=0.125f;
  float mx=s;
  for (int o=8;o>0;o>>=1) mx=fmaxf(mx,__shfl_xor(mx,o,16));
  float e=__expf(s-mx), sm=e;
  for (int o=8;o>0;o>>=1) sm+=__shfl_xor(sm,o,16);
  pp[i][j]=e/sm;
  __syncthreads();
  int d=tid&63;
  for (int pass=0;pass<4;pass++){
    int row=pass*4+(tid>>6);
    float acc=0.f;
    #pragma unroll
    for (int jj=0;jj<16;jj++) acc+=pp[row][jj]*vv[jj][d];
    outb[(size_t)(b*16+row)*512 + h*64+d]=acc;
  }
}

// ---------------- SS2D ----------------
__global__ __launch_bounds__(256) void k_xz(const float* __restrict__ ksp, const float* __restrict__ w,
                                            const float* __restrict__ bv, float* __restrict__ xz){
  int blk=blockIdx.x; int b=blk>>6; int p0=(blk&63)*256; int tid=threadIdx.x;
  __shared__ float lin[32][256];
  __shared__ float lw[2048];
  for (int i=tid;i<2048;i+=256) lw[i]=w[i];
  for (int i=tid;i<8192;i+=256){ int c=i>>8, p=i&255; lin[c][p]=ksp[(size_t)(b*32+c)*L_+p0+p]; }
  __syncthreads();
  float xv[32];
  #pragma unroll
  for (int c=0;c<32;c++) xv[c]=lin[c][tid];
  for (int e=0;e<64;e++){
    float a=bv[e];
    #pragma unroll
    for (int c=0;c<32;c++) a+=xv[c]*lw[c*64+e];
    xz[(size_t)(b*64+e)*L_+p0+tid]=a;
  }
}

__global__ void k_dwconv(const float* __restrict__ xz, const float* __restrict__ w,
                         const float* __restrict__ bv, float* __restrict__ xs0){
  int i=blockIdx.x*256+threadIdx.x;
  int p=i&16383; int d=(i>>14)&31; int b=i>>19;
  int h=p>>7, ww=p&127;
  const float* src=xz+(size_t)(b*64+d)*L_;
  float acc=bv[d];
  for (int ky=0;ky<3;ky++){
    int hh=h+ky-1; if(hh<0||hh>127) continue;
    for (int kx=0;kx<3;kx++){
      int wx=ww+kx-1; if(wx<0||wx>127) continue;
      acc+=src[hh*128+wx]*w[d*9+ky*3+kx];
    }
  }
  xs0[(size_t)(b*32+d)*L_+p]=acc*sigmoidf_(acc);
}

__global__ __launch_bounds__(256) void k_transpose(const float* __restrict__ src, float* __restrict__ dst){
  __shared__ float tile[32][33];
  int z=blockIdx.z;
  int h0=blockIdx.y*32, w0=blockIdx.x*32;
  int tid=threadIdx.x, tx=tid&31, ty=tid>>5;
  const float* s=src+(size_t)z*L_;
  float* d=dst+(size_t)z*L_;
  for (int r=ty;r<32;r+=8) tile[r][tx]=s[(h0+r)*128+w0+tx];
  __syncthreads();
  for (int r=ty;r<32;r+=8) d[(w0+r)*128+h0+tx]=tile[tx][r];
}

__global__ __launch_bounds__(256) void k_dbl(const float* __restrict__ xs0, const float* __restrict__ xs0T,
                                             const float* __restrict__ xproj, float* __restrict__ dbl){
  int bk=blockIdx.y; int b=bk>>2, k=bk&3;
  int l0=blockIdx.x*256, tid=threadIdx.x;
  const float* src=(k&1)?xs0T:xs0;
  __shared__ float xv[32][256];
  __shared__ float xp[576];
  for (int i=tid;i<576;i+=256) xp[i]=xproj[k*576+i];
  for (int i=tid;i<8192;i+=256){
    int dd=i>>8, p=i&255; int l=l0+p; int li=(k<2)?l:(16383-l);
    xv[dd][p]=src[(size_t)(b*32+dd)*L_+li];
  }
  __syncthreads();
  float xr[32];
  #pragma unroll
  for (int dd=0;dd<32;dd++) xr[dd]=xv[dd][tid];
  float* out=&dbl[((size_t)(b*4+k)*L_ + l0+tid)*18];
  for (int c=0;c<18;c++){
    float a=0.f;
    #pragma unroll
    for (int dd=0;dd<32;dd++) a+=xr[dd]*xp[dd*18+c];
    out[c]=a;
  }
}

// ---- chunked 3-phase selective scan (v2: dedup'd softplus, padded LDS) ----
// phase1: block=(bk,chunk of 128), thread=(d,s). Precompute (dt,u) cooperatively,
// then per-thread local scan -> summary (P,Q)
__global__ __launch_bounds__(256) void k_scan1(const float* __restrict__ dbl, const float* __restrict__ xs0,
                                               const float* __restrict__ xs0T, const float* __restrict__ dtw,
                                               const float* __restrict__ dtb, const float* __restrict__ Alog,
                                               float2* __restrict__ sm){
  int blk=blockIdx.x; int bk=blk>>7, c=blk&127;
  int b=bk>>2, k=bk&3;
  int tid=threadIdx.x, d=tid>>3, s=tid&7;
  __shared__ float ed[128][18];
  __shared__ float2 du[32][129];
  const float* dbase=dbl+((size_t)bk*L_+c*128)*18;
  for (int i=tid;i<2304;i+=256) ((float*)ed)[i]=dbase[i];
  __syncthreads();
  const float* src=(k&1)?xs0T:xs0;
  bool rev=(k>=2);
  for (int i=tid;i<4096;i+=256){
    int dd=i>>7, j=i&127; int l=c*128+j;
    float xsv=src[(size_t)(b*32+dd)*L_+(rev?(16383-l):l)];
    float w0=dtw[(k*2+0)*32+dd], w1=dtw[(k*2+1)*32+dd], bb=dtb[k*32+dd];
    float dt=softplusf_(ed[j][0]*w0+ed[j][1]*w1+bb);
    du[dd][j]=make_float2(dt, dt*xsv);
  }
  __syncthreads();
  float Av=-__expf(Alog[(k*32+d)*8+s]);
  float P=1.f, Q=0.f;
  for (int j=0;j<128;j++){
    float2 v=du[d][j];
    float a=__expf(v.x*Av);
    Q=a*Q+v.y*ed[j][2+s];
    P*=a;
  }
  sm[((size_t)bk*128+c)*256+tid]=make_float2(P,Q);
}

// phase2: per (bk) stitch 128 chunk summaries with batched loads
__global__ __launch_bounds__(256) void k_scan2(const float2* __restrict__ sm, float* __restrict__ pre){
  int bk=blockIdx.x, tid=threadIdx.x;
  float run=0.f;
  for (int cb=0; cb<128; cb+=16){
    float2 v[16];
    #pragma unroll
    for (int t=0;t<16;t++) v[t]=sm[((size_t)bk*128+cb+t)*256+tid];
    #pragma unroll
    for (int t=0;t<16;t++){
      pre[((size_t)bk*128+cb+t)*256+tid]=run;
      run=v[t].x*run+v[t].y;
    }
  }
}

// phase3: rescan with injected prefix, y = sum_s h*C written directly (D-term moved to ycomb)
__global__ __launch_bounds__(256) void k_scan3(const float* __restrict__ dbl, const float* __restrict__ xs0,
                                               const float* __restrict__ xs0T, const float* __restrict__ dtw,
                                               const float* __restrict__ dtb, const float* __restrict__ Alog,
                                               const float* __restrict__ pre, float* __restrict__ ys){
  int blk=blockIdx.x; int bk=blk>>7, c=blk&127;
  int b=bk>>2, k=bk&3;
  int tid=threadIdx.x, d=tid>>3, s=tid&7;
  __shared__ float ed[128][18];
  __shared__ float2 du[32][129];
  const float* dbase=dbl+((size_t)bk*L_+c*128)*18;
  for (int i=tid;i<2304;i+=256) ((float*)ed)[i]=dbase[i];
  __syncthreads();
  const float* src=(k&1)?xs0T:xs0;
  bool rev=(k>=2);
  for (int i=tid;i<4096;i+=256){
    int dd=i>>7, j=i&127; int l=c*128+j;
    float xsv=src[(size_t)(b*32+dd)*L_+(rev?(16383-l):l)];
    float w0=dtw[(k*2+0)*32+dd], w1=dtw[(k*2+1)*32+dd], bb=dtb[k*32+dd];
    float dt=softplusf_(ed[j][0]*w0+ed[j][1]*w1+bb);
    du[dd][j]=make_float2(dt, dt*xsv);
  }
  __syncthreads();
  float Av=-__expf(Alog[(k*32+d)*8+s]);
  float h=pre[((size_t)bk*128+c)*256+tid];
  float* yout=ys+((size_t)bk*32+d)*L_+c*128;
  for (int j=0;j<128;j++){
    float2 v=du[d][j];
    float a=__expf(v.x*Av);
    h=a*h+v.y*ed[j][2+s];
    float yp=h*ed[j][10+s];
    yp+=__shfl_xor(yp,1,8);
    yp+=__shfl_xor(yp,2,8);
    yp+=__shfl_xor(yp,4,8);
    if (s==0) yout[j]=yp;
  }
}

// combine 4 directions + Dsum*xs + LN + *silu(z) + out proj; 2-team d-split
__global__ __launch_bounds__(256) void k_ycomb(const float* __restrict__ ys, const float* __restrict__ xz,
                                               const float* __restrict__ xs0, const float* __restrict__ Dp,
                                               const float* __restrict__ g, const float* __restrict__ bv,
                                               const float* __restrict__ ow, const float* __restrict__ ob,
                                               float* __restrict__ oss){
  int blk=blockIdx.x; int b=blk>>7; int pg=blk&127;
  int tid=threadIdx.x; int pos=tid&127; int team=tid>>7;
  int p=pg*128+pos;
  int lt=pos*128+pg;
  __shared__ float lw[640]; __shared__ float lb[20]; __shared__ float lg[32], lbv[32], lD[32];
  __shared__ float red[2][2][128];
  __shared__ float prj[128][21];
  for (int i=tid;i<640;i+=256) lw[i]=ow[i];
  if (tid<20) lb[tid]=ob[tid];
  if (tid<32){ lg[tid]=g[tid]; lbv[tid]=bv[tid]; lD[tid]=Dp[tid]+Dp[32+tid]+Dp[64+tid]+Dp[96+tid]; }
  __syncthreads();
  size_t base=(size_t)b*128*L_;
  int d0=team*16;
  float y[16];
  float s=0.f, ss=0.f;
  #pragma unroll
  for (int dd=0;dd<16;dd++){
    int d=d0+dd;
    float v=ys[base+(size_t)(0*32+d)*L_+p] + ys[base+(size_t)(2*32+d)*L_+16383-p]
          + ys[base+(size_t)(1*32+d)*L_+lt] + ys[base+(size_t)(3*32+d)*L_+16383-lt]
          + lD[d]*xs0[(size_t)(b*32+d)*L_+p];
    y[dd]=v; s+=v; ss+=v*v;
  }
  red[team][0][pos]=s; red[team][1][pos]=ss;
  __syncthreads();
  float S=red[0][0][pos]+red[1][0][pos];
  float SS=red[0][1][pos]+red[1][1][pos];
  float mean=S/32.f, var=SS/32.f-mean*mean, inv=1.f/sqrtf(var+1e-5f);
  float pc[20];
  #pragma unroll
  for (int c2=0;c2<20;c2++) pc[c2]=0.f;
  #pragma unroll
  for (int dd=0;dd<16;dd++){
    int d=d0+dd;
    float yn=(y[dd]-mean)*inv*lg[d]+lbv[d];
    float zv=xz[(size_t)(b*64+32+d)*L_+p];
    float t2=yn*(zv*sigmoidf_(zv));
    #pragma unroll
    for (int c2=0;c2<20;c2++) pc[c2]+=t2*lw[d*20+c2];
  }
  if (team==1){
    #pragma unroll
    for (int c2=0;c2<20;c2++) prj[pos][c2]=pc[c2];
  }
  __syncthreads();
  if (team==0){
    #pragma unroll
    for (int c2=0;c2<20;c2++) oss[(size_t)(b*20+c2)*L_+p]=lb[c2]+pc[c2]+prj[pos][c2];
  }
}

__global__ void k_concat(const float* __restrict__ x, const float* __restrict__ img,
                         const float* __restrict__ oss, float* __restrict__ xc){
  int i=blockIdx.x*256+threadIdx.x;
  int p=i&16383; int ch=(i>>14)%56; int b=i/(56*16384);
  float v;
  if (ch<4) v=x[(size_t)(b*4+ch)*L_+p];
  else if (ch<36) v=img[(size_t)(b*32+ch-4)*L_+p];
  else v=oss[(size_t)(b*20+ch-36)*L_+p];
  xc[i]=v;
}

// ---- fast conv3x3 ----
template<int NCO>
__global__ __launch_bounds__(256) void k_conv3s(const float* __restrict__ in, const float* __restrict__ wt,
                                                float* __restrict__ sc, int Cin, int Cout, int CIS){
  int tile=blockIdx.x; int th0=(tile>>2)*32, tw0=(tile&3)*32;
  int cg=blockIdx.y;
  int bz=blockIdx.z; int b=bz>>1, ks=bz&1;
  int cibase=ks*CIS;
  int cic=Cin-cibase; if (cic>CIS) cic=CIS;
  __shared__ float wlds[32][NCO][9];
  __shared__ float ibuf[2][34][34];
  int tid=threadIdx.x;
  for (int i=tid;i<cic*NCO*9;i+=256){
    int ci=i/(NCO*9), rem=i%(NCO*9), co=rem/9, q=rem%9;
    wlds[ci][co][q]=wt[(((size_t)(cg*NCO+co))*Cin + cibase+ci)*9+q];
  }
  auto stage=[&](int buf, int ci){
    const float* src=in+((size_t)b*Cin+cibase+ci)*L_;
    for (int i=tid;i<34*34;i+=256){
      int r=i/34, c=i%34;
      int gh=th0+r-1, gw=tw0+c-1;
      ibuf[buf][r][c]=(gh>=0&&gh<128&&gw>=0&&gw<128)?src[gh*128+gw]:0.f;
    }
  };
  stage(0,0);
  __syncthreads();
  float acc[NCO][4];
  #pragma unroll
  for (int co=0;co<NCO;co++){acc[co][0]=0.f;acc[co][1]=0.f;acc[co][2]=0.f;acc[co][3]=0.f;}
  int tr=((tid>>4)&15)<<1, tc=(tid&15)<<1;
  for (int ci=0;ci<cic;ci++){
    int cur=ci&1;
    if (ci+1<cic) stage(cur^1, ci+1);
    float iv[4][4];
    #pragma unroll
    for (int dr=0;dr<4;dr++)
      #pragma unroll
      for (int dc=0;dc<4;dc++) iv[dr][dc]=ibuf[cur][tr+dr][tc+dc];
    #pragma unroll
    for (int co=0;co<NCO;co++){
      float w0=wlds[ci][co][0],w1=wlds[ci][co][1],w2=wlds[ci][co][2];
      float w3=wlds[ci][co][3],w4=wlds[ci][co][4],w5=wlds[ci][co][5];
      float w6=wlds[ci][co][6],w7=wlds[ci][co][7],w8=wlds[ci][co][8];
      acc[co][0]+=iv[0][0]*w0+iv[0][1]*w1+iv[0][2]*w2
                 +iv[1][0]*w3+iv[1][1]*w4+iv[1][2]*w5
                 +iv[2][0]*w6+iv[2][1]*w7+iv[2][2]*w8;
      acc[co][1]+=iv[0][1]*w0+iv[0][2]*w1+iv[0][3]*w2
                 +iv[1][1]*w3+iv[1][2]*w4+iv[1][3]*w5
                 +iv[2][1]*w6+iv[2][2]*w7+iv[2][3]*w8;
      acc[co][2]+=iv[1][0]*w0+iv[1][1]*w1+iv[1][2]*w2
                 +iv[2][0]*w3+iv[2][1]*w4+iv[2][2]*w5
                 +iv[3][0]*w6+iv[3][1]*w7+iv[3][2]*w8;
      acc[co][3]+=iv[1][1]*w0+iv[1][2]*w1+iv[1][3]*w2
                 +iv[2][1]*w3+iv[2][2]*w4+iv[2][3]*w5
                 +iv[3][1]*w6+iv[3][2]*w7+iv[3][3]*w8;
    }
    __syncthreads();
  }
  #pragma unroll
  for (int co=0;co<NCO;co++){
    int gco=cg*NCO+co;
    float* dst=sc+((size_t)((ks*2+b)*Cout+gco))*L_+(size_t)(th0+tr)*128+tw0+tc;
    float2 a={acc[co][0],acc[co][1]}, c={acc[co][2],acc[co][3]};
    *(float2*)dst=a;
    *(float2*)(dst+128)=c;
  }
}

__global__ void k_epi(const float* __restrict__ sc, const float* __restrict__ bias,
                      const float* __restrict__ res, float* __restrict__ out, int Cout, int act){
  int i=blockIdx.x*256+threadIdx.x;
  int co=(i/L_)%Cout;
  size_t half=(size_t)2*Cout*L_;
  float v=sc[i]+sc[half+i]+bias[co];
  if (res) v+=res[i];
  if (act) v=v>0.f?v:0.2f*v;
  out[i]=v;
}

// ---------------- FFT data consistency (3-way split) ----------------
__device__ __forceinline__ int rev7(int x){
  return ((x&1)<<6)|((x&2)<<4)|((x&4)<<2)|(x&8)|((x&16)>>2)|((x&32)>>4)|((x&64)>>6);
}

__global__ __launch_bounds__(256) void k_fftA(const float* __restrict__ x_ri, const float* __restrict__ sens,
                                              float* __restrict__ tmp){
  int blk=blockIdx.x; int b=blk>>7, coil=(blk>>3)&15, rg=blk&7;
  int r0=rg*16;
  __shared__ float Ar[16][128], Ai[16][128];
  __shared__ float twr[64], twi[64];
  int tid=threadIdx.x;
  if (tid<64){ float ang=-2.f*PI_F*(float)tid/128.f; twr[tid]=cosf(ang); twi[tid]=sinf(ang); }
  const float* srp=sens+(size_t)(b*32+2*coil)*L_;
  const float* sip=sens+(size_t)(b*32+2*coil+1)*L_;
  const float* xrp=x_ri+(size_t)(b*2)*L_;
  const float* xip=xrp+L_;
  for (int i=tid;i<2048;i+=256){
    int lr=i>>7, w=i&127; int gh=r0+lr; int idx=gh*128+w;
    float sg=((gh+w)&1)?-1.f:1.f;
    float sr=srp[idx],si=sip[idx],xr=xrp[idx],xi=xip[idx];
    Ar[lr][w]=sg*(sr*xr-si*xi);
    Ai[lr][w]=sg*(sr*xi+si*xr);
  }
  __syncthreads();
  for (int s=0;s<7;s++){
    int m=64>>s;
    for (int q=tid;q<1024;q+=256){
      int lr=q>>6, jj=q&63;
      int j=jj&(m-1), gg=jj>>(6-s);
      int kpos=(gg<<(7-s))+j;
      int tw=j<<s;
      float ur=Ar[lr][kpos],ui=Ai[lr][kpos],vr=Ar[lr][kpos+m],vi=Ai[lr][kpos+m];
      Ar[lr][kpos]=ur+vr; Ai[lr][kpos]=ui+vi;
      float dr=ur-vr,di=ui-vi,wr=twr[tw],wi=twi[tw];
      Ar[lr][kpos+m]=dr*wr-di*wi; Ai[lr][kpos+m]=dr*wi+di*wr;
    }
    __syncthreads();
  }
  float* tr=tmp+(size_t)(b*16+coil)*2*L_;
  float* ti=tr+L_;
  for (int i=tid;i<2048;i+=256){
    int lr=i>>7, w=i&127; int idx=(r0+lr)*128+w;
    tr[idx]=Ar[lr][w]; ti[idx]=Ai[lr][w];
  }
}

__global__ __launch_bounds__(256) void k_fftB(float* __restrict__ tmp, const float* __restrict__ ksp,
                                              const float* __restrict__ mask, const float* __restrict__ alpha_p){
  int blk=blockIdx.x; int b=blk>>7, coil=(blk>>3)&15, cg=blk&7;
  int c0=cg*16;
  __shared__ float Br[128][17], Bi[128][17];
  __shared__ float twr[64], twi[64];
  int tid=threadIdx.x;
  if (tid<64){ float ang=-2.f*PI_F*(float)tid/128.f; twr[tid]=cosf(ang); twi[tid]=sinf(ang); }
  float* tr=tmp+(size_t)(b*16+coil)*2*L_;
  float* ti=tr+L_;
  for (int i=tid;i<2048;i+=256){
    int r=i>>4, lc=i&15;
    Br[r][lc]=tr[r*128+c0+lc]; Bi[r][lc]=ti[r*128+c0+lc];
  }
  __syncthreads();
  for (int s=0;s<7;s++){
    int m=64>>s;
    for (int q=tid;q<1024;q+=256){
      int lc=q&15, jj=q>>4;
      int j=jj&(m-1), gg=jj>>(6-s);
      int kpos=(gg<<(7-s))+j;
      int tw=j<<s;
      float ur=Br[kpos][lc],ui=Bi[kpos][lc],vr=Br[kpos+m][lc],vi=Bi[kpos+m][lc];
      Br[kpos][lc]=ur+vr; Bi[kpos][lc]=ui+vi;
      float dr=ur-vr,di=ui-vi,wr=twr[tw],wi=twi[tw];
      Br[kpos+m][lc]=dr*wr-di*wi; Bi[kpos+m][lc]=dr*wi+di*wr;
    }
    __syncthreads();
  }
  float alpha=alpha_p[0];
  const float* krp=ksp+(size_t)(b*32+2*coil)*L_;
  const float* kip=ksp+(size_t)(b*32+2*coil+1)*L_;
  const float* mkp=mask+(size_t)b*L_;
  for (int i=tid;i<2048;i+=256){
    int r=i>>4, lc=i&15;
    int k1=rev7(r), k2=rev7(c0+lc);
    int kidx=k1*128+k2;
    float mv=mkp[kidx]*alpha;
    float sg=((k1+k2)&1)?-128.f:128.f;
    float kr=krp[kidx]*100.f*sg, ki=kip[kidx]*100.f*sg;
    Br[r][lc]=(1.f-mv)*Br[r][lc]+mv*kr;
    Bi[r][lc]=(1.f-mv)*Bi[r][lc]+mv*ki;
  }
  __syncthreads();
  for (int s=0;s<7;s++){
    int m=1<<s;
    for (int q=tid;q<1024;q+=256){
      int lc=q&15, jj=q>>4;
      int j=jj&(m-1), gg=jj>>s;
      int kpos=(gg<<(s+1))+j;
      int tw=j<<(6-s);
      float wr=twr[tw], wi=-twi[tw];
      float vr=Br[kpos+m][lc],vi=Bi[kpos+m][lc];
      float t2r=vr*wr-vi*wi, t2i=vr*wi+vi*wr;
      float ur=Br[kpos][lc],ui=Bi[kpos][lc];
      Br[kpos][lc]=ur+t2r; Bi[kpos][lc]=ui+t2i;
      Br[kpos+m][lc]=ur-t2r; Bi[kpos+m][lc]=ui-t2i;
    }
    __syncthreads();
  }
  for (int i=tid;i<2048;i+=256){
    int r=i>>4, lc=i&15;
    tr[r*128+c0+lc]=Br[r][lc]; ti[r*128+c0+lc]=Bi[r][lc];
  }
}

__global__ __launch_bounds__(256) void k_fftC(const float* __restrict__ tmp, const float* __restrict__ sens,
                                              float* __restrict__ acc){
  int blk=blockIdx.x; int b=blk>>7, coil=(blk>>3)&15, rg=blk&7;
  int r0=rg*16;
  __shared__ float Ar[16][128], Ai[16][128];
  __shared__ float twr[64], twi[64];
  int tid=threadIdx.x;
  if (tid<64){ float ang=-2.f*PI_F*(float)tid/128.f; twr[tid]=cosf(ang); twi[tid]=sinf(ang); }
  const float* tr=tmp+(size_t)(b*16+coil)*2*L_;
  const float* ti=tr+L_;
  for (int i=tid;i<2048;i+=256){
    int lr=i>>7, w=i&127; int idx=(r0+lr)*128+w;
    Ar[lr][w]=tr[idx]; Ai[lr][w]=ti[idx];
  }
  __syncthreads();
  for (int s=0;s<7;s++){
    int m=1<<s;
    for (int q=tid;q<1024;q+=256){
      int lr=q>>6, jj=q&63;
      int j=jj&(m-1), gg=jj>>s;
      int kpos=(gg<<(s+1))+j;
      int tw=j<<(6-s);
      float wr=twr[tw], wi=-twi[tw];
      float vr=Ar[lr][kpos+m],vi=Ai[lr][kpos+m];
      float t2r=vr*wr-vi*wi, t2i=vr*wi+vi*wr;
      float ur=Ar[lr][kpos],ui=Ai[lr][kpos];
      Ar[lr][kpos]=ur+t2r; Ai[lr][kpos]=ui+t2i;
      Ar[lr][kpos+m]=ur-t2r; Ai[lr][kpos+m]=ui-t2i;
    }
    __syncthreads();
  }
  const float* srp=sens+(size_t)(b*32+2*coil)*L_;
  const float* sip=sens+(size_t)(b*32+2*coil+1)*L_;
  float* accr=acc+(size_t)(b*2)*L_;
  float* acci=accr+L_;
  for (int i=tid;i<2048;i+=256){
    int lr=i>>7, w=i&127; int gh=r0+lr; int idx=gh*128+w;
    float sc=(((gh+w)&1)?-1.f:1.f)*(1.f/16384.f);
    float wr2=Ar[lr][w]*sc, wi2=Ai[lr][w]*sc;
    float sr=srp[idx], si=sip[idx];
    atomicAdd(&accr[idx], sr*wr2+si*wi2);
    atomicAdd(&acci[idx], sr*wi2-si*wr2);
  }
}

__global__ void k_mag(const float* __restrict__ acc, float* __restrict__ out){
  int i=blockIdx.x*256+threadIdx.x;
  int b=i>>14, p=i&16383;
  float re=acc[(size_t)(b*2)*L_+p], im=acc[(size_t)(b*2+1)*L_+p];
  out[i]=sqrtf(re*re+im*im+1e-12f);
}

extern "C" void kernel_launch(void* const* d_in, const int* in_sizes, int n_in,
                              void* d_out, int out_size, void* d_ws, size_t ws_size,
                              hipStream_t stream){
  const float* in_imgs=(const float*)d_in[0];
  const float* in_ksp=(const float*)d_in[1];
  const float* mask=(const float*)d_in[2];
  const float* sens=(const float*)d_in[3];
  const float* pe_ln1_g=(const float*)d_in[4];
  const float* pe_ln1_b=(const float*)d_in[5];
  const float* pe_w=(const float*)d_in[6];
  const float* pe_b=(const float*)d_in[7];
  const float* pe_ln2_g=(const float*)d_in[8];
  const float* pe_ln2_b=(const float*)d_in[9];
  const float* pos_emb=(const float*)d_in[10];
  const float* enc_aln_g=(const float*)d_in[11];
  const float* enc_aln_b=(const float*)d_in[12];
  const float* enc_wqkv=(const float*)d_in[13];
  const float* enc_wo=(const float*)d_in[14];
  const float* enc_bo=(const float*)d_in[15];
  const float* enc_fln_g=(const float*)d_in[16];
  const float* enc_fln_b=(const float*)d_in[17];
  const float* enc_w1=(const float*)d_in[18];
  const float* enc_b1=(const float*)d_in[19];
  const float* enc_w2=(const float*)d_in[20];
  const float* enc_b2=(const float*)d_in[21];
  const float* enc_ng=(const float*)d_in[22];
  const float* enc_nb=(const float*)d_in[23];
  const float* dec_pos=(const float*)d_in[24];
  const float* dec_aln_g=(const float*)d_in[25];
  const float* dec_aln_b=(const float*)d_in[26];
  const float* dec_wqkv=(const float*)d_in[27];
  const float* dec_wo=(const float*)d_in[28];
  const float* dec_bo=(const float*)d_in[29];
  const float* dec_fln_g=(const float*)d_in[30];
  const float* dec_fln_b=(const float*)d_in[31];
  const float* dec_w1=(const float*)d_in[32];
  const float* dec_b1=(const float*)d_in[33];
  const float* dec_w2=(const float*)d_in[34];
  const float* dec_b2=(const float*)d_in[35];
  const float* dec_ng=(const float*)d_in[36];
  const float* dec_nb=(const float*)d_in[37];
  const float* fin_w=(const float*)d_in[38];
  const float* fin_b=(const float*)d_in[39];
  const float* ss_in_w=(const float*)d_in[40];
  const float* ss_in_b=(const float*)d_in[41];
  const float* ss_conv_w=(const float*)d_in[42];
  const float* ss_conv_b=(const float*)d_in[43];
  const float* ss_xproj=(const float*)d_in[44];
  const float* ss_dt_w=(const float*)d_in[45];
  const float* ss_dt_b=(const float*)d_in[46];
  const float* ss_Alog=(const float*)d_in[47];
  const float* ss_D=(const float*)d_in[48];
  const float* ss_ln_g=(const float*)d_in[49];
  const float* ss_ln_b=(const float*)d_in[50];
  const float* ss_out_w=(const float*)d_in[51];
  const float* ss_out_b=(const float*)d_in[52];
  const float* head_w=(const float*)d_in[53];
  const float* head_b=(const float*)d_in[54];
  const float* res_w1=(const float*)d_in[55];
  const float* res_b1=(const float*)d_in[56];
  const float* res_w2=(const float*)d_in[57];
  const float* res_b2=(const float*)d_in[58];
  const float* tail_w=(const float*)d_in[59];
  const float* tail_b=(const float*)d_in[60];
  const float* dc_alpha=(const float*)d_in[61];

  char* ws=(char*)d_ws;
  size_t off=0;
  auto alloc=[&](size_t nfloats)->float*{ float* p=(float*)(ws+off); off+=((nfloats*4+255)/256)*256; return p; };
  float* xn   =alloc((size_t)32*32768);
  float* stats=alloc(64);
  float* tA   =alloc(32*512);
  float* tB   =alloc(32*512);
  float* aln  =alloc(32*512);
  float* qkv  =alloc(32*1536);
  float* attno=alloc(32*512);
  float* ffh  =alloc(32*3072);
  float* xup  =alloc((size_t)2*4*L_);
  float* xz   =alloc((size_t)2*64*L_);
  float* xs0  =alloc((size_t)2*32*L_);
  float* xs0T =alloc((size_t)2*32*L_);
  float* dbl  =alloc((size_t)2*4*L_*18);
  float* ys   =alloc((size_t)2*4*32*L_);
  float* smv  =alloc((size_t)8*128*256*2);
  float* prebuf=alloc((size_t)8*128*256);
  float* oss  =alloc((size_t)2*20*L_);
  float* xc   =alloc((size_t)2*56*L_);
  float* h0   =alloc((size_t)2*64*L_);
  float* tmpc =alloc((size_t)2*64*L_);
  float* csc  =alloc((size_t)2*2*64*L_);
  float* x_ri =alloc((size_t)2*2*L_);
  float* ftmp =alloc((size_t)32*2*L_);
  float* accb =alloc((size_t)2*2*L_);
  (void)ws_size; (void)in_sizes; (void)n_in; (void)out_size;

  // ---- patch embed + encoder/decoder ----
  hipMemsetAsync(stats, 0, 64*4, stream);
  k_pesum<<<256,256,0,stream>>>(in_imgs, stats);
  k_penorm<<<256,256,0,stream>>>(in_imgs, stats, pe_ln1_g, pe_ln1_b, xn);
  hipMemsetAsync(tA, 0, 32*512*4, stream);
  k_gemm_sk<256,0><<<dim3(8,128),256,0,stream>>>(xn, pe_w, pe_b, tA, 512, 32768);
  k_pe_post<<<32,256,0,stream>>>(tA, pe_ln2_g, pe_ln2_b, pos_emb);

  for (int i=0;i<4;i++){
    k_ln_tok<<<32,256,0,stream>>>(tA, enc_aln_g+i*512, enc_aln_b+i*512, aln);
    hipMemsetAsync(qkv, 0, 32*1536*4, stream);
    k_gemm_sk<64,0><<<dim3(24,8),256,0,stream>>>(aln, enc_wqkv+(size_t)i*512*1536, nullptr, qkv, 1536, 512);
    k_attn<<<16,256,0,stream>>>(qkv, attno);
    k_gemm_sk<64,0><<<dim3(8,8),256,0,stream>>>(attno, enc_wo+(size_t)i*512*512, enc_bo+i*512, tA, 512, 512);
    k_ln_tok<<<32,256,0,stream>>>(tA, enc_fln_g+i*512, enc_fln_b+i*512, aln);
    hipMemsetAsync(ffh, 0, 32*2048*4, stream);
    k_gemm_sk<64,0><<<dim3(32,8),256,0,stream>>>(aln, enc_w1+(size_t)i*512*2048, enc_b1+i*2048, ffh, 2048, 512);
    k_gemm_sk<64,1><<<dim3(8,32),256,0,stream>>>(ffh, enc_w2+(size_t)i*2048*512, enc_b2+i*512, tA, 512, 2048);
  }
  k_ln_tok<<<32,256,0,stream>>>(tA, enc_ng, enc_nb, tA);
  k_addpos<<<64,256,0,stream>>>(tA, dec_pos, tB);
  k_ln_tok<<<32,256,0,stream>>>(tB, dec_aln_g, dec_aln_b, aln);
  hipMemsetAsync(qkv, 0, 32*1536*4, stream);
  k_gemm_sk<64,0><<<dim3(24,8),256,0,stream>>>(aln, dec_wqkv, nullptr, qkv, 1536, 512);
  k_attn<<<16,256,0,stream>>>(qkv, attno);
  k_gemm_sk<64,0><<<dim3(8,8),256,0,stream>>>(attno, dec_wo, dec_bo, tB, 512, 512);
  k_ln_tok<<<32,256,0,stream>>>(tB, dec_fln_g, dec_fln_b, aln);
  hipMemsetAsync(ffh, 0, 32*3072*4, stream);
  k_gemm_sk<64,0><<<dim3(48,8),256,0,stream>>>(aln, dec_w1, dec_b1, ffh, 3072, 512);
  k_gemm_sk<64,1><<<dim3(8,48),256,0,stream>>>(ffh, dec_w2, dec_b2, tB, 512, 3072);
  k_ln_tok<<<32,256,0,stream>>>(tB, dec_ng, dec_nb, tB);
  hipMemsetAsync(xup, 0, (size_t)2*4*L_*4, stream);
  k_gemm_sk<64,2><<<dim3(64,8),256,0,stream>>>(tB, fin_w, fin_b, xup, 4096, 512);

  // ---- SS2D ----
  k_xz<<<128,256,0,stream>>>(in_ksp, ss_in_w, ss_in_b, xz);
  k_dwconv<<<4096,256,0,stream>>>(xz, ss_conv_w, ss_conv_b, xs0);
  k_transpose<<<dim3(4,4,64),256,0,stream>>>(xs0, xs0T);
  k_dbl<<<dim3(64,8),256,0,stream>>>(xs0, xs0T, ss_xproj, dbl);
  k_scan1<<<1024,256,0,stream>>>(dbl, xs0, xs0T, ss_dt_w, ss_dt_b, ss_Alog, (float2*)smv);
  k_scan2<<<8,256,0,stream>>>((const float2*)smv, prebuf);
  k_scan3<<<1024,256,0,stream>>>(dbl, xs0, xs0T, ss_dt_w, ss_dt_b, ss_Alog, prebuf, ys);
  k_ycomb<<<256,256,0,stream>>>(ys, xz, xs0, ss_D, ss_ln_g, ss_ln_b, ss_out_w, ss_out_b, oss);

  // ---- conv head ----
  k_concat<<<7168,256,0,stream>>>(xup, in_imgs, oss, xc);
  k_conv3s<4><<<dim3(16,16,4),256,0,stream>>>(xc, head_w, csc, 56, 64, 28);
  k_epi<<<8192,256,0,stream>>>(csc, head_b, nullptr, h0, 64, 1);
  for (int i=0;i<3;i++){
    k_conv3s<4><<<dim3(16,16,4),256,0,stream>>>(h0, res_w1+(size_t)i*64*64*9, csc, 64, 64, 32);
    k_epi<<<8192,256,0,stream>>>(csc, res_b1+i*64, nullptr, tmpc, 64, 1);
    k_conv3s<4><<<dim3(16,16,4),256,0,stream>>>(tmpc, res_w2+(size_t)i*64*64*9, csc, 64, 64, 32);
    k_epi<<<8192,256,0,stream>>>(csc, res_b2+i*64, h0, h0, 64, 1);
  }
  k_conv3s<2><<<dim3(16,1,4),256,0,stream>>>(h0, tail_w, csc, 64, 2, 32);
  k_epi<<<256,256,0,stream>>>(csc, tail_b, nullptr, x_ri, 2, 0);

  // ---- FFT data consistency ----
  hipMemsetAsync(accb, 0, (size_t)2*2*L_*4, stream);
  k_fftA<<<256,256,0,stream>>>(x_ri, sens, ftmp);
  k_fftB<<<256,256,0,stream>>>(ftmp, in_ksp, mask, dc_alpha);
  k_fftC<<<256,256,0,stream>>>(ftmp, sens, accb);
  k_mag<<<128,256,0,stream>>>(accb, (float*)d_out);
}